// Round 6
// baseline (1222.640 us; speedup 1.0000x reference)
//
#include <hip/hip_runtime.h>
#include <stdint.h>
#include <math.h>

#define TT 516
#define BB 16
#define DD 512
#define LL 512
#define NN 512
#define HH 8
#define DHD 64
#define DFFN 2048
#define PP 336
#define MM 512
#define KNN 10
#define BT (BB*TT)      /* 8256 */
#define PN (PP*NN)      /* 172032 */
#define SKC 32          /* sims k-chunks */
#define SCHUNK (PN/SKC) /* 5376 */
#define SSTG (SCHUNK/256) /* 21 stages */
#define VSTR 528        /* transposed-V row stride (uint16 elems) */

using f32x4  = __attribute__((ext_vector_type(4))) float;
using bf16x8 = __attribute__((ext_vector_type(8))) __bf16;
using u16x8  = __attribute__((ext_vector_type(8))) unsigned short;

__device__ __forceinline__ float gelu_tanh(float x){
    float x3 = x*x*x;
    return 0.5f*x*(1.0f + tanhf(0.7978845608028654f*(x + 0.044715f*x3)));
}

__device__ __forceinline__ uint16_t f2bf(float x){
    uint32_t u = __builtin_bit_cast(uint32_t, x);
    uint32_t r = (u + 0x7FFFu + ((u >> 16) & 1u)) >> 16;
    return (uint16_t)r;
}

__device__ __forceinline__ void split_bf(float x, uint16_t& hi, uint16_t& lo){
    uint32_t u  = __builtin_bit_cast(uint32_t, x);
    uint32_t hr = (u + 0x7FFFu + ((u >> 16) & 1u)) & 0xFFFF0000u;
    float hf = __builtin_bit_cast(float, hr);
    hi = (uint16_t)(hr >> 16);
    lo = f2bf(x - hf);
}

__device__ __forceinline__ void gl16(const uint16_t* g, uint16_t* l){
    __builtin_amdgcn_global_load_lds(
        (const __attribute__((address_space(1))) unsigned int*)(const void*)g,
        (__attribute__((address_space(3))) unsigned int*)(void*)l, 16, 0, 0);
}

__device__ __forceinline__ bf16x8 ldb8(const uint16_t* p){
    return __builtin_bit_cast(bf16x8, *(const u16x8*)p);
}

#define EPI_F32   1
#define EPI_BF16  2
#define EPI_GELU  4
#define EPI_PREDT 8
#define EPI_QKV   16

// ---------------------------------------------------------------------------
// Split-bf16 MFMA GEMM, v2: double-buffered LDS + counted vmcnt (T3-min
// 2-phase). Stage tile k+1 BEFORE waiting on tile k; never vmcnt(0) mid-loop.
// ---------------------------------------------------------------------------
template<int BN, int FLAGS>
__global__ __launch_bounds__(256, (BN==64)?3:2)
void bgemm(const uint16_t* __restrict__ Ah, const uint16_t* __restrict__ Al,
           const uint16_t* __restrict__ Bh, const uint16_t* __restrict__ Bl,
           const float* __restrict__ bias, float* __restrict__ Cf,
           uint16_t* __restrict__ Cbh, uint16_t* __restrict__ Cbl,
           uint16_t* __restrict__ Xkh, uint16_t* __restrict__ Xkl,
           uint16_t* __restrict__ Xvh, uint16_t* __restrict__ Xvl,
           int Msz, int Nsz, int Ksz)
{
    constexpr int FN  = BN/32;
    constexpr int NLD = (BN==128) ? 8 : 6;    // gl16 per wave per stage
    __shared__ uint16_t As0[8192], As1[8192];          // 2 bufs x 128x32
    __shared__ uint16_t Bs0[2*BN*32], Bs1[2*BN*32];    // 2 bufs x BNx32

    const int tid  = threadIdx.x;
    const int lane = tid & 63;
    const int wu   = __builtin_amdgcn_readfirstlane(tid >> 6);
    const int wm   = wu >> 1, wn = wu & 1;
    const int m0   = blockIdx.y * 128;
    const int n0   = blockIdx.x * BN;

    const int r0c = tid >> 2;
    const int cc  = tid & 3;
    const int sw  = (r0c ^ (r0c >> 2)) & 3;
    const int csw = (cc ^ sw) * 8;
    int rA0 = m0 + r0c;      if (rA0 > Msz-1) rA0 = Msz-1;
    int rA1 = m0 + r0c + 64; if (rA1 > Msz-1) rA1 = Msz-1;
    int rB0 = n0 + r0c;      if (rB0 > Nsz-1) rB0 = Nsz-1;
    int rB1 = n0 + r0c + 64; if (rB1 > Nsz-1) rB1 = Nsz-1;
    const uint16_t* pAh0 = Ah + (size_t)rA0*Ksz + csw;
    const uint16_t* pAh1 = Ah + (size_t)rA1*Ksz + csw;
    const uint16_t* pAl0 = Al + (size_t)rA0*Ksz + csw;
    const uint16_t* pAl1 = Al + (size_t)rA1*Ksz + csw;
    const uint16_t* pBh0 = Bh + (size_t)rB0*Ksz + csw;
    const uint16_t* pBh1 = Bh + (size_t)rB1*Ksz + csw;
    const uint16_t* pBl0 = Bl + (size_t)rB0*Ksz + csw;
    const uint16_t* pBl1 = Bl + (size_t)rB1*Ksz + csw;

    f32x4 acc[4][FN];
#pragma unroll
    for (int i=0;i<4;i++)
#pragma unroll
        for (int j=0;j<FN;j++) acc[i][j] = (f32x4){0.f,0.f,0.f,0.f};

    const int lc16  = lane & 15;
    const int slot8 = (((lane>>4) ^ (lane&3) ^ ((lane>>2)&3))) * 8;
    const int rAf   = (wm*64 + lc16) * 32 + slot8;
    const int rBf   = (wn*(BN/2) + lc16) * 32 + slot8;

    auto stage = [&](int buf, int kt){
        uint16_t* a0 = &As0[buf*4096];
        uint16_t* a1 = &As1[buf*4096];
        uint16_t* b0 = &Bs0[buf*BN*32];
        uint16_t* b1 = &Bs1[buf*BN*32];
        gl16(pAh0 + kt, a0 + wu*512);
        gl16(pAh1 + kt, a0 + 2048 + wu*512);
        gl16(pAl0 + kt, a1 + wu*512);
        gl16(pAl1 + kt, a1 + 2048 + wu*512);
        if (BN == 128){
            gl16(pBh0 + kt, b0 + wu*512);
            gl16(pBh1 + kt, b0 + 2048 + wu*512);
            gl16(pBl0 + kt, b1 + wu*512);
            gl16(pBl1 + kt, b1 + 2048 + wu*512);
        } else {
            gl16(pBh0 + kt, b0 + wu*512);
            gl16(pBl0 + kt, b1 + wu*512);
        }
    };

    stage(0, 0);
    int cur = 0;
    for (int kt = 0; kt < Ksz; kt += 32){
        if (kt + 32 < Ksz){
            stage(cur^1, kt + 32);
            asm volatile("s_waitcnt vmcnt(%0)" :: "i"(NLD) : "memory");
        } else {
            asm volatile("s_waitcnt vmcnt(0)" ::: "memory");
        }
        __builtin_amdgcn_s_barrier();
        __builtin_amdgcn_sched_barrier(0);

        const uint16_t* a0 = &As0[cur*4096];
        const uint16_t* a1 = &As1[cur*4096];
        const uint16_t* b0 = &Bs0[cur*BN*32];
        const uint16_t* b1 = &Bs1[cur*BN*32];

        bf16x8 ah[4], al[4];
#pragma unroll
        for (int fm=0; fm<4; fm++){
            ah[fm] = ldb8(a0 + rAf + fm*512);
            al[fm] = ldb8(a1 + rAf + fm*512);
        }
#pragma unroll
        for (int fn=0; fn<FN; fn++){
            bf16x8 bh = ldb8(b0 + rBf + fn*512);
            bf16x8 bl = ldb8(b1 + rBf + fn*512);
#pragma unroll
            for (int fm=0; fm<4; fm++){
                acc[fm][fn] = __builtin_amdgcn_mfma_f32_16x16x32_bf16(ah[fm], bh, acc[fm][fn], 0,0,0);
                acc[fm][fn] = __builtin_amdgcn_mfma_f32_16x16x32_bf16(ah[fm], bl, acc[fm][fn], 0,0,0);
                acc[fm][fn] = __builtin_amdgcn_mfma_f32_16x16x32_bf16(al[fm], bh, acc[fm][fn], 0,0,0);
            }
        }
        __builtin_amdgcn_sched_barrier(0);
        __builtin_amdgcn_s_barrier();
        cur ^= 1;
    }

    const int lr4 = (lane >> 4) * 4;
#pragma unroll
    for (int fm=0; fm<4; fm++){
        const int rbase = m0 + wm*64 + fm*16 + lr4;
#pragma unroll
        for (int fn=0; fn<FN; fn++){
            const int col = n0 + wn*(BN/2) + fn*16 + lc16;
            f32x4 v = acc[fm][fn];
            if (FLAGS & EPI_PREDT){
#pragma unroll
                for (int r=0;r<4;r++){
                    int row = rbase + r;
                    if (row < Msz && col < PP){
                        int b = row / TT, t = row - b*TT;
                        if (t < NN)
                            Cf[((size_t)b*PP + col)*NN + t] = v[r] + bias[col];
                    }
                }
            } else if (FLAGS & EPI_QKV){
                const int g   = col >> 9;
                const int cc2 = col & 511;
                const int hh2 = cc2 >> 6, dd2 = cc2 & 63;
                const float bcol = bias[col];
#pragma unroll
                for (int r=0;r<4;r++){
                    int row = rbase + r;
                    if (row < Msz){
                        float x = v[r] + bcol;
                        int b2 = row / TT, t2 = row - b2*TT;
                        int bh2 = b2*HH + hh2;
                        uint16_t hi, lo; split_bf(x, hi, lo);
                        if (g == 0){
                            size_t o = ((size_t)bh2*TT + t2)*64 + dd2;
                            Cbh[o] = hi; Cbl[o] = lo;
                        } else if (g == 1){
                            size_t o = ((size_t)bh2*TT + t2)*64 + dd2;
                            Xkh[o] = hi; Xkl[o] = lo;
                        } else {
                            size_t o = ((size_t)bh2*64 + dd2)*VSTR + t2;
                            Xvh[o] = hi; Xvl[o] = lo;
                        }
                    }
                }
            } else {
                const float bcol = bias[col];
#pragma unroll
                for (int r=0;r<4;r++){
                    int row = rbase + r;
                    if (row < Msz){
                        float x = v[r] + bcol;
                        if (FLAGS & EPI_GELU) x = gelu_tanh(x);
                        if (FLAGS & EPI_F32) Cf[(size_t)row*Nsz + col] = x;
                        if (FLAGS & EPI_BF16){
                            uint16_t hi, lo; split_bf(x, hi, lo);
                            Cbh[(size_t)row*Nsz + col] = hi;
                            Cbl[(size_t)row*Nsz + col] = lo;
                        }
                    }
                }
            }
        }
    }
}

// ---------------------------------------------------------------------------
// tok transpose + split (unchanged)
// ---------------------------------------------------------------------------
__global__ __launch_bounds__(256)
void tok_k(const float* __restrict__ xe, const float* __restrict__ xm,
           uint16_t* __restrict__ th, uint16_t* __restrict__ tl)
{
    const int b = blockIdx.z;
    const int t0 = blockIdx.x*32, l0 = blockIdx.y*32;
    __shared__ float tile[32][33];
    const int i = threadIdx.x >> 3;
    const int j4 = (threadIdx.x & 7) * 4;
#pragma unroll
    for (int c=0;c<4;c++){
        int t = t0 + j4 + c;
        float v = 0.0f;
        if (t < 512)      v = xe[((size_t)b*LL + l0+i)*NN + t];
        else if (t < 516) v = xm[((size_t)b*LL + l0+i)*4 + (t-512)];
        tile[i][j4+c] = v;
    }
    __syncthreads();
    int t = t0 + i;
    if (t < TT){
#pragma unroll
        for (int c=0;c<4;c++){
            uint16_t hi, lo; split_bf(tile[j4+c][i], hi, lo);
            size_t idx = ((size_t)b*TT + t)*512 + l0 + j4 + c;
            th[idx] = hi; tl[idx] = lo;
        }
    }
}

// ---------------------------------------------------------------------------
// weight transpose-split (unchanged)
// ---------------------------------------------------------------------------
__global__ __launch_bounds__(256)
void wtr_k(const float* __restrict__ src, uint16_t* __restrict__ dh,
           uint16_t* __restrict__ dl, int Ksz, int Nsz, size_t zstride)
{
    const int z = blockIdx.z;
    src += (size_t)z*Ksz*Nsz; dh += (size_t)z*zstride; dl += (size_t)z*zstride;
    __shared__ float tile[32][33];
    const int kt = blockIdx.y*32, nt = blockIdx.x*32;
    const int i = threadIdx.x >> 3;
    const int j4 = (threadIdx.x & 7) * 4;
#pragma unroll
    for (int c=0;c<4;c++){
        int n = nt + j4 + c;
        tile[i][j4+c] = (n < Nsz) ? src[(size_t)(kt+i)*Nsz + n] : 0.0f;
    }
    __syncthreads();
    int n = nt + i;
    if (n < Nsz){
#pragma unroll
        for (int c=0;c<4;c++){
            uint16_t hi, lo; split_bf(tile[j4+c][i], hi, lo);
            size_t idx = (size_t)n*Ksz + kt + j4 + c;
            dh[idx] = hi; dl[idx] = lo;
        }
    }
}

__global__ void catb_k(const float* __restrict__ bq, const float* __restrict__ bk,
                       const float* __restrict__ bv, float* __restrict__ dst){
    int j = blockIdx.x*256 + threadIdx.x;
    if (j >= 3072) return;
    int layer = j / 1536, r = j - layer*1536;
    float v;
    if (r < 512)       v = bq[layer*512 + r];
    else if (r < 1024) v = bk[layer*512 + r - 512];
    else               v = bv[layer*512 + r - 1024];
    dst[j] = v;
}

// ---------------------------------------------------------------------------
// MFMA flash attention (unchanged from round 5, dead code removed)
// ---------------------------------------------------------------------------
__global__ __launch_bounds__(256, 2)
void attnm_k(const uint16_t* __restrict__ qh, const uint16_t* __restrict__ ql,
             const uint16_t* __restrict__ kh, const uint16_t* __restrict__ kl,
             const uint16_t* __restrict__ vth, const uint16_t* __restrict__ vtl,
             uint16_t* __restrict__ oh, uint16_t* __restrict__ ol)
{
    const int qt = blockIdx.x;
    const int h  = blockIdx.y;
    const int b  = blockIdx.z;
    const int bh = b*HH + h;
    const int q0 = qt*64;
    const int tid  = threadIdx.x;
    const int lane = tid & 63;
    const int wu   = __builtin_amdgcn_readfirstlane(tid >> 6);
    const int mrow = lane & 15;
    const int kgrp = lane >> 4;

    __shared__ uint16_t Khs[4096], Kls[4096];
    __shared__ uint16_t Vhs[4096], Vls[4096];
    __shared__ uint16_t Phs[4096], Pls[4096];

    int tq = q0 + wu*16 + mrow; if (tq > TT-1) tq = TT-1;
    const uint16_t* qbase = qh + ((size_t)bh*TT + tq)*64 + kgrp*8;
    const uint16_t* qbasl = ql + ((size_t)bh*TT + tq)*64 + kgrp*8;
    bf16x8 qfh[2], qfl[2];
    qfh[0] = ldb8(qbase);      qfh[1] = ldb8(qbase + 32);
    qfl[0] = ldb8(qbasl);      qfl[1] = ldb8(qbasl + 32);

    const int srw = lane >> 3;
    const int sg  = lane & 7;

    f32x4 oacc[4];
#pragma unroll
    for (int f=0;f<4;f++) oacc[f] = (f32x4){0.f,0.f,0.f,0.f};
    float m_r[4] = {-1e30f,-1e30f,-1e30f,-1e30f};
    float l_r[4] = {0.f,0.f,0.f,0.f};

    for (int st=0; st<9; ++st){
        const int s0 = st*64;
        __syncthreads();
#pragma unroll
        for (int c=0;c<2;c++){
            const int r   = wu*16 + c*8 + srw;
            const int gsl = sg ^ (r & 7);
            int sk = s0 + r; if (sk > TT-1) sk = TT-1;
            const uint16_t* ksh_ = kh  + ((size_t)bh*TT + sk)*64 + gsl*8;
            const uint16_t* ksl_ = kl  + ((size_t)bh*TT + sk)*64 + gsl*8;
            int cb = s0 + gsl*8; if (cb > VSTR-8) cb = VSTR-8;
            const uint16_t* vsh_ = vth + ((size_t)bh*64 + r)*VSTR + cb;
            const uint16_t* vsl_ = vtl + ((size_t)bh*64 + r)*VSTR + cb;
            gl16(ksh_, &Khs[(wu*16 + c*8)*64]);
            gl16(ksl_, &Kls[(wu*16 + c*8)*64]);
            gl16(vsh_, &Vhs[(wu*16 + c*8)*64]);
            gl16(vsl_, &Vls[(wu*16 + c*8)*64]);
        }
        __syncthreads();

        f32x4 sacc[4];
#pragma unroll
        for (int f=0;f<4;f++) sacc[f] = (f32x4){0.f,0.f,0.f,0.f};
#pragma unroll
        for (int ks=0; ks<2; ks++){
#pragma unroll
            for (int f=0; f<4; f++){
                const int sr = f*16 + mrow;
                const int sl = ((ks*4 + kgrp) ^ (sr & 7))*8;
                bf16x8 kbh = ldb8(&Khs[sr*64 + sl]);
                bf16x8 kbl = ldb8(&Kls[sr*64 + sl]);
                sacc[f] = __builtin_amdgcn_mfma_f32_16x16x32_bf16(qfh[ks], kbh, sacc[f], 0,0,0);
                sacc[f] = __builtin_amdgcn_mfma_f32_16x16x32_bf16(qfh[ks], kbl, sacc[f], 0,0,0);
                sacc[f] = __builtin_amdgcn_mfma_f32_16x16x32_bf16(qfl[ks], kbh, sacc[f], 0,0,0);
            }
        }

        float alpha[4];
#pragma unroll
        for (int r=0;r<4;r++){
            float mx = -1e30f;
#pragma unroll
            for (int f=0;f<4;f++){
                float sv = sacc[f][r]*0.125f;
                if (s0 + f*16 + mrow >= TT) sv = -1e30f;
                sacc[f][r] = sv;
                mx = fmaxf(mx, sv);
            }
#pragma unroll
            for (int msk=1; msk<16; msk<<=1) mx = fmaxf(mx, __shfl_xor(mx, msk));
            float mn = fmaxf(m_r[r], mx);
            alpha[r] = __expf(m_r[r] - mn);
            m_r[r] = mn;
            float rs = 0.0f;
#pragma unroll
            for (int f=0;f<4;f++){
                float e = __expf(sacc[f][r] - mn);
                sacc[f][r] = e;
                rs += e;
            }
#pragma unroll
            for (int msk=1; msk<16; msk<<=1) rs += __shfl_xor(rs, msk);
            l_r[r] = l_r[r]*alpha[r] + rs;
#pragma unroll
            for (int f=0;f<4;f++) oacc[f][r] *= alpha[r];
        }

#pragma unroll
        for (int r=0;r<4;r++){
            const int tr = wu*16 + kgrp*4 + r;
#pragma unroll
            for (int f=0;f<4;f++){
                const int c = f*16 + mrow;
                const int idx = tr*64 + ((c>>3) ^ (tr&7))*8 + (c&7);
                uint16_t hi, lo; split_bf(sacc[f][r], hi, lo);
                Phs[idx] = hi; Pls[idx] = lo;
            }
        }

#pragma unroll
        for (int ks=0; ks<2; ks++){
            const int trr = wu*16 + mrow;
            const int psl = ((ks*4 + kgrp) ^ (trr & 7))*8;
            bf16x8 pah = ldb8(&Phs[trr*64 + psl]);
            bf16x8 pal = ldb8(&Pls[trr*64 + psl]);
#pragma unroll
            for (int f=0; f<4; f++){
                const int dr = f*16 + mrow;
                const int vsl = ((ks*4 + kgrp) ^ (dr & 7))*8;
                bf16x8 vbh = ldb8(&Vhs[dr*64 + vsl]);
                bf16x8 vbl = ldb8(&Vls[dr*64 + vsl]);
                oacc[f] = __builtin_amdgcn_mfma_f32_16x16x32_bf16(pah, vbh, oacc[f], 0,0,0);
                oacc[f] = __builtin_amdgcn_mfma_f32_16x16x32_bf16(pah, vbl, oacc[f], 0,0,0);
                oacc[f] = __builtin_amdgcn_mfma_f32_16x16x32_bf16(pal, vbh, oacc[f], 0,0,0);
            }
        }
    }

#pragma unroll
    for (int r=0;r<4;r++){
        const int t = q0 + wu*16 + kgrp*4 + r;
        if (t < TT){
            const float inv = 1.0f / l_r[r];
#pragma unroll
            for (int f=0;f<4;f++){
                const int d = f*16 + mrow;
                uint16_t hi, lo; split_bf(oacc[f][r]*inv, hi, lo);
                size_t o = ((size_t)(b*TT + t))*DD + h*DHD + d;
                oh[o] = hi; ol[o] = lo;
            }
        }
    }
}

// ---------------------------------------------------------------------------
// Residual + LayerNorm (unchanged)
// ---------------------------------------------------------------------------
__global__ __launch_bounds__(256)
void ln_k(const float* __restrict__ src, const float* __restrict__ res,
          const float* __restrict__ w, const float* __restrict__ bia,
          float* __restrict__ dst, uint16_t* __restrict__ dbh,
          uint16_t* __restrict__ dbl)
{
    const int r = blockIdx.x;
    const int tid = threadIdx.x;
    const float* sp = src + (size_t)r*DD;
    float x0 = sp[tid], x1 = sp[tid + 256];
    if (res){
        x0 += res[(size_t)r*DD + tid];
        x1 += res[(size_t)r*DD + tid + 256];
    }
    float s  = x0 + x1;
    float sq = x0*x0 + x1*x1;
#pragma unroll
    for (int msk=1; msk<64; msk<<=1){
        s  += __shfl_xor(s,  msk);
        sq += __shfl_xor(sq, msk);
    }
    __shared__ float sm[8];
    int wv = tid >> 6, ln = tid & 63;
    if (ln == 0){ sm[wv] = s; sm[wv+4] = sq; }
    __syncthreads();
    s  = sm[0]+sm[1]+sm[2]+sm[3];
    sq = sm[4]+sm[5]+sm[6]+sm[7];
    float mu  = s * (1.0f/512.0f);
    float var = sq * (1.0f/512.0f) - mu*mu;
    float rsd = rsqrtf(var + 1e-5f);
    float y0 = (x0 - mu)*rsd*w[tid]       + bia[tid];
    float y1 = (x1 - mu)*rsd*w[tid + 256] + bia[tid + 256];
    dst[(size_t)r*DD + tid]       = y0;
    dst[(size_t)r*DD + tid + 256] = y1;
    uint16_t hi, lo;
    split_bf(y0, hi, lo); dbh[(size_t)r*DD + tid] = hi;       dbl[(size_t)r*DD + tid] = lo;
    split_bf(y1, hi, lo); dbh[(size_t)r*DD + tid + 256] = hi; dbl[(size_t)r*DD + tid + 256] = lo;
}

// ---------------------------------------------------------------------------
// sims (unchanged from round 4)
// ---------------------------------------------------------------------------
__global__ __launch_bounds__(256, 2)
void sims_k(const float* __restrict__ pred, const float* __restrict__ bank,
            float* __restrict__ dotp, float* __restrict__ nrmp)
{
    const int jt = blockIdx.x, kt = blockIdx.y;
    const int tid  = threadIdx.x;
    const int lane = tid & 63;
    const int w    = tid >> 6;
    const int qq   = lane & 15;
    const int rep  = lane >> 4;
    const int sb   = (w*4 + rep)*16;
    const int srow = tid >> 4;
    const int tau  = tid & 15;

    __shared__ float BS[16*264];

    const int jr = jt*16 + srow;
    const float* bsrc = (jr < MM) ? (bank + (size_t)jr*PN)
                                  : (pred + (size_t)(jr - MM)*PN);
    bsrc += (size_t)kt*SCHUNK + tau*4;
    const float* psrc = pred + (size_t)qq*PN + (size_t)kt*SCHUNK + sb;

    float acc[16];
#pragma unroll
    for (int j=0;j<16;j++) acc[j] = 0.0f;
    float nr = 0.0f;

    for (int st=0; st<SSTG; ++st){
        float4 blv[4];
#pragma unroll
        for (int c=0;c<4;c++) blv[c] = *(const float4*)(bsrc + c*64);
        float4 pr[4];
#pragma unroll
        for (int i=0;i<4;i++) pr[i] = *(const float4*)(psrc + i*4);
        __syncthreads();
#pragma unroll
        for (int c=0;c<4;c++){
            *(float4*)&BS[srow*264 + tau*4 + c*64] = blv[c];
            nr = fmaf(blv[c].x, blv[c].x, nr);
            nr = fmaf(blv[c].y, blv[c].y, nr);
            nr = fmaf(blv[c].z, blv[c].z, nr);
            nr = fmaf(blv[c].w, blv[c].w, nr);
        }
        __syncthreads();
#pragma unroll
        for (int j=0;j<16;j++){
            float a = acc[j];
#pragma unroll
            for (int i=0;i<4;i++){
                float4 bv = *(const float4*)&BS[j*264 + sb + i*4];
                a = fmaf(bv.x, pr[i].x, a);
                a = fmaf(bv.y, pr[i].y, a);
                a = fmaf(bv.z, pr[i].z, a);
                a = fmaf(bv.w, pr[i].w, a);
            }
            acc[j] = a;
        }
        bsrc += 256; psrc += 256;
    }

    __syncthreads();
    float* RED = BS;
    const int slot = w*4 + rep;
#pragma unroll
    for (int j=0;j<16;j++) RED[(slot*16 + j)*16 + qq] = acc[j];
#pragma unroll
    for (int m=1;m<16;m<<=1) nr += __shfl_xor(nr, m);
    __syncthreads();
    const int j2 = tid >> 4, q2 = tid & 15;
    float s = 0.0f;
#pragma unroll
    for (int s16=0;s16<16;s16++) s += RED[(s16*16 + j2)*16 + q2];
    dotp[((size_t)kt*528 + jt*16 + j2)*16 + q2] = s;
    if (tau == 0) nrmp[kt*528 + jt*16 + srow] = nr;
}

__global__ void norms_k(const float* __restrict__ nrmp, float* __restrict__ invn){
    int j = blockIdx.x*blockDim.x + threadIdx.x;
    if (j < 528){
        float s = 0.0f;
        for (int kt=0; kt<SKC; kt++) s += nrmp[kt*528 + j];
        invn[j] = 1.0f/(sqrtf(s) + 1e-8f);
    }
}

__global__ void simsfin_k(const float* __restrict__ dotp, const float* __restrict__ invn,
                          float* __restrict__ sims){
    int fid = blockIdx.x*256 + threadIdx.x;
    int j = fid >> 4, q = fid & 15;
    float s = 0.0f;
    for (int kt=0; kt<SKC; kt++) s += dotp[((size_t)kt*528 + j)*16 + q];
    sims[q*528 + j] = s * invn[j] * invn[MM + q];
}

__global__ __launch_bounds__(64)
void topk_k(const float* __restrict__ sims, int* __restrict__ idx){
    const int q = blockIdx.x;
    const int lane = threadIdx.x;
    __shared__ float vals[528];
    for (int j=lane; j<528; j+=64) vals[j] = sims[q*528 + j];
    __syncthreads();
    for (int kk=0; kk<KNN; kk++){
        float bv = -3.0e38f; int bi = 1<<30;
        for (int j=lane; j<528; j+=64){
            float v2 = vals[j];
            if (v2 > bv || (v2 == bv && j < bi)){ bv = v2; bi = j; }
        }
#pragma unroll
        for (int msk=1; msk<64; msk<<=1){
            float ov = __shfl_xor(bv, msk);
            int   oi = __shfl_xor(bi, msk);
            if (ov > bv || (ov == bv && oi < bi)){ bv = ov; bi = oi; }
        }
        if (lane == 0){
            idx[q*KNN + kk] = bi;
            vals[bi] = -3.0e38f;
        }
        __syncthreads();
    }
}

__global__ __launch_bounds__(256)
void fuse_k(const float* __restrict__ pred, const float* __restrict__ bank,
            const int* __restrict__ idx, float* __restrict__ out){
    int u = blockIdx.x*256 + threadIdx.x;
    int b = u / (PN/4);
    int e = (u - b*(PN/4)) * 4;
    int id[KNN];
#pragma unroll
    for (int k2=0;k2<KNN;k2++) id[k2] = idx[b*KNN + k2];
    float4 pv = *(const float4*)(pred + (size_t)b*PN + e);
    float ax = 0.5f*pv.x, ay = 0.5f*pv.y, az = 0.5f*pv.z, aw = 0.5f*pv.w;
#pragma unroll
    for (int k2=0;k2<KNN;k2++){
        const float* rp = (id[k2] < MM) ? (bank + (size_t)id[k2]*PN)
                                        : (pred + (size_t)(id[k2]-MM)*PN);
        float4 rv = *(const float4*)(rp + e);
        ax = fmaf(0.05f, rv.x, ax); ay = fmaf(0.05f, rv.y, ay);
        az = fmaf(0.05f, rv.z, az); aw = fmaf(0.05f, rv.w, aw);
    }
    float4 ov; ov.x=ax; ov.y=ay; ov.z=az; ov.w=aw;
    *(float4*)(out + (size_t)b*PN + e) = ov;
}

// ---------------------------------------------------------------------------
extern "C" void kernel_launch(void* const* d_in, const int* in_sizes, int n_in,
                              void* d_out, int out_size, void* d_ws, size_t ws_size,
                              hipStream_t stream)
{
    (void)in_sizes; (void)n_in; (void)out_size; (void)ws_size;
    const float* x_enc  = (const float*)d_in[0];
    const float* x_mark = (const float*)d_in[1];
    const float* W_emb  = (const float*)d_in[4];
    const float* b_emb  = (const float*)d_in[5];
    const float* Wq  = (const float*)d_in[6];
    const float* Wk  = (const float*)d_in[7];
    const float* Wv  = (const float*)d_in[8];
    const float* Wo  = (const float*)d_in[9];
    const float* bq  = (const float*)d_in[10];
    const float* bk  = (const float*)d_in[11];
    const float* bv_ = (const float*)d_in[12];
    const float* bo  = (const float*)d_in[13];
    const float* ln1w = (const float*)d_in[14];
    const float* ln1b = (const float*)d_in[15];
    const float* ln2w = (const float*)d_in[16];
    const float* ln2b = (const float*)d_in[17];
    const float* Wff1 = (const float*)d_in[18];
    const float* bff1 = (const float*)d_in[19];
    const float* Wff2 = (const float*)d_in[20];
    const float* bff2 = (const float*)d_in[21];
    const float* lnfw = (const float*)d_in[22];
    const float* lnfb = (const float*)d_in[23];
    const float* Wproj = (const float*)d_in[24];
    const float* bproj = (const float*)d_in[25];
    const float* bank  = (const float*)d_in[26];
    float* out = (float*)d_out;

    char* pp = (char*)d_ws;
    auto a16 = [&](size_t elems)->uint16_t*{ uint16_t* r=(uint16_t*)pp; pp += ((elems*2 + 255)/256)*256; return r; };
    auto af  = [&](size_t elems)->float*  { float* r=(float*)pp;  pp += ((elems*4 + 255)/256)*256; return r; };

    uint16_t* wembT_h = a16(262144);        uint16_t* wembT_l = a16(262144);
    uint16_t* wqkvT_h = a16(2*1536*512);    uint16_t* wqkvT_l = a16(2*1536*512);
    uint16_t* woT_h   = a16(2*262144);      uint16_t* woT_l   = a16(2*262144);
    uint16_t* wff1T_h = a16(2*2048*512);    uint16_t* wff1T_l = a16(2*2048*512);
    uint16_t* wff2T_h = a16(2*512*2048);    uint16_t* wff2T_l = a16(2*512*2048);
    uint16_t* wprjT_h = a16(172032);        uint16_t* wprjT_l = a16(172032);
    float*    bqkv    = af(3072);
    uint16_t* hb_h    = a16((size_t)BT*512);
    uint16_t* hb_l    = a16((size_t)BT*512);
    uint16_t* tok_h   = a16((size_t)BT*512);     // og fp32 aliases tok region
    uint16_t* tok_l   = a16((size_t)BT*512);
    float*    og      = (float*)tok_h;
    uint16_t* qsh     = a16((size_t)128*TT*64);
    uint16_t* qsl     = a16((size_t)128*TT*64);
    uint16_t* ksh     = a16((size_t)128*TT*64);
    uint16_t* ksl     = a16((size_t)128*TT*64);
    uint16_t* vsh     = a16((size_t)128*64*VSTR + 4096);
    uint16_t* vsl     = a16((size_t)128*64*VSTR + 4096);
    uint16_t* t1b_h   = a16((size_t)BT*512);
    uint16_t* t1b_l   = a16((size_t)BT*512);
    uint16_t* midb_h  = qsh;                     // mid aliases qsh..t1b region
    uint16_t* midb_l  = midb_h + (size_t)BT*2048;
    float*    h       = af((size_t)BT*512);
    float*    pred    = af((size_t)BB*PN);
    float*    dotp    = af((size_t)SKC*528*16);
    float*    nrmp    = af(SKC*528);
    float*    invn    = af(528);
    float*    sims    = af(16*528);
    int*      idxp    = (int*)af(256);

    dim3 blk(256);

    tok_k<<<dim3(17,16,BB), blk, 0, stream>>>(x_enc, x_mark, tok_h, tok_l);
    wtr_k<<<dim3(16,16,1), blk, 0, stream>>>(W_emb, wembT_h, wembT_l, 512, 512, 262144);
    wtr_k<<<dim3(16,16,2), blk, 0, stream>>>(Wq, wqkvT_h,          wqkvT_l,          512, 512, 786432);
    wtr_k<<<dim3(16,16,2), blk, 0, stream>>>(Wk, wqkvT_h + 262144, wqkvT_l + 262144, 512, 512, 786432);
    wtr_k<<<dim3(16,16,2), blk, 0, stream>>>(Wv, wqkvT_h + 524288, wqkvT_l + 524288, 512, 512, 786432);
    wtr_k<<<dim3(16,16,2), blk, 0, stream>>>(Wo, woT_h, woT_l, 512, 512, 262144);
    wtr_k<<<dim3(64,16,2), blk, 0, stream>>>(Wff1, wff1T_h, wff1T_l, 512, 2048, 1048576);
    wtr_k<<<dim3(16,64,2), blk, 0, stream>>>(Wff2, wff2T_h, wff2T_l, 2048, 512, 1048576);
    wtr_k<<<dim3(11,16,1), blk, 0, stream>>>(Wproj, wprjT_h, wprjT_l, 512, 336, 172032);
    catb_k<<<dim3(12), blk, 0, stream>>>(bq, bk, bv_, bqkv);

    bgemm<64, EPI_F32|EPI_BF16><<<dim3(8,65), blk, 0, stream>>>(
        tok_h, tok_l, wembT_h, wembT_l, b_emb, h, hb_h, hb_l,
        nullptr, nullptr, nullptr, nullptr, BT, 512, 512);

    for (int i=0;i<2;i++){
        bgemm<128, EPI_QKV><<<dim3(12,65), blk, 0, stream>>>(
            hb_h, hb_l, wqkvT_h + (size_t)i*786432, wqkvT_l + (size_t)i*786432,
            bqkv + i*1536, nullptr, qsh, qsl, ksh, ksl, vsh, vsl, BT, 1536, 512);
        attnm_k<<<dim3(9,HH,BB), blk, 0, stream>>>(qsh, qsl, ksh, ksl, vsh, vsl, t1b_h, t1b_l);
        bgemm<64, EPI_F32><<<dim3(8,65), blk, 0, stream>>>(
            t1b_h, t1b_l, woT_h + (size_t)i*262144, woT_l + (size_t)i*262144,
            bo + i*512, og, nullptr, nullptr,
            nullptr, nullptr, nullptr, nullptr, BT, 512, 512);
        ln_k<<<BT, blk, 0, stream>>>(h, og, ln1w + i*512, ln1b + i*512, h, hb_h, hb_l);
        bgemm<128, EPI_GELU|EPI_BF16><<<dim3(16,65), blk, 0, stream>>>(
            hb_h, hb_l, wff1T_h + (size_t)i*1048576, wff1T_l + (size_t)i*1048576,
            bff1 + i*DFFN, nullptr, midb_h, midb_l,
            nullptr, nullptr, nullptr, nullptr, BT, DFFN, 512);
        bgemm<64, EPI_F32><<<dim3(8,65), blk, 0, stream>>>(
            midb_h, midb_l, wff2T_h + (size_t)i*1048576, wff2T_l + (size_t)i*1048576,
            bff2 + i*512, og, nullptr, nullptr,
            nullptr, nullptr, nullptr, nullptr, BT, 512, DFFN);
        ln_k<<<BT, blk, 0, stream>>>(h, og, ln2w + i*512, ln2b + i*512, h, hb_h, hb_l);
    }

    ln_k<<<BT, blk, 0, stream>>>(h, nullptr, lnfw, lnfb, h, hb_h, hb_l);

    bgemm<64, EPI_PREDT><<<dim3(6,65), blk, 0, stream>>>(
        hb_h, hb_l, wprjT_h, wprjT_l, bproj, pred, nullptr, nullptr,
        nullptr, nullptr, nullptr, nullptr, BT, PP, 512);

    sims_k<<<dim3(33,SKC), blk, 0, stream>>>(pred, bank, dotp, nrmp);
    norms_k<<<dim3(3), blk, 0, stream>>>(nrmp, invn);
    simsfin_k<<<dim3(33), blk, 0, stream>>>(dotp, invn, sims);
    topk_k<<<dim3(BB), dim3(64), 0, stream>>>(sims, idxp);
    fuse_k<<<dim3((BB*PN/4)/256), blk, 0, stream>>>(pred, bank, idxp, out);
}

// Round 7
// 1185.107 us; speedup vs baseline: 1.0317x; 1.0317x over previous
//
#include <hip/hip_runtime.h>
#include <stdint.h>
#include <math.h>

#define TT 516
#define BB 16
#define DD 512
#define LL 512
#define NN 512
#define HH 8
#define DHD 64
#define DFFN 2048
#define PP 336
#define MM 512
#define KNN 10
#define BT (BB*TT)      /* 8256 */
#define PN (PP*NN)      /* 172032 */
#define SKC 32          /* sims k-chunks */
#define SCHUNK (PN/SKC) /* 5376 */
#define SSTG (SCHUNK/256) /* 21 stages */
#define VSTR 528        /* transposed-V row stride (uint16 elems) */

using f32x4  = __attribute__((ext_vector_type(4))) float;
using bf16x8 = __attribute__((ext_vector_type(8))) __bf16;
using u16x8  = __attribute__((ext_vector_type(8))) unsigned short;

__device__ __forceinline__ float gelu_tanh(float x){
    float x3 = x*x*x;
    return 0.5f*x*(1.0f + tanhf(0.7978845608028654f*(x + 0.044715f*x3)));
}

__device__ __forceinline__ uint16_t f2bf(float x){
    uint32_t u = __builtin_bit_cast(uint32_t, x);
    uint32_t r = (u + 0x7FFFu + ((u >> 16) & 1u)) >> 16;
    return (uint16_t)r;
}

__device__ __forceinline__ void split_bf(float x, uint16_t& hi, uint16_t& lo){
    uint32_t u  = __builtin_bit_cast(uint32_t, x);
    uint32_t hr = (u + 0x7FFFu + ((u >> 16) & 1u)) & 0xFFFF0000u;
    float hf = __builtin_bit_cast(float, hr);
    hi = (uint16_t)(hr >> 16);
    lo = f2bf(x - hf);
}

__device__ __forceinline__ void gl16(const uint16_t* g, uint16_t* l){
    __builtin_amdgcn_global_load_lds(
        (const __attribute__((address_space(1))) unsigned int*)(const void*)g,
        (__attribute__((address_space(3))) unsigned int*)(void*)l, 16, 0, 0);
}

__device__ __forceinline__ bf16x8 ldb8(const uint16_t* p){
    return __builtin_bit_cast(bf16x8, *(const u16x8*)p);
}

#define EPI_F32   1
#define EPI_BF16  2
#define EPI_GELU  4
#define EPI_PREDT 8
#define EPI_QKV   16

// ---------------------------------------------------------------------------
// Split-bf16 MFMA GEMM (round-5 structure: single-buffer, __syncthreads;
// 2-phase dbuf experiment REGRESSED in round 6 — reverted)
// ---------------------------------------------------------------------------
template<int BN, int FLAGS>
__global__ __launch_bounds__(256)
void bgemm(const uint16_t* __restrict__ Ah, const uint16_t* __restrict__ Al,
           const uint16_t* __restrict__ Bh, const uint16_t* __restrict__ Bl,
           const float* __restrict__ bias, float* __restrict__ Cf,
           uint16_t* __restrict__ Cbh, uint16_t* __restrict__ Cbl,
           uint16_t* __restrict__ Xkh, uint16_t* __restrict__ Xkl,
           uint16_t* __restrict__ Xvh, uint16_t* __restrict__ Xvl,
           int Msz, int Nsz, int Ksz)
{
    constexpr int FN = BN/32;
    __shared__ uint16_t As0[4096], As1[4096];
    __shared__ uint16_t Bs0[BN*32], Bs1[BN*32];

    const int tid  = threadIdx.x;
    const int lane = tid & 63;
    const int wu   = __builtin_amdgcn_readfirstlane(tid >> 6);
    const int wm   = wu >> 1, wn = wu & 1;
    const int m0   = blockIdx.y * 128;
    const int n0   = blockIdx.x * BN;

    const int r0c = tid >> 2;
    const int cc  = tid & 3;
    const int sw  = (r0c ^ (r0c >> 2)) & 3;
    const int csw = (cc ^ sw) * 8;
    int rA0 = m0 + r0c;      if (rA0 > Msz-1) rA0 = Msz-1;
    int rA1 = m0 + r0c + 64; if (rA1 > Msz-1) rA1 = Msz-1;
    int rB0 = n0 + r0c;      if (rB0 > Nsz-1) rB0 = Nsz-1;
    int rB1 = n0 + r0c + 64; if (rB1 > Nsz-1) rB1 = Nsz-1;
    const uint16_t* pAh0 = Ah + (size_t)rA0*Ksz + csw;
    const uint16_t* pAh1 = Ah + (size_t)rA1*Ksz + csw;
    const uint16_t* pAl0 = Al + (size_t)rA0*Ksz + csw;
    const uint16_t* pAl1 = Al + (size_t)rA1*Ksz + csw;
    const uint16_t* pBh0 = Bh + (size_t)rB0*Ksz + csw;
    const uint16_t* pBh1 = Bh + (size_t)rB1*Ksz + csw;
    const uint16_t* pBl0 = Bl + (size_t)rB0*Ksz + csw;
    const uint16_t* pBl1 = Bl + (size_t)rB1*Ksz + csw;

    f32x4 acc[4][FN];
#pragma unroll
    for (int i=0;i<4;i++)
#pragma unroll
        for (int j=0;j<FN;j++) acc[i][j] = (f32x4){0.f,0.f,0.f,0.f};

    const int lc16  = lane & 15;
    const int slot8 = (((lane>>4) ^ (lane&3) ^ ((lane>>2)&3))) * 8;
    const int rAf   = (wm*64 + lc16) * 32 + slot8;
    const int rBf   = (wn*(BN/2) + lc16) * 32 + slot8;

    for (int kt = 0; kt < Ksz; kt += 32){
        gl16(pAh0 + kt, &As0[wu*512]);
        gl16(pAh1 + kt, &As0[2048 + wu*512]);
        gl16(pAl0 + kt, &As1[wu*512]);
        gl16(pAl1 + kt, &As1[2048 + wu*512]);
        if (BN == 128){
            gl16(pBh0 + kt, &Bs0[wu*512]);
            gl16(pBh1 + kt, &Bs0[2048 + wu*512]);
            gl16(pBl0 + kt, &Bs1[wu*512]);
            gl16(pBl1 + kt, &Bs1[2048 + wu*512]);
        } else {
            gl16(pBh0 + kt, &Bs0[wu*512]);
            gl16(pBl0 + kt, &Bs1[wu*512]);
        }
        __syncthreads();

        bf16x8 ah[4], al[4];
#pragma unroll
        for (int fm=0; fm<4; fm++){
            ah[fm] = ldb8(&As0[rAf + fm*512]);
            al[fm] = ldb8(&As1[rAf + fm*512]);
        }
#pragma unroll
        for (int fn=0; fn<FN; fn++){
            bf16x8 bh = ldb8(&Bs0[rBf + fn*512]);
            bf16x8 bl = ldb8(&Bs1[rBf + fn*512]);
#pragma unroll
            for (int fm=0; fm<4; fm++){
                acc[fm][fn] = __builtin_amdgcn_mfma_f32_16x16x32_bf16(ah[fm], bh, acc[fm][fn], 0,0,0);
                acc[fm][fn] = __builtin_amdgcn_mfma_f32_16x16x32_bf16(ah[fm], bl, acc[fm][fn], 0,0,0);
                acc[fm][fn] = __builtin_amdgcn_mfma_f32_16x16x32_bf16(al[fm], bh, acc[fm][fn], 0,0,0);
            }
        }
        __syncthreads();
    }

    const int lr4 = (lane >> 4) * 4;
#pragma unroll
    for (int fm=0; fm<4; fm++){
        const int rbase = m0 + wm*64 + fm*16 + lr4;
#pragma unroll
        for (int fn=0; fn<FN; fn++){
            const int col = n0 + wn*(BN/2) + fn*16 + lc16;
            f32x4 v = acc[fm][fn];
            if (FLAGS & EPI_PREDT){
#pragma unroll
                for (int r=0;r<4;r++){
                    int row = rbase + r;
                    if (row < Msz && col < PP){
                        int b = row / TT, t = row - b*TT;
                        if (t < NN)
                            Cf[((size_t)b*PP + col)*NN + t] = v[r] + bias[col];
                    }
                }
            } else if (FLAGS & EPI_QKV){
                const int g   = col >> 9;
                const int cc2 = col & 511;
                const int hh2 = cc2 >> 6, dd2 = cc2 & 63;
                const float bcol = bias[col];
#pragma unroll
                for (int r=0;r<4;r++){
                    int row = rbase + r;
                    if (row < Msz){
                        float x = v[r] + bcol;
                        int b2 = row / TT, t2 = row - b2*TT;
                        int bh2 = b2*HH + hh2;
                        uint16_t hi, lo; split_bf(x, hi, lo);
                        if (g == 0){
                            size_t o = ((size_t)bh2*TT + t2)*64 + dd2;
                            Cbh[o] = hi; Cbl[o] = lo;
                        } else if (g == 1){
                            size_t o = ((size_t)bh2*TT + t2)*64 + dd2;
                            Xkh[o] = hi; Xkl[o] = lo;
                        } else {
                            size_t o = ((size_t)bh2*64 + dd2)*VSTR + t2;
                            Xvh[o] = hi; Xvl[o] = lo;
                        }
                    }
                }
            } else {
                const float bcol = bias[col];
#pragma unroll
                for (int r=0;r<4;r++){
                    int row = rbase + r;
                    if (row < Msz){
                        float x = v[r] + bcol;
                        if (FLAGS & EPI_GELU) x = gelu_tanh(x);
                        if (FLAGS & EPI_F32) Cf[(size_t)row*Nsz + col] = x;
                        if (FLAGS & EPI_BF16){
                            uint16_t hi, lo; split_bf(x, hi, lo);
                            Cbh[(size_t)row*Nsz + col] = hi;
                            Cbl[(size_t)row*Nsz + col] = lo;
                        }
                    }
                }
            }
        }
    }
}

// ---------------------------------------------------------------------------
// tok transpose + split (unchanged)
// ---------------------------------------------------------------------------
__global__ __launch_bounds__(256)
void tok_k(const float* __restrict__ xe, const float* __restrict__ xm,
           uint16_t* __restrict__ th, uint16_t* __restrict__ tl)
{
    const int b = blockIdx.z;
    const int t0 = blockIdx.x*32, l0 = blockIdx.y*32;
    __shared__ float tile[32][33];
    const int i = threadIdx.x >> 3;
    const int j4 = (threadIdx.x & 7) * 4;
#pragma unroll
    for (int c=0;c<4;c++){
        int t = t0 + j4 + c;
        float v = 0.0f;
        if (t < 512)      v = xe[((size_t)b*LL + l0+i)*NN + t];
        else if (t < 516) v = xm[((size_t)b*LL + l0+i)*4 + (t-512)];
        tile[i][j4+c] = v;
    }
    __syncthreads();
    int t = t0 + i;
    if (t < TT){
#pragma unroll
        for (int c=0;c<4;c++){
            uint16_t hi, lo; split_bf(tile[j4+c][i], hi, lo);
            size_t idx = ((size_t)b*TT + t)*512 + l0 + j4 + c;
            th[idx] = hi; tl[idx] = lo;
        }
    }
}

// ---------------------------------------------------------------------------
// weight transpose-split (unchanged)
// ---------------------------------------------------------------------------
__global__ __launch_bounds__(256)
void wtr_k(const float* __restrict__ src, uint16_t* __restrict__ dh,
           uint16_t* __restrict__ dl, int Ksz, int Nsz, size_t zstride)
{
    const int z = blockIdx.z;
    src += (size_t)z*Ksz*Nsz; dh += (size_t)z*zstride; dl += (size_t)z*zstride;
    __shared__ float tile[32][33];
    const int kt = blockIdx.y*32, nt = blockIdx.x*32;
    const int i = threadIdx.x >> 3;
    const int j4 = (threadIdx.x & 7) * 4;
#pragma unroll
    for (int c=0;c<4;c++){
        int n = nt + j4 + c;
        tile[i][j4+c] = (n < Nsz) ? src[(size_t)(kt+i)*Nsz + n] : 0.0f;
    }
    __syncthreads();
    int n = nt + i;
    if (n < Nsz){
#pragma unroll
        for (int c=0;c<4;c++){
            uint16_t hi, lo; split_bf(tile[j4+c][i], hi, lo);
            size_t idx = (size_t)n*Ksz + kt + j4 + c;
            dh[idx] = hi; dl[idx] = lo;
        }
    }
}

__global__ void catb_k(const float* __restrict__ bq, const float* __restrict__ bk,
                       const float* __restrict__ bv, float* __restrict__ dst){
    int j = blockIdx.x*256 + threadIdx.x;
    if (j >= 3072) return;
    int layer = j / 1536, r = j - layer*1536;
    float v;
    if (r < 512)       v = bq[layer*512 + r];
    else if (r < 1024) v = bk[layer*512 + r - 512];
    else               v = bv[layer*512 + r - 1024];
    dst[j] = v;
}

// ---------------------------------------------------------------------------
// MFMA flash attention (unchanged)
// ---------------------------------------------------------------------------
__global__ __launch_bounds__(256, 2)
void attnm_k(const uint16_t* __restrict__ qh, const uint16_t* __restrict__ ql,
             const uint16_t* __restrict__ kh, const uint16_t* __restrict__ kl,
             const uint16_t* __restrict__ vth, const uint16_t* __restrict__ vtl,
             uint16_t* __restrict__ oh, uint16_t* __restrict__ ol)
{
    const int qt = blockIdx.x;
    const int h  = blockIdx.y;
    const int b  = blockIdx.z;
    const int bh = b*HH + h;
    const int q0 = qt*64;
    const int tid  = threadIdx.x;
    const int lane = tid & 63;
    const int wu   = __builtin_amdgcn_readfirstlane(tid >> 6);
    const int mrow = lane & 15;
    const int kgrp = lane >> 4;

    __shared__ uint16_t Khs[4096], Kls[4096];
    __shared__ uint16_t Vhs[4096], Vls[4096];
    __shared__ uint16_t Phs[4096], Pls[4096];

    int tq = q0 + wu*16 + mrow; if (tq > TT-1) tq = TT-1;
    const uint16_t* qbase = qh + ((size_t)bh*TT + tq)*64 + kgrp*8;
    const uint16_t* qbasl = ql + ((size_t)bh*TT + tq)*64 + kgrp*8;
    bf16x8 qfh[2], qfl[2];
    qfh[0] = ldb8(qbase);      qfh[1] = ldb8(qbase + 32);
    qfl[0] = ldb8(qbasl);      qfl[1] = ldb8(qbasl + 32);

    const int srw = lane >> 3;
    const int sg  = lane & 7;

    f32x4 oacc[4];
#pragma unroll
    for (int f=0;f<4;f++) oacc[f] = (f32x4){0.f,0.f,0.f,0.f};
    float m_r[4] = {-1e30f,-1e30f,-1e30f,-1e30f};
    float l_r[4] = {0.f,0.f,0.f,0.f};

    for (int st=0; st<9; ++st){
        const int s0 = st*64;
        __syncthreads();
#pragma unroll
        for (int c=0;c<2;c++){
            const int r   = wu*16 + c*8 + srw;
            const int gsl = sg ^ (r & 7);
            int sk = s0 + r; if (sk > TT-1) sk = TT-1;
            const uint16_t* ksh_ = kh  + ((size_t)bh*TT + sk)*64 + gsl*8;
            const uint16_t* ksl_ = kl  + ((size_t)bh*TT + sk)*64 + gsl*8;
            int cb = s0 + gsl*8; if (cb > VSTR-8) cb = VSTR-8;
            const uint16_t* vsh_ = vth + ((size_t)bh*64 + r)*VSTR + cb;
            const uint16_t* vsl_ = vtl + ((size_t)bh*64 + r)*VSTR + cb;
            gl16(ksh_, &Khs[(wu*16 + c*8)*64]);
            gl16(ksl_, &Kls[(wu*16 + c*8)*64]);
            gl16(vsh_, &Vhs[(wu*16 + c*8)*64]);
            gl16(vsl_, &Vls[(wu*16 + c*8)*64]);
        }
        __syncthreads();

        f32x4 sacc[4];
#pragma unroll
        for (int f=0;f<4;f++) sacc[f] = (f32x4){0.f,0.f,0.f,0.f};
#pragma unroll
        for (int ks=0; ks<2; ks++){
#pragma unroll
            for (int f=0; f<4; f++){
                const int sr = f*16 + mrow;
                const int sl = ((ks*4 + kgrp) ^ (sr & 7))*8;
                bf16x8 kbh = ldb8(&Khs[sr*64 + sl]);
                bf16x8 kbl = ldb8(&Kls[sr*64 + sl]);
                sacc[f] = __builtin_amdgcn_mfma_f32_16x16x32_bf16(qfh[ks], kbh, sacc[f], 0,0,0);
                sacc[f] = __builtin_amdgcn_mfma_f32_16x16x32_bf16(qfh[ks], kbl, sacc[f], 0,0,0);
                sacc[f] = __builtin_amdgcn_mfma_f32_16x16x32_bf16(qfl[ks], kbh, sacc[f], 0,0,0);
            }
        }

        float alpha[4];
#pragma unroll
        for (int r=0;r<4;r++){
            float mx = -1e30f;
#pragma unroll
            for (int f=0;f<4;f++){
                float sv = sacc[f][r]*0.125f;
                if (s0 + f*16 + mrow >= TT) sv = -1e30f;
                sacc[f][r] = sv;
                mx = fmaxf(mx, sv);
            }
#pragma unroll
            for (int msk=1; msk<16; msk<<=1) mx = fmaxf(mx, __shfl_xor(mx, msk));
            float mn = fmaxf(m_r[r], mx);
            alpha[r] = __expf(m_r[r] - mn);
            m_r[r] = mn;
            float rs = 0.0f;
#pragma unroll
            for (int f=0;f<4;f++){
                float e = __expf(sacc[f][r] - mn);
                sacc[f][r] = e;
                rs += e;
            }
#pragma unroll
            for (int msk=1; msk<16; msk<<=1) rs += __shfl_xor(rs, msk);
            l_r[r] = l_r[r]*alpha[r] + rs;
#pragma unroll
            for (int f=0;f<4;f++) oacc[f][r] *= alpha[r];
        }

#pragma unroll
        for (int r=0;r<4;r++){
            const int tr = wu*16 + kgrp*4 + r;
#pragma unroll
            for (int f=0;f<4;f++){
                const int c = f*16 + mrow;
                const int idx = tr*64 + ((c>>3) ^ (tr&7))*8 + (c&7);
                uint16_t hi, lo; split_bf(sacc[f][r], hi, lo);
                Phs[idx] = hi; Pls[idx] = lo;
            }
        }

#pragma unroll
        for (int ks=0; ks<2; ks++){
            const int trr = wu*16 + mrow;
            const int psl = ((ks*4 + kgrp) ^ (trr & 7))*8;
            bf16x8 pah = ldb8(&Phs[trr*64 + psl]);
            bf16x8 pal = ldb8(&Pls[trr*64 + psl]);
#pragma unroll
            for (int f=0; f<4; f++){
                const int dr = f*16 + mrow;
                const int vsl = ((ks*4 + kgrp) ^ (dr & 7))*8;
                bf16x8 vbh = ldb8(&Vhs[dr*64 + vsl]);
                bf16x8 vbl = ldb8(&Vls[dr*64 + vsl]);
                oacc[f] = __builtin_amdgcn_mfma_f32_16x16x32_bf16(pah, vbh, oacc[f], 0,0,0);
                oacc[f] = __builtin_amdgcn_mfma_f32_16x16x32_bf16(pah, vbl, oacc[f], 0,0,0);
                oacc[f] = __builtin_amdgcn_mfma_f32_16x16x32_bf16(pal, vbh, oacc[f], 0,0,0);
            }
        }
    }

#pragma unroll
    for (int r=0;r<4;r++){
        const int t = q0 + wu*16 + kgrp*4 + r;
        if (t < TT){
            const float inv = 1.0f / l_r[r];
#pragma unroll
            for (int f=0;f<4;f++){
                const int d = f*16 + mrow;
                uint16_t hi, lo; split_bf(oacc[f][r]*inv, hi, lo);
                size_t o = ((size_t)(b*TT + t))*DD + h*DHD + d;
                oh[o] = hi; ol[o] = lo;
            }
        }
    }
}

// ---------------------------------------------------------------------------
// Residual + LayerNorm (unchanged)
// ---------------------------------------------------------------------------
__global__ __launch_bounds__(256)
void ln_k(const float* __restrict__ src, const float* __restrict__ res,
          const float* __restrict__ w, const float* __restrict__ bia,
          float* __restrict__ dst, uint16_t* __restrict__ dbh,
          uint16_t* __restrict__ dbl)
{
    const int r = blockIdx.x;
    const int tid = threadIdx.x;
    const float* sp = src + (size_t)r*DD;
    float x0 = sp[tid], x1 = sp[tid + 256];
    if (res){
        x0 += res[(size_t)r*DD + tid];
        x1 += res[(size_t)r*DD + tid + 256];
    }
    float s  = x0 + x1;
    float sq = x0*x0 + x1*x1;
#pragma unroll
    for (int msk=1; msk<64; msk<<=1){
        s  += __shfl_xor(s,  msk);
        sq += __shfl_xor(sq, msk);
    }
    __shared__ float sm[8];
    int wv = tid >> 6, ln = tid & 63;
    if (ln == 0){ sm[wv] = s; sm[wv+4] = sq; }
    __syncthreads();
    s  = sm[0]+sm[1]+sm[2]+sm[3];
    sq = sm[4]+sm[5]+sm[6]+sm[7];
    float mu  = s * (1.0f/512.0f);
    float var = sq * (1.0f/512.0f) - mu*mu;
    float rsd = rsqrtf(var + 1e-5f);
    float y0 = (x0 - mu)*rsd*w[tid]       + bia[tid];
    float y1 = (x1 - mu)*rsd*w[tid + 256] + bia[tid + 256];
    dst[(size_t)r*DD + tid]       = y0;
    dst[(size_t)r*DD + tid + 256] = y1;
    uint16_t hi, lo;
    split_bf(y0, hi, lo); dbh[(size_t)r*DD + tid] = hi;       dbl[(size_t)r*DD + tid] = lo;
    split_bf(y1, hi, lo); dbh[(size_t)r*DD + tid + 256] = hi; dbl[(size_t)r*DD + tid + 256] = lo;
}

// ---------------------------------------------------------------------------
// sims v3: q-blocked 2x — each thread owns queries (qq, qq+8) over an 8-elem
// slice, so each bank ds_read_b128 feeds 8 MACs (was 4). LDS-issue halves.
// Deterministic shuffle + LDS reduction.
// ---------------------------------------------------------------------------
__global__ __launch_bounds__(256, 2)
void sims_k(const float* __restrict__ pred, const float* __restrict__ bank,
            float* __restrict__ dotp, float* __restrict__ nrmp)
{
    const int jt = blockIdx.x, kt = blockIdx.y;
    const int tid  = threadIdx.x;
    const int qq    = tid & 7;       // handles queries qq and qq+8
    const int slice = tid >> 3;      // 0..31, 8-elem slice of each 256-stage
    const int sb    = slice*8;
    const int srow  = tid >> 4;      // staging row 0..15
    const int tau   = tid & 15;

    __shared__ float BS[16*264];     // bank tile, stride 264 floats

    const int jr = jt*16 + srow;
    const float* bsrc = (jr < MM) ? (bank + (size_t)jr*PN)
                                  : (pred + (size_t)(jr - MM)*PN);
    bsrc += (size_t)kt*SCHUNK + tau*4;
    const float* p0 = pred + (size_t)qq*PN      + (size_t)kt*SCHUNK + sb;
    const float* p1 = pred + (size_t)(qq+8)*PN  + (size_t)kt*SCHUNK + sb;

    float acc0[16], acc1[16];
#pragma unroll
    for (int j=0;j<16;j++){ acc0[j] = 0.0f; acc1[j] = 0.0f; }
    float nr = 0.0f;

    for (int st=0; st<SSTG; ++st){
        float4 blv[4];
#pragma unroll
        for (int c=0;c<4;c++) blv[c] = *(const float4*)(bsrc + c*64);
        float4 pr0[2], pr1[2];
        pr0[0] = *(const float4*)(p0);     pr0[1] = *(const float4*)(p0 + 4);
        pr1[0] = *(const float4*)(p1);     pr1[1] = *(const float4*)(p1 + 4);
        __syncthreads();   // previous stage's compute done before overwrite
#pragma unroll
        for (int c=0;c<4;c++){
            *(float4*)&BS[srow*264 + tau*4 + c*64] = blv[c];
            nr = fmaf(blv[c].x, blv[c].x, nr);
            nr = fmaf(blv[c].y, blv[c].y, nr);
            nr = fmaf(blv[c].z, blv[c].z, nr);
            nr = fmaf(blv[c].w, blv[c].w, nr);
        }
        __syncthreads();
#pragma unroll
        for (int j=0;j<16;j++){
            float4 b0 = *(const float4*)&BS[j*264 + sb];
            float4 b1 = *(const float4*)&BS[j*264 + sb + 4];
            float a0 = acc0[j], a1 = acc1[j];
            a0 = fmaf(b0.x, pr0[0].x, a0); a0 = fmaf(b0.y, pr0[0].y, a0);
            a0 = fmaf(b0.z, pr0[0].z, a0); a0 = fmaf(b0.w, pr0[0].w, a0);
            a0 = fmaf(b1.x, pr0[1].x, a0); a0 = fmaf(b1.y, pr0[1].y, a0);
            a0 = fmaf(b1.z, pr0[1].z, a0); a0 = fmaf(b1.w, pr0[1].w, a0);
            a1 = fmaf(b0.x, pr1[0].x, a1); a1 = fmaf(b0.y, pr1[0].y, a1);
            a1 = fmaf(b0.z, pr1[0].z, a1); a1 = fmaf(b0.w, pr1[0].w, a1);
            a1 = fmaf(b1.x, pr1[1].x, a1); a1 = fmaf(b1.y, pr1[1].y, a1);
            a1 = fmaf(b1.z, pr1[1].z, a1); a1 = fmaf(b1.w, pr1[1].w, a1);
            acc0[j] = a0; acc1[j] = a1;
        }
        bsrc += 256; p0 += 256; p1 += 256;
    }

    // ---- reduce: within-wave over slice bits (masks 8/16/32 keep qq) ----
#pragma unroll
    for (int m=8; m<64; m<<=1){
#pragma unroll
        for (int j=0;j<16;j++){
            acc0[j] += __shfl_xor(acc0[j], m);
            acc1[j] += __shfl_xor(acc1[j], m);
        }
    }
    // norm reduce over the 16 tau lanes of each staging row
#pragma unroll
    for (int m=1;m<16;m<<=1) nr += __shfl_xor(nr, m);

    __syncthreads();
    float* RED = BS;                 // [wave4][j16][q16] = 1024 floats
    const int wu2  = tid >> 6;
    const int lane = tid & 63;
    if (lane < 8){
#pragma unroll
        for (int j=0;j<16;j++){
            RED[(wu2*16 + j)*16 + lane]     = acc0[j];
            RED[(wu2*16 + j)*16 + lane + 8] = acc1[j];
        }
    }
    __syncthreads();
    const int j2 = tid >> 4, q2 = tid & 15;
    float s = RED[(0*16 + j2)*16 + q2] + RED[(1*16 + j2)*16 + q2]
            + RED[(2*16 + j2)*16 + q2] + RED[(3*16 + j2)*16 + q2];
    dotp[((size_t)kt*528 + jt*16 + j2)*16 + q2] = s;
    if (tau == 0) nrmp[kt*528 + jt*16 + srow] = nr;
}

__global__ void norms_k(const float* __restrict__ nrmp, float* __restrict__ invn){
    int j = blockIdx.x*blockDim.x + threadIdx.x;
    if (j < 528){
        float s = 0.0f;
        for (int kt=0; kt<SKC; kt++) s += nrmp[kt*528 + j];
        invn[j] = 1.0f/(sqrtf(s) + 1e-8f);
    }
}

__global__ void simsfin_k(const float* __restrict__ dotp, const float* __restrict__ invn,
                          float* __restrict__ sims){
    int fid = blockIdx.x*256 + threadIdx.x;
    int j = fid >> 4, q = fid & 15;
    float s = 0.0f;
    for (int kt=0; kt<SKC; kt++) s += dotp[((size_t)kt*528 + j)*16 + q];
    sims[q*528 + j] = s * invn[j] * invn[MM + q];
}

__global__ __launch_bounds__(64)
void topk_k(const float* __restrict__ sims, int* __restrict__ idx){
    const int q = blockIdx.x;
    const int lane = threadIdx.x;
    __shared__ float vals[528];
    for (int j=lane; j<528; j+=64) vals[j] = sims[q*528 + j];
    __syncthreads();
    for (int kk=0; kk<KNN; kk++){
        float bv = -3.0e38f; int bi = 1<<30;
        for (int j=lane; j<528; j+=64){
            float v2 = vals[j];
            if (v2 > bv || (v2 == bv && j < bi)){ bv = v2; bi = j; }
        }
#pragma unroll
        for (int msk=1; msk<64; msk<<=1){
            float ov = __shfl_xor(bv, msk);
            int   oi = __shfl_xor(bi, msk);
            if (ov > bv || (ov == bv && oi < bi)){ bv = ov; bi = oi; }
        }
        if (lane == 0){
            idx[q*KNN + kk] = bi;
            vals[bi] = -3.0e38f;
        }
        __syncthreads();
    }
}

__global__ __launch_bounds__(256)
void fuse_k(const float* __restrict__ pred, const float* __restrict__ bank,
            const int* __restrict__ idx, float* __restrict__ out){
    int u = blockIdx.x*256 + threadIdx.x;
    int b = u / (PN/4);
    int e = (u - b*(PN/4)) * 4;
    int id[KNN];
#pragma unroll
    for (int k2=0;k2<KNN;k2++) id[k2] = idx[b*KNN + k2];
    float4 pv = *(const float4*)(pred + (size_t)b*PN + e);
    float ax = 0.5f*pv.x, ay = 0.5f*pv.y, az = 0.5f*pv.z, aw = 0.5f*pv.w;
#pragma unroll
    for (int k2=0;k2<KNN;k2++){
        const float* rp = (id[k2] < MM) ? (bank + (size_t)id[k2]*PN)
                                        : (pred + (size_t)(id[k2]-MM)*PN);
        float4 rv = *(const float4*)(rp + e);
        ax = fmaf(0.05f, rv.x, ax); ay = fmaf(0.05f, rv.y, ay);
        az = fmaf(0.05f, rv.z, az); aw = fmaf(0.05f, rv.w, aw);
    }
    float4 ov; ov.x=ax; ov.y=ay; ov.z=az; ov.w=aw;
    *(float4*)(out + (size_t)b*PN + e) = ov;
}

// ---------------------------------------------------------------------------
extern "C" void kernel_launch(void* const* d_in, const int* in_sizes, int n_in,
                              void* d_out, int out_size, void* d_ws, size_t ws_size,
                              hipStream_t stream)
{
    (void)in_sizes; (void)n_in; (void)out_size; (void)ws_size;
    const float* x_enc  = (const float*)d_in[0];
    const float* x_mark = (const float*)d_in[1];
    const float* W_emb  = (const float*)d_in[4];
    const float* b_emb  = (const float*)d_in[5];
    const float* Wq  = (const float*)d_in[6];
    const float* Wk  = (const float*)d_in[7];
    const float* Wv  = (const float*)d_in[8];
    const float* Wo  = (const float*)d_in[9];
    const float* bq  = (const float*)d_in[10];
    const float* bk  = (const float*)d_in[11];
    const float* bv_ = (const float*)d_in[12];
    const float* bo  = (const float*)d_in[13];
    const float* ln1w = (const float*)d_in[14];
    const float* ln1b = (const float*)d_in[15];
    const float* ln2w = (const float*)d_in[16];
    const float* ln2b = (const float*)d_in[17];
    const float* Wff1 = (const float*)d_in[18];
    const float* bff1 = (const float*)d_in[19];
    const float* Wff2 = (const float*)d_in[20];
    const float* bff2 = (const float*)d_in[21];
    const float* lnfw = (const float*)d_in[22];
    const float* lnfb = (const float*)d_in[23];
    const float* Wproj = (const float*)d_in[24];
    const float* bproj = (const float*)d_in[25];
    const float* bank  = (const float*)d_in[26];
    float* out = (float*)d_out;

    char* pp = (char*)d_ws;
    auto a16 = [&](size_t elems)->uint16_t*{ uint16_t* r=(uint16_t*)pp; pp += ((elems*2 + 255)/256)*256; return r; };
    auto af  = [&](size_t elems)->float*  { float* r=(float*)pp;  pp += ((elems*4 + 255)/256)*256; return r; };

    uint16_t* wembT_h = a16(262144);        uint16_t* wembT_l = a16(262144);
    uint16_t* wqkvT_h = a16(2*1536*512);    uint16_t* wqkvT_l = a16(2*1536*512);
    uint16_t* woT_h   = a16(2*262144);      uint16_t* woT_l   = a16(2*262144);
    uint16_t* wff1T_h = a16(2*2048*512);    uint16_t* wff1T_l = a16(2*2048*512);
    uint16_t* wff2T_h = a16(2*512*2048);    uint16_t* wff2T_l = a16(2*512*2048);
    uint16_t* wprjT_h = a16(172032);        uint16_t* wprjT_l = a16(172032);
    float*    bqkv    = af(3072);
    uint16_t* hb_h    = a16((size_t)BT*512);
    uint16_t* hb_l    = a16((size_t)BT*512);
    uint16_t* tok_h   = a16((size_t)BT*512);     // og fp32 aliases tok region
    uint16_t* tok_l   = a16((size_t)BT*512);
    float*    og      = (float*)tok_h;
    uint16_t* qsh     = a16((size_t)128*TT*64);
    uint16_t* qsl     = a16((size_t)128*TT*64);
    uint16_t* ksh     = a16((size_t)128*TT*64);
    uint16_t* ksl     = a16((size_t)128*TT*64);
    uint16_t* vsh     = a16((size_t)128*64*VSTR + 4096);
    uint16_t* vsl     = a16((size_t)128*64*VSTR + 4096);
    uint16_t* t1b_h   = a16((size_t)BT*512);
    uint16_t* t1b_l   = a16((size_t)BT*512);
    uint16_t* midb_h  = qsh;                     // mid aliases qsh..t1b region
    uint16_t* midb_l  = midb_h + (size_t)BT*2048;
    float*    h       = af((size_t)BT*512);
    float*    pred    = af((size_t)BB*PN);
    float*    dotp    = af((size_t)SKC*528*16);
    float*    nrmp    = af(SKC*528);
    float*    invn    = af(528);
    float*    sims    = af(16*528);
    int*      idxp    = (int*)af(256);

    dim3 blk(256);

    tok_k<<<dim3(17,16,BB), blk, 0, stream>>>(x_enc, x_mark, tok_h, tok_l);
    wtr_k<<<dim3(16,16,1), blk, 0, stream>>>(W_emb, wembT_h, wembT_l, 512, 512, 262144);
    wtr_k<<<dim3(16,16,2), blk, 0, stream>>>(Wq, wqkvT_h,          wqkvT_l,          512, 512, 786432);
    wtr_k<<<dim3(16,16,2), blk, 0, stream>>>(Wk, wqkvT_h + 262144, wqkvT_l + 262144, 512, 512, 786432);
    wtr_k<<<dim3(16,16,2), blk, 0, stream>>>(Wv, wqkvT_h + 524288, wqkvT_l + 524288, 512, 512, 786432);
    wtr_k<<<dim3(16,16,2), blk, 0, stream>>>(Wo, woT_h, woT_l, 512, 512, 262144);
    wtr_k<<<dim3(64,16,2), blk, 0, stream>>>(Wff1, wff1T_h, wff1T_l, 512, 2048, 1048576);
    wtr_k<<<dim3(16,64,2), blk, 0, stream>>>(Wff2, wff2T_h, wff2T_l, 2048, 512, 1048576);
    wtr_k<<<dim3(11,16,1), blk, 0, stream>>>(Wproj, wprjT_h, wprjT_l, 512, 336, 172032);
    catb_k<<<dim3(12), blk, 0, stream>>>(bq, bk, bv_, bqkv);

    bgemm<64, EPI_F32|EPI_BF16><<<dim3(8,65), blk, 0, stream>>>(
        tok_h, tok_l, wembT_h, wembT_l, b_emb, h, hb_h, hb_l,
        nullptr, nullptr, nullptr, nullptr, BT, 512, 512);

    for (int i=0;i<2;i++){
        bgemm<128, EPI_QKV><<<dim3(12,65), blk, 0, stream>>>(
            hb_h, hb_l, wqkvT_h + (size_t)i*786432, wqkvT_l + (size_t)i*786432,
            bqkv + i*1536, nullptr, qsh, qsl, ksh, ksl, vsh, vsl, BT, 1536, 512);
        attnm_k<<<dim3(9,HH,BB), blk, 0, stream>>>(qsh, qsl, ksh, ksl, vsh, vsl, t1b_h, t1b_l);
        bgemm<64, EPI_F32><<<dim3(8,65), blk, 0, stream>>>(
            t1b_h, t1b_l, woT_h + (size_t)i*262144, woT_l + (size_t)i*262144,
            bo + i*512, og, nullptr, nullptr,
            nullptr, nullptr, nullptr, nullptr, BT, 512, 512);
        ln_k<<<BT, blk, 0, stream>>>(h, og, ln1w + i*512, ln1b + i*512, h, hb_h, hb_l);
        bgemm<128, EPI_GELU|EPI_BF16><<<dim3(16,65), blk, 0, stream>>>(
            hb_h, hb_l, wff1T_h + (size_t)i*1048576, wff1T_l + (size_t)i*1048576,
            bff1 + i*DFFN, nullptr, midb_h, midb_l,
            nullptr, nullptr, nullptr, nullptr, BT, DFFN, 512);
        bgemm<64, EPI_F32><<<dim3(8,65), blk, 0, stream>>>(
            midb_h, midb_l, wff2T_h + (size_t)i*1048576, wff2T_l + (size_t)i*1048576,
            bff2 + i*512, og, nullptr, nullptr,
            nullptr, nullptr, nullptr, nullptr, BT, 512, DFFN);
        ln_k<<<BT, blk, 0, stream>>>(h, og, ln2w + i*512, ln2b + i*512, h, hb_h, hb_l);
    }

    ln_k<<<BT, blk, 0, stream>>>(h, nullptr, lnfw, lnfb, h, hb_h, hb_l);

    bgemm<64, EPI_PREDT><<<dim3(6,65), blk, 0, stream>>>(
        hb_h, hb_l, wprjT_h, wprjT_l, bproj, pred, nullptr, nullptr,
        nullptr, nullptr, nullptr, nullptr, BT, PP, 512);

    sims_k<<<dim3(33,SKC), blk, 0, stream>>>(pred, bank, dotp, nrmp);
    norms_k<<<dim3(3), blk, 0, stream>>>(nrmp, invn);
    simsfin_k<<<dim3(33), blk, 0, stream>>>(dotp, invn, sims);
    topk_k<<<dim3(BB), dim3(64), 0, stream>>>(sims, idxp);
    fuse_k<<<dim3((BB*PN/4)/256), blk, 0, stream>>>(pred, bank, idxp, out);
}

// Round 8
// 1154.878 us; speedup vs baseline: 1.0587x; 1.0262x over previous
//
#include <hip/hip_runtime.h>
#include <stdint.h>
#include <math.h>

#define TT 516
#define BB 16
#define DD 512
#define LL 512
#define NN 512
#define HH 8
#define DHD 64
#define DFFN 2048
#define PP 336
#define MM 512
#define KNN 10
#define BT (BB*TT)      /* 8256 */
#define PN (PP*NN)      /* 172032 */
#define SKC 32          /* sims k-chunks */
#define SCHUNK (PN/SKC) /* 5376 */
#define SSTG (SCHUNK/256) /* 21 stages */
#define VSTR 528        /* transposed-V row stride (uint16 elems) */

using f32x4  = __attribute__((ext_vector_type(4))) float;
using bf16x8 = __attribute__((ext_vector_type(8))) __bf16;
using u16x8  = __attribute__((ext_vector_type(8))) unsigned short;

__device__ __forceinline__ float gelu_tanh(float x){
    float x3 = x*x*x;
    return 0.5f*x*(1.0f + tanhf(0.7978845608028654f*(x + 0.044715f*x3)));
}

__device__ __forceinline__ uint16_t f2bf(float x){
    uint32_t u = __builtin_bit_cast(uint32_t, x);
    uint32_t r = (u + 0x7FFFu + ((u >> 16) & 1u)) >> 16;
    return (uint16_t)r;
}

__device__ __forceinline__ void split_bf(float x, uint16_t& hi, uint16_t& lo){
    uint32_t u  = __builtin_bit_cast(uint32_t, x);
    uint32_t hr = (u + 0x7FFFu + ((u >> 16) & 1u)) & 0xFFFF0000u;
    float hf = __builtin_bit_cast(float, hr);
    hi = (uint16_t)(hr >> 16);
    lo = f2bf(x - hf);
}

__device__ __forceinline__ void gl16(const uint16_t* g, uint16_t* l){
    __builtin_amdgcn_global_load_lds(
        (const __attribute__((address_space(1))) unsigned int*)(const void*)g,
        (__attribute__((address_space(3))) unsigned int*)(void*)l, 16, 0, 0);
}

__device__ __forceinline__ bf16x8 ldb8(const uint16_t* p){
    return __builtin_bit_cast(bf16x8, *(const u16x8*)p);
}

#define EPI_F32   1
#define EPI_BF16  2
#define EPI_GELU  4
#define EPI_PREDT 8
#define EPI_QKV   16

// ---------------------------------------------------------------------------
// Split-bf16 MFMA GEMM, BN=128, BK=32 (round-5 structure, unchanged).
// Used for QKV (N=1536) and FF1 (N=2048).
// ---------------------------------------------------------------------------
template<int FLAGS>
__global__ __launch_bounds__(256)
void bgemm(const uint16_t* __restrict__ Ah, const uint16_t* __restrict__ Al,
           const uint16_t* __restrict__ Bh, const uint16_t* __restrict__ Bl,
           const float* __restrict__ bias, float* __restrict__ Cf,
           uint16_t* __restrict__ Cbh, uint16_t* __restrict__ Cbl,
           uint16_t* __restrict__ Xkh, uint16_t* __restrict__ Xkl,
           uint16_t* __restrict__ Xvh, uint16_t* __restrict__ Xvl,
           int Msz, int Nsz, int Ksz)
{
    constexpr int BN = 128;
    constexpr int FN = 4;
    __shared__ uint16_t As0[4096], As1[4096];
    __shared__ uint16_t Bs0[BN*32], Bs1[BN*32];

    const int tid  = threadIdx.x;
    const int lane = tid & 63;
    const int wu   = __builtin_amdgcn_readfirstlane(tid >> 6);
    const int wm   = wu >> 1, wn = wu & 1;
    const int m0   = blockIdx.y * 128;
    const int n0   = blockIdx.x * BN;

    const int r0c = tid >> 2;
    const int cc  = tid & 3;
    const int sw  = (r0c ^ (r0c >> 2)) & 3;
    const int csw = (cc ^ sw) * 8;
    int rA0 = m0 + r0c;      if (rA0 > Msz-1) rA0 = Msz-1;
    int rA1 = m0 + r0c + 64; if (rA1 > Msz-1) rA1 = Msz-1;
    int rB0 = n0 + r0c;      if (rB0 > Nsz-1) rB0 = Nsz-1;
    int rB1 = n0 + r0c + 64; if (rB1 > Nsz-1) rB1 = Nsz-1;
    const uint16_t* pAh0 = Ah + (size_t)rA0*Ksz + csw;
    const uint16_t* pAh1 = Ah + (size_t)rA1*Ksz + csw;
    const uint16_t* pAl0 = Al + (size_t)rA0*Ksz + csw;
    const uint16_t* pAl1 = Al + (size_t)rA1*Ksz + csw;
    const uint16_t* pBh0 = Bh + (size_t)rB0*Ksz + csw;
    const uint16_t* pBh1 = Bh + (size_t)rB1*Ksz + csw;
    const uint16_t* pBl0 = Bl + (size_t)rB0*Ksz + csw;
    const uint16_t* pBl1 = Bl + (size_t)rB1*Ksz + csw;

    f32x4 acc[4][FN];
#pragma unroll
    for (int i=0;i<4;i++)
#pragma unroll
        for (int j=0;j<FN;j++) acc[i][j] = (f32x4){0.f,0.f,0.f,0.f};

    const int lc16  = lane & 15;
    const int slot8 = (((lane>>4) ^ (lane&3) ^ ((lane>>2)&3))) * 8;
    const int rAf   = (wm*64 + lc16) * 32 + slot8;
    const int rBf   = (wn*(BN/2) + lc16) * 32 + slot8;

    for (int kt = 0; kt < Ksz; kt += 32){
        gl16(pAh0 + kt, &As0[wu*512]);
        gl16(pAh1 + kt, &As0[2048 + wu*512]);
        gl16(pAl0 + kt, &As1[wu*512]);
        gl16(pAl1 + kt, &As1[2048 + wu*512]);
        gl16(pBh0 + kt, &Bs0[wu*512]);
        gl16(pBh1 + kt, &Bs0[2048 + wu*512]);
        gl16(pBl0 + kt, &Bs1[wu*512]);
        gl16(pBl1 + kt, &Bs1[2048 + wu*512]);
        __syncthreads();

        bf16x8 ah[4], al[4];
#pragma unroll
        for (int fm=0; fm<4; fm++){
            ah[fm] = ldb8(&As0[rAf + fm*512]);
            al[fm] = ldb8(&As1[rAf + fm*512]);
        }
#pragma unroll
        for (int fn=0; fn<FN; fn++){
            bf16x8 bh = ldb8(&Bs0[rBf + fn*512]);
            bf16x8 bl = ldb8(&Bs1[rBf + fn*512]);
#pragma unroll
            for (int fm=0; fm<4; fm++){
                acc[fm][fn] = __builtin_amdgcn_mfma_f32_16x16x32_bf16(ah[fm], bh, acc[fm][fn], 0,0,0);
                acc[fm][fn] = __builtin_amdgcn_mfma_f32_16x16x32_bf16(ah[fm], bl, acc[fm][fn], 0,0,0);
                acc[fm][fn] = __builtin_amdgcn_mfma_f32_16x16x32_bf16(al[fm], bh, acc[fm][fn], 0,0,0);
            }
        }
        __syncthreads();
    }

    const int lr4 = (lane >> 4) * 4;
#pragma unroll
    for (int fm=0; fm<4; fm++){
        const int rbase = m0 + wm*64 + fm*16 + lr4;
#pragma unroll
        for (int fn=0; fn<FN; fn++){
            const int col = n0 + wn*(BN/2) + fn*16 + lc16;
            f32x4 v = acc[fm][fn];
            if (FLAGS & EPI_QKV){
                const int g   = col >> 9;
                const int cc2 = col & 511;
                const int hh2 = cc2 >> 6, dd2 = cc2 & 63;
                const float bcol = bias[col];
#pragma unroll
                for (int r=0;r<4;r++){
                    int row = rbase + r;
                    if (row < Msz){
                        float x = v[r] + bcol;
                        int b2 = row / TT, t2 = row - b2*TT;
                        int bh2 = b2*HH + hh2;
                        uint16_t hi, lo; split_bf(x, hi, lo);
                        if (g == 0){
                            size_t o = ((size_t)bh2*TT + t2)*64 + dd2;
                            Cbh[o] = hi; Cbl[o] = lo;
                        } else if (g == 1){
                            size_t o = ((size_t)bh2*TT + t2)*64 + dd2;
                            Xkh[o] = hi; Xkl[o] = lo;
                        } else {
                            size_t o = ((size_t)bh2*64 + dd2)*VSTR + t2;
                            Xvh[o] = hi; Xvl[o] = lo;
                        }
                    }
                }
            } else {
                const float bcol = bias[col];
#pragma unroll
                for (int r=0;r<4;r++){
                    int row = rbase + r;
                    if (row < Msz){
                        float x = v[r] + bcol;
                        if (FLAGS & EPI_GELU) x = gelu_tanh(x);
                        if (FLAGS & EPI_F32) Cf[(size_t)row*Nsz + col] = x;
                        if (FLAGS & EPI_BF16){
                            uint16_t hi, lo; split_bf(x, hi, lo);
                            Cbh[(size_t)row*Nsz + col] = hi;
                            Cbl[(size_t)row*Nsz + col] = lo;
                        }
                    }
                }
            }
        }
    }
}

// ---------------------------------------------------------------------------
// NEW: BN=64, BK=64 split-bf16 GEMM — half the barrier pairs per K (48 MFMA
// per pair vs 24), 48 KB LDS -> 3 blocks/CU. Used for emb/Wo/FF2/proj.
// ---------------------------------------------------------------------------
template<int FLAGS>
__global__ __launch_bounds__(256, 3)
void bgemm64(const uint16_t* __restrict__ Ah, const uint16_t* __restrict__ Al,
             const uint16_t* __restrict__ Bh, const uint16_t* __restrict__ Bl,
             const float* __restrict__ bias, float* __restrict__ Cf,
             uint16_t* __restrict__ Cbh, uint16_t* __restrict__ Cbl,
             int Msz, int Nsz, int Ksz)
{
    __shared__ uint16_t As0[8192], As1[8192];   // 128 rows x 64 k
    __shared__ uint16_t Bs0[4096], Bs1[4096];   // 64 rows x 64 k

    const int tid  = threadIdx.x;
    const int lane = tid & 63;
    const int wu   = __builtin_amdgcn_readfirstlane(tid >> 6);
    const int wm   = wu >> 1, wn = wu & 1;
    const int m0   = blockIdx.y * 128;
    const int n0   = blockIdx.x * 64;

    // staging: each gl16 moves 512 contig elems = 8 rows x 64 k (linear LDS).
    // source k-granule pre-swizzled: LDS[r][g] <- global k-granule g^(r&7).
    const int sr8 = lane >> 3;                 // dest row within 8-row group
    const int skw = (((lane & 7) ^ sr8) * 8);  // swizzled source k-offset

    int rA[4], rB[2];
#pragma unroll
    for (int i=0;i<4;i++){
        int r = m0 + (wu*4 + i)*8 + sr8;
        rA[i] = (r > Msz-1) ? Msz-1 : r;
    }
#pragma unroll
    for (int i=0;i<2;i++){
        int r = n0 + (wu*2 + i)*8 + sr8;
        rB[i] = (r > Nsz-1) ? Nsz-1 : r;
    }

    f32x4 acc[4][2];
#pragma unroll
    for (int i=0;i<4;i++)
#pragma unroll
        for (int j=0;j<2;j++) acc[i][j] = (f32x4){0.f,0.f,0.f,0.f};

    const int lc16 = lane & 15;
    const int kgrp = lane >> 4;

    for (int kt = 0; kt < Ksz; kt += 64){
#pragma unroll
        for (int i=0;i<4;i++){
            gl16(Ah + (size_t)rA[i]*Ksz + kt + skw, &As0[(wu*4 + i)*512]);
            gl16(Al + (size_t)rA[i]*Ksz + kt + skw, &As1[(wu*4 + i)*512]);
        }
#pragma unroll
        for (int i=0;i<2;i++){
            gl16(Bh + (size_t)rB[i]*Ksz + kt + skw, &Bs0[(wu*2 + i)*512]);
            gl16(Bl + (size_t)rB[i]*Ksz + kt + skw, &Bs1[(wu*2 + i)*512]);
        }
        __syncthreads();

#pragma unroll
        for (int ks=0; ks<2; ks++){
            bf16x8 ah[4], al[4];
#pragma unroll
            for (int fm=0; fm<4; fm++){
                const int r   = wm*64 + fm*16 + lc16;
                const int off = r*64 + (((ks*4 + kgrp) ^ (r & 7))*8);
                ah[fm] = ldb8(&As0[off]);
                al[fm] = ldb8(&As1[off]);
            }
#pragma unroll
            for (int fn=0; fn<2; fn++){
                const int rb   = wn*32 + fn*16 + lc16;
                const int offb = rb*64 + (((ks*4 + kgrp) ^ (rb & 7))*8);
                bf16x8 bh = ldb8(&Bs0[offb]);
                bf16x8 bl = ldb8(&Bs1[offb]);
#pragma unroll
                for (int fm=0; fm<4; fm++){
                    acc[fm][fn] = __builtin_amdgcn_mfma_f32_16x16x32_bf16(ah[fm], bh, acc[fm][fn], 0,0,0);
                    acc[fm][fn] = __builtin_amdgcn_mfma_f32_16x16x32_bf16(ah[fm], bl, acc[fm][fn], 0,0,0);
                    acc[fm][fn] = __builtin_amdgcn_mfma_f32_16x16x32_bf16(al[fm], bh, acc[fm][fn], 0,0,0);
                }
            }
        }
        __syncthreads();
    }

    const int lr4 = (lane >> 4) * 4;
#pragma unroll
    for (int fm=0; fm<4; fm++){
        const int rbase = m0 + wm*64 + fm*16 + lr4;
#pragma unroll
        for (int fn=0; fn<2; fn++){
            const int col = n0 + wn*32 + fn*16 + lc16;
            f32x4 v = acc[fm][fn];
            if (FLAGS & EPI_PREDT){
#pragma unroll
                for (int r=0;r<4;r++){
                    int row = rbase + r;
                    if (row < Msz && col < PP){
                        int b = row / TT, t = row - b*TT;
                        if (t < NN)
                            Cf[((size_t)b*PP + col)*NN + t] = v[r] + bias[col];
                    }
                }
            } else {
                const float bcol = bias[col];
#pragma unroll
                for (int r=0;r<4;r++){
                    int row = rbase + r;
                    if (row < Msz){
                        float x = v[r] + bcol;
                        if (FLAGS & EPI_GELU) x = gelu_tanh(x);
                        if (FLAGS & EPI_F32) Cf[(size_t)row*Nsz + col] = x;
                        if (FLAGS & EPI_BF16){
                            uint16_t hi, lo; split_bf(x, hi, lo);
                            Cbh[(size_t)row*Nsz + col] = hi;
                            Cbl[(size_t)row*Nsz + col] = lo;
                        }
                    }
                }
            }
        }
    }
}

// ---------------------------------------------------------------------------
// tok transpose + split (unchanged)
// ---------------------------------------------------------------------------
__global__ __launch_bounds__(256)
void tok_k(const float* __restrict__ xe, const float* __restrict__ xm,
           uint16_t* __restrict__ th, uint16_t* __restrict__ tl)
{
    const int b = blockIdx.z;
    const int t0 = blockIdx.x*32, l0 = blockIdx.y*32;
    __shared__ float tile[32][33];
    const int i = threadIdx.x >> 3;
    const int j4 = (threadIdx.x & 7) * 4;
#pragma unroll
    for (int c=0;c<4;c++){
        int t = t0 + j4 + c;
        float v = 0.0f;
        if (t < 512)      v = xe[((size_t)b*LL + l0+i)*NN + t];
        else if (t < 516) v = xm[((size_t)b*LL + l0+i)*4 + (t-512)];
        tile[i][j4+c] = v;
    }
    __syncthreads();
    int t = t0 + i;
    if (t < TT){
#pragma unroll
        for (int c=0;c<4;c++){
            uint16_t hi, lo; split_bf(tile[j4+c][i], hi, lo);
            size_t idx = ((size_t)b*TT + t)*512 + l0 + j4 + c;
            th[idx] = hi; tl[idx] = lo;
        }
    }
}

// ---------------------------------------------------------------------------
// weight transpose-split (unchanged)
// ---------------------------------------------------------------------------
__global__ __launch_bounds__(256)
void wtr_k(const float* __restrict__ src, uint16_t* __restrict__ dh,
           uint16_t* __restrict__ dl, int Ksz, int Nsz, size_t zstride)
{
    const int z = blockIdx.z;
    src += (size_t)z*Ksz*Nsz; dh += (size_t)z*zstride; dl += (size_t)z*zstride;
    __shared__ float tile[32][33];
    const int kt = blockIdx.y*32, nt = blockIdx.x*32;
    const int i = threadIdx.x >> 3;
    const int j4 = (threadIdx.x & 7) * 4;
#pragma unroll
    for (int c=0;c<4;c++){
        int n = nt + j4 + c;
        tile[i][j4+c] = (n < Nsz) ? src[(size_t)(kt+i)*Nsz + n] : 0.0f;
    }
    __syncthreads();
    int n = nt + i;
    if (n < Nsz){
#pragma unroll
        for (int c=0;c<4;c++){
            uint16_t hi, lo; split_bf(tile[j4+c][i], hi, lo);
            size_t idx = (size_t)n*Ksz + kt + j4 + c;
            dh[idx] = hi; dl[idx] = lo;
        }
    }
}

__global__ void catb_k(const float* __restrict__ bq, const float* __restrict__ bk,
                       const float* __restrict__ bv, float* __restrict__ dst){
    int j = blockIdx.x*256 + threadIdx.x;
    if (j >= 3072) return;
    int layer = j / 1536, r = j - layer*1536;
    float v;
    if (r < 512)       v = bq[layer*512 + r];
    else if (r < 1024) v = bk[layer*512 + r - 512];
    else               v = bv[layer*512 + r - 1024];
    dst[j] = v;
}

// ---------------------------------------------------------------------------
// MFMA flash attention (unchanged)
// ---------------------------------------------------------------------------
__global__ __launch_bounds__(256, 2)
void attnm_k(const uint16_t* __restrict__ qh, const uint16_t* __restrict__ ql,
             const uint16_t* __restrict__ kh, const uint16_t* __restrict__ kl,
             const uint16_t* __restrict__ vth, const uint16_t* __restrict__ vtl,
             uint16_t* __restrict__ oh, uint16_t* __restrict__ ol)
{
    const int qt = blockIdx.x;
    const int h  = blockIdx.y;
    const int b  = blockIdx.z;
    const int bh = b*HH + h;
    const int q0 = qt*64;
    const int tid  = threadIdx.x;
    const int lane = tid & 63;
    const int wu   = __builtin_amdgcn_readfirstlane(tid >> 6);
    const int mrow = lane & 15;
    const int kgrp = lane >> 4;

    __shared__ uint16_t Khs[4096], Kls[4096];
    __shared__ uint16_t Vhs[4096], Vls[4096];
    __shared__ uint16_t Phs[4096], Pls[4096];

    int tq = q0 + wu*16 + mrow; if (tq > TT-1) tq = TT-1;
    const uint16_t* qbase = qh + ((size_t)bh*TT + tq)*64 + kgrp*8;
    const uint16_t* qbasl = ql + ((size_t)bh*TT + tq)*64 + kgrp*8;
    bf16x8 qfh[2], qfl[2];
    qfh[0] = ldb8(qbase);      qfh[1] = ldb8(qbase + 32);
    qfl[0] = ldb8(qbasl);      qfl[1] = ldb8(qbasl + 32);

    const int srw = lane >> 3;
    const int sg  = lane & 7;

    f32x4 oacc[4];
#pragma unroll
    for (int f=0;f<4;f++) oacc[f] = (f32x4){0.f,0.f,0.f,0.f};
    float m_r[4] = {-1e30f,-1e30f,-1e30f,-1e30f};
    float l_r[4] = {0.f,0.f,0.f,0.f};

    for (int st=0; st<9; ++st){
        const int s0 = st*64;
        __syncthreads();
#pragma unroll
        for (int c=0;c<2;c++){
            const int r   = wu*16 + c*8 + srw;
            const int gsl = sg ^ (r & 7);
            int sk = s0 + r; if (sk > TT-1) sk = TT-1;
            const uint16_t* ksh_ = kh  + ((size_t)bh*TT + sk)*64 + gsl*8;
            const uint16_t* ksl_ = kl  + ((size_t)bh*TT + sk)*64 + gsl*8;
            int cb = s0 + gsl*8; if (cb > VSTR-8) cb = VSTR-8;
            const uint16_t* vsh_ = vth + ((size_t)bh*64 + r)*VSTR + cb;
            const uint16_t* vsl_ = vtl + ((size_t)bh*64 + r)*VSTR + cb;
            gl16(ksh_, &Khs[(wu*16 + c*8)*64]);
            gl16(ksl_, &Kls[(wu*16 + c*8)*64]);
            gl16(vsh_, &Vhs[(wu*16 + c*8)*64]);
            gl16(vsl_, &Vls[(wu*16 + c*8)*64]);
        }
        __syncthreads();

        f32x4 sacc[4];
#pragma unroll
        for (int f=0;f<4;f++) sacc[f] = (f32x4){0.f,0.f,0.f,0.f};
#pragma unroll
        for (int ks=0; ks<2; ks++){
#pragma unroll
            for (int f=0; f<4; f++){
                const int sr = f*16 + mrow;
                const int sl = ((ks*4 + kgrp) ^ (sr & 7))*8;
                bf16x8 kbh = ldb8(&Khs[sr*64 + sl]);
                bf16x8 kbl = ldb8(&Kls[sr*64 + sl]);
                sacc[f] = __builtin_amdgcn_mfma_f32_16x16x32_bf16(qfh[ks], kbh, sacc[f], 0,0,0);
                sacc[f] = __builtin_amdgcn_mfma_f32_16x16x32_bf16(qfh[ks], kbl, sacc[f], 0,0,0);
                sacc[f] = __builtin_amdgcn_mfma_f32_16x16x32_bf16(qfl[ks], kbh, sacc[f], 0,0,0);
            }
        }

        float alpha[4];
#pragma unroll
        for (int r=0;r<4;r++){
            float mx = -1e30f;
#pragma unroll
            for (int f=0;f<4;f++){
                float sv = sacc[f][r]*0.125f;
                if (s0 + f*16 + mrow >= TT) sv = -1e30f;
                sacc[f][r] = sv;
                mx = fmaxf(mx, sv);
            }
#pragma unroll
            for (int msk=1; msk<16; msk<<=1) mx = fmaxf(mx, __shfl_xor(mx, msk));
            float mn = fmaxf(m_r[r], mx);
            alpha[r] = __expf(m_r[r] - mn);
            m_r[r] = mn;
            float rs = 0.0f;
#pragma unroll
            for (int f=0;f<4;f++){
                float e = __expf(sacc[f][r] - mn);
                sacc[f][r] = e;
                rs += e;
            }
#pragma unroll
            for (int msk=1; msk<16; msk<<=1) rs += __shfl_xor(rs, msk);
            l_r[r] = l_r[r]*alpha[r] + rs;
#pragma unroll
            for (int f=0;f<4;f++) oacc[f][r] *= alpha[r];
        }

#pragma unroll
        for (int r=0;r<4;r++){
            const int tr = wu*16 + kgrp*4 + r;
#pragma unroll
            for (int f=0;f<4;f++){
                const int c = f*16 + mrow;
                const int idx = tr*64 + ((c>>3) ^ (tr&7))*8 + (c&7);
                uint16_t hi, lo; split_bf(sacc[f][r], hi, lo);
                Phs[idx] = hi; Pls[idx] = lo;
            }
        }

#pragma unroll
        for (int ks=0; ks<2; ks++){
            const int trr = wu*16 + mrow;
            const int psl = ((ks*4 + kgrp) ^ (trr & 7))*8;
            bf16x8 pah = ldb8(&Phs[trr*64 + psl]);
            bf16x8 pal = ldb8(&Pls[trr*64 + psl]);
#pragma unroll
            for (int f=0; f<4; f++){
                const int dr = f*16 + mrow;
                const int vsl = ((ks*4 + kgrp) ^ (dr & 7))*8;
                bf16x8 vbh = ldb8(&Vhs[dr*64 + vsl]);
                bf16x8 vbl = ldb8(&Vls[dr*64 + vsl]);
                oacc[f] = __builtin_amdgcn_mfma_f32_16x16x32_bf16(pah, vbh, oacc[f], 0,0,0);
                oacc[f] = __builtin_amdgcn_mfma_f32_16x16x32_bf16(pah, vbl, oacc[f], 0,0,0);
                oacc[f] = __builtin_amdgcn_mfma_f32_16x16x32_bf16(pal, vbh, oacc[f], 0,0,0);
            }
        }
    }

#pragma unroll
    for (int r=0;r<4;r++){
        const int t = q0 + wu*16 + kgrp*4 + r;
        if (t < TT){
            const float inv = 1.0f / l_r[r];
#pragma unroll
            for (int f=0;f<4;f++){
                const int d = f*16 + mrow;
                uint16_t hi, lo; split_bf(oacc[f][r]*inv, hi, lo);
                size_t o = ((size_t)(b*TT + t))*DD + h*DHD + d;
                oh[o] = hi; ol[o] = lo;
            }
        }
    }
}

// ---------------------------------------------------------------------------
// Residual + LayerNorm (unchanged)
// ---------------------------------------------------------------------------
__global__ __launch_bounds__(256)
void ln_k(const float* __restrict__ src, const float* __restrict__ res,
          const float* __restrict__ w, const float* __restrict__ bia,
          float* __restrict__ dst, uint16_t* __restrict__ dbh,
          uint16_t* __restrict__ dbl)
{
    const int r = blockIdx.x;
    const int tid = threadIdx.x;
    const float* sp = src + (size_t)r*DD;
    float x0 = sp[tid], x1 = sp[tid + 256];
    if (res){
        x0 += res[(size_t)r*DD + tid];
        x1 += res[(size_t)r*DD + tid + 256];
    }
    float s  = x0 + x1;
    float sq = x0*x0 + x1*x1;
#pragma unroll
    for (int msk=1; msk<64; msk<<=1){
        s  += __shfl_xor(s,  msk);
        sq += __shfl_xor(sq, msk);
    }
    __shared__ float sm[8];
    int wv = tid >> 6, ln = tid & 63;
    if (ln == 0){ sm[wv] = s; sm[wv+4] = sq; }
    __syncthreads();
    s  = sm[0]+sm[1]+sm[2]+sm[3];
    sq = sm[4]+sm[5]+sm[6]+sm[7];
    float mu  = s * (1.0f/512.0f);
    float var = sq * (1.0f/512.0f) - mu*mu;
    float rsd = rsqrtf(var + 1e-5f);
    float y0 = (x0 - mu)*rsd*w[tid]       + bia[tid];
    float y1 = (x1 - mu)*rsd*w[tid + 256] + bia[tid + 256];
    dst[(size_t)r*DD + tid]       = y0;
    dst[(size_t)r*DD + tid + 256] = y1;
    uint16_t hi, lo;
    split_bf(y0, hi, lo); dbh[(size_t)r*DD + tid] = hi;       dbl[(size_t)r*DD + tid] = lo;
    split_bf(y1, hi, lo); dbh[(size_t)r*DD + tid + 256] = hi; dbl[(size_t)r*DD + tid + 256] = lo;
}

// ---------------------------------------------------------------------------
// sims v3 (unchanged from round 7)
// ---------------------------------------------------------------------------
__global__ __launch_bounds__(256, 2)
void sims_k(const float* __restrict__ pred, const float* __restrict__ bank,
            float* __restrict__ dotp, float* __restrict__ nrmp)
{
    const int jt = blockIdx.x, kt = blockIdx.y;
    const int tid  = threadIdx.x;
    const int qq    = tid & 7;
    const int slice = tid >> 3;
    const int sb    = slice*8;
    const int srow  = tid >> 4;
    const int tau   = tid & 15;

    __shared__ float BS[16*264];

    const int jr = jt*16 + srow;
    const float* bsrc = (jr < MM) ? (bank + (size_t)jr*PN)
                                  : (pred + (size_t)(jr - MM)*PN);
    bsrc += (size_t)kt*SCHUNK + tau*4;
    const float* p0 = pred + (size_t)qq*PN      + (size_t)kt*SCHUNK + sb;
    const float* p1 = pred + (size_t)(qq+8)*PN  + (size_t)kt*SCHUNK + sb;

    float acc0[16], acc1[16];
#pragma unroll
    for (int j=0;j<16;j++){ acc0[j] = 0.0f; acc1[j] = 0.0f; }
    float nr = 0.0f;

    for (int st=0; st<SSTG; ++st){
        float4 blv[4];
#pragma unroll
        for (int c=0;c<4;c++) blv[c] = *(const float4*)(bsrc + c*64);
        float4 pr0[2], pr1[2];
        pr0[0] = *(const float4*)(p0);     pr0[1] = *(const float4*)(p0 + 4);
        pr1[0] = *(const float4*)(p1);     pr1[1] = *(const float4*)(p1 + 4);
        __syncthreads();
#pragma unroll
        for (int c=0;c<4;c++){
            *(float4*)&BS[srow*264 + tau*4 + c*64] = blv[c];
            nr = fmaf(blv[c].x, blv[c].x, nr);
            nr = fmaf(blv[c].y, blv[c].y, nr);
            nr = fmaf(blv[c].z, blv[c].z, nr);
            nr = fmaf(blv[c].w, blv[c].w, nr);
        }
        __syncthreads();
#pragma unroll
        for (int j=0;j<16;j++){
            float4 b0 = *(const float4*)&BS[j*264 + sb];
            float4 b1 = *(const float4*)&BS[j*264 + sb + 4];
            float a0 = acc0[j], a1 = acc1[j];
            a0 = fmaf(b0.x, pr0[0].x, a0); a0 = fmaf(b0.y, pr0[0].y, a0);
            a0 = fmaf(b0.z, pr0[0].z, a0); a0 = fmaf(b0.w, pr0[0].w, a0);
            a0 = fmaf(b1.x, pr0[1].x, a0); a0 = fmaf(b1.y, pr0[1].y, a0);
            a0 = fmaf(b1.z, pr0[1].z, a0); a0 = fmaf(b1.w, pr0[1].w, a0);
            a1 = fmaf(b0.x, pr1[0].x, a1); a1 = fmaf(b0.y, pr1[0].y, a1);
            a1 = fmaf(b0.z, pr1[0].z, a1); a1 = fmaf(b0.w, pr1[0].w, a1);
            a1 = fmaf(b1.x, pr1[1].x, a1); a1 = fmaf(b1.y, pr1[1].y, a1);
            a1 = fmaf(b1.z, pr1[1].z, a1); a1 = fmaf(b1.w, pr1[1].w, a1);
            acc0[j] = a0; acc1[j] = a1;
        }
        bsrc += 256; p0 += 256; p1 += 256;
    }

#pragma unroll
    for (int m=8; m<64; m<<=1){
#pragma unroll
        for (int j=0;j<16;j++){
            acc0[j] += __shfl_xor(acc0[j], m);
            acc1[j] += __shfl_xor(acc1[j], m);
        }
    }
#pragma unroll
    for (int m=1;m<16;m<<=1) nr += __shfl_xor(nr, m);

    __syncthreads();
    float* RED = BS;
    const int wu2  = tid >> 6;
    const int lane = tid & 63;
    if (lane < 8){
#pragma unroll
        for (int j=0;j<16;j++){
            RED[(wu2*16 + j)*16 + lane]     = acc0[j];
            RED[(wu2*16 + j)*16 + lane + 8] = acc1[j];
        }
    }
    __syncthreads();
    const int j2 = tid >> 4, q2 = tid & 15;
    float s = RED[(0*16 + j2)*16 + q2] + RED[(1*16 + j2)*16 + q2]
            + RED[(2*16 + j2)*16 + q2] + RED[(3*16 + j2)*16 + q2];
    dotp[((size_t)kt*528 + jt*16 + j2)*16 + q2] = s;
    if (tau == 0) nrmp[kt*528 + jt*16 + srow] = nr;
}

__global__ void norms_k(const float* __restrict__ nrmp, float* __restrict__ invn){
    int j = blockIdx.x*blockDim.x + threadIdx.x;
    if (j < 528){
        float s = 0.0f;
        for (int kt=0; kt<SKC; kt++) s += nrmp[kt*528 + j];
        invn[j] = 1.0f/(sqrtf(s) + 1e-8f);
    }
}

__global__ void simsfin_k(const float* __restrict__ dotp, const float* __restrict__ invn,
                          float* __restrict__ sims){
    int fid = blockIdx.x*256 + threadIdx.x;
    int j = fid >> 4, q = fid & 15;
    float s = 0.0f;
    for (int kt=0; kt<SKC; kt++) s += dotp[((size_t)kt*528 + j)*16 + q];
    sims[q*528 + j] = s * invn[j] * invn[MM + q];
}

__global__ __launch_bounds__(64)
void topk_k(const float* __restrict__ sims, int* __restrict__ idx){
    const int q = blockIdx.x;
    const int lane = threadIdx.x;
    __shared__ float vals[528];
    for (int j=lane; j<528; j+=64) vals[j] = sims[q*528 + j];
    __syncthreads();
    for (int kk=0; kk<KNN; kk++){
        float bv = -3.0e38f; int bi = 1<<30;
        for (int j=lane; j<528; j+=64){
            float v2 = vals[j];
            if (v2 > bv || (v2 == bv && j < bi)){ bv = v2; bi = j; }
        }
#pragma unroll
        for (int msk=1; msk<64; msk<<=1){
            float ov = __shfl_xor(bv, msk);
            int   oi = __shfl_xor(bi, msk);
            if (ov > bv || (ov == bv && oi < bi)){ bv = ov; bi = oi; }
        }
        if (lane == 0){
            idx[q*KNN + kk] = bi;
            vals[bi] = -3.0e38f;
        }
        __syncthreads();
    }
}

__global__ __launch_bounds__(256)
void fuse_k(const float* __restrict__ pred, const float* __restrict__ bank,
            const int* __restrict__ idx, float* __restrict__ out){
    int u = blockIdx.x*256 + threadIdx.x;
    int b = u / (PN/4);
    int e = (u - b*(PN/4)) * 4;
    int id[KNN];
#pragma unroll
    for (int k2=0;k2<KNN;k2++) id[k2] = idx[b*KNN + k2];
    float4 pv = *(const float4*)(pred + (size_t)b*PN + e);
    float ax = 0.5f*pv.x, ay = 0.5f*pv.y, az = 0.5f*pv.z, aw = 0.5f*pv.w;
#pragma unroll
    for (int k2=0;k2<KNN;k2++){
        const float* rp = (id[k2] < MM) ? (bank + (size_t)id[k2]*PN)
                                        : (pred + (size_t)(id[k2]-MM)*PN);
        float4 rv = *(const float4*)(rp + e);
        ax = fmaf(0.05f, rv.x, ax); ay = fmaf(0.05f, rv.y, ay);
        az = fmaf(0.05f, rv.z, az); aw = fmaf(0.05f, rv.w, aw);
    }
    float4 ov; ov.x=ax; ov.y=ay; ov.z=az; ov.w=aw;
    *(float4*)(out + (size_t)b*PN + e) = ov;
}

// ---------------------------------------------------------------------------
extern "C" void kernel_launch(void* const* d_in, const int* in_sizes, int n_in,
                              void* d_out, int out_size, void* d_ws, size_t ws_size,
                              hipStream_t stream)
{
    (void)in_sizes; (void)n_in; (void)out_size; (void)ws_size;
    const float* x_enc  = (const float*)d_in[0];
    const float* x_mark = (const float*)d_in[1];
    const float* W_emb  = (const float*)d_in[4];
    const float* b_emb  = (const float*)d_in[5];
    const float* Wq  = (const float*)d_in[6];
    const float* Wk  = (const float*)d_in[7];
    const float* Wv  = (const float*)d_in[8];
    const float* Wo  = (const float*)d_in[9];
    const float* bq  = (const float*)d_in[10];
    const float* bk  = (const float*)d_in[11];
    const float* bv_ = (const float*)d_in[12];
    const float* bo  = (const float*)d_in[13];
    const float* ln1w = (const float*)d_in[14];
    const float* ln1b = (const float*)d_in[15];
    const float* ln2w = (const float*)d_in[16];
    const float* ln2b = (const float*)d_in[17];
    const float* Wff1 = (const float*)d_in[18];
    const float* bff1 = (const float*)d_in[19];
    const float* Wff2 = (const float*)d_in[20];
    const float* bff2 = (const float*)d_in[21];
    const float* lnfw = (const float*)d_in[22];
    const float* lnfb = (const float*)d_in[23];
    const float* Wproj = (const float*)d_in[24];
    const float* bproj = (const float*)d_in[25];
    const float* bank  = (const float*)d_in[26];
    float* out = (float*)d_out;

    char* pp = (char*)d_ws;
    auto a16 = [&](size_t elems)->uint16_t*{ uint16_t* r=(uint16_t*)pp; pp += ((elems*2 + 255)/256)*256; return r; };
    auto af  = [&](size_t elems)->float*  { float* r=(float*)pp;  pp += ((elems*4 + 255)/256)*256; return r; };

    uint16_t* wembT_h = a16(262144);        uint16_t* wembT_l = a16(262144);
    uint16_t* wqkvT_h = a16(2*1536*512);    uint16_t* wqkvT_l = a16(2*1536*512);
    uint16_t* woT_h   = a16(2*262144);      uint16_t* woT_l   = a16(2*262144);
    uint16_t* wff1T_h = a16(2*2048*512);    uint16_t* wff1T_l = a16(2*2048*512);
    uint16_t* wff2T_h = a16(2*512*2048);    uint16_t* wff2T_l = a16(2*512*2048);
    uint16_t* wprjT_h = a16(172032);        uint16_t* wprjT_l = a16(172032);
    float*    bqkv    = af(3072);
    uint16_t* hb_h    = a16((size_t)BT*512);
    uint16_t* hb_l    = a16((size_t)BT*512);
    uint16_t* tok_h   = a16((size_t)BT*512);     // og fp32 aliases tok region
    uint16_t* tok_l   = a16((size_t)BT*512);
    float*    og      = (float*)tok_h;
    uint16_t* qsh     = a16((size_t)128*TT*64);
    uint16_t* qsl     = a16((size_t)128*TT*64);
    uint16_t* ksh     = a16((size_t)128*TT*64);
    uint16_t* ksl     = a16((size_t)128*TT*64);
    uint16_t* vsh     = a16((size_t)128*64*VSTR + 4096);
    uint16_t* vsl     = a16((size_t)128*64*VSTR + 4096);
    uint16_t* t1b_h   = a16((size_t)BT*512);
    uint16_t* t1b_l   = a16((size_t)BT*512);
    uint16_t* midb_h  = qsh;                     // mid aliases qsh..t1b region
    uint16_t* midb_l  = midb_h + (size_t)BT*2048;
    float*    h       = af((size_t)BT*512);
    float*    pred    = af((size_t)BB*PN);
    float*    dotp    = af((size_t)SKC*528*16);
    float*    nrmp    = af(SKC*528);
    float*    invn    = af(528);
    float*    sims    = af(16*528);
    int*      idxp    = (int*)af(256);

    dim3 blk(256);

    tok_k<<<dim3(17,16,BB), blk, 0, stream>>>(x_enc, x_mark, tok_h, tok_l);
    wtr_k<<<dim3(16,16,1), blk, 0, stream>>>(W_emb, wembT_h, wembT_l, 512, 512, 262144);
    wtr_k<<<dim3(16,16,2), blk, 0, stream>>>(Wq, wqkvT_h,          wqkvT_l,          512, 512, 786432);
    wtr_k<<<dim3(16,16,2), blk, 0, stream>>>(Wk, wqkvT_h + 262144, wqkvT_l + 262144, 512, 512, 786432);
    wtr_k<<<dim3(16,16,2), blk, 0, stream>>>(Wv, wqkvT_h + 524288, wqkvT_l + 524288, 512, 512, 786432);
    wtr_k<<<dim3(16,16,2), blk, 0, stream>>>(Wo, woT_h, woT_l, 512, 512, 262144);
    wtr_k<<<dim3(64,16,2), blk, 0, stream>>>(Wff1, wff1T_h, wff1T_l, 512, 2048, 1048576);
    wtr_k<<<dim3(16,64,2), blk, 0, stream>>>(Wff2, wff2T_h, wff2T_l, 2048, 512, 1048576);
    wtr_k<<<dim3(11,16,1), blk, 0, stream>>>(Wproj, wprjT_h, wprjT_l, 512, 336, 172032);
    catb_k<<<dim3(12), blk, 0, stream>>>(bq, bk, bv_, bqkv);

    bgemm64<EPI_F32|EPI_BF16><<<dim3(8,65), blk, 0, stream>>>(
        tok_h, tok_l, wembT_h, wembT_l, b_emb, h, hb_h, hb_l, BT, 512, 512);

    for (int i=0;i<2;i++){
        bgemm<EPI_QKV><<<dim3(12,65), blk, 0, stream>>>(
            hb_h, hb_l, wqkvT_h + (size_t)i*786432, wqkvT_l + (size_t)i*786432,
            bqkv + i*1536, nullptr, qsh, qsl, ksh, ksl, vsh, vsl, BT, 1536, 512);
        attnm_k<<<dim3(9,HH,BB), blk, 0, stream>>>(qsh, qsl, ksh, ksl, vsh, vsl, t1b_h, t1b_l);
        bgemm64<EPI_F32><<<dim3(8,65), blk, 0, stream>>>(
            t1b_h, t1b_l, woT_h + (size_t)i*262144, woT_l + (size_t)i*262144,
            bo + i*512, og, nullptr, nullptr, BT, 512, 512);
        ln_k<<<BT, blk, 0, stream>>>(h, og, ln1w + i*512, ln1b + i*512, h, hb_h, hb_l);
        bgemm<EPI_GELU|EPI_BF16><<<dim3(16,65), blk, 0, stream>>>(
            hb_h, hb_l, wff1T_h + (size_t)i*1048576, wff1T_l + (size_t)i*1048576,
            bff1 + i*DFFN, nullptr, midb_h, midb_l,
            nullptr, nullptr, nullptr, nullptr, BT, DFFN, 512);
        bgemm64<EPI_F32><<<dim3(8,65), blk, 0, stream>>>(
            midb_h, midb_l, wff2T_h + (size_t)i*1048576, wff2T_l + (size_t)i*1048576,
            bff2 + i*512, og, nullptr, nullptr, BT, 512, DFFN);
        ln_k<<<BT, blk, 0, stream>>>(h, og, ln2w + i*512, ln2b + i*512, h, hb_h, hb_l);
    }

    ln_k<<<BT, blk, 0, stream>>>(h, nullptr, lnfw, lnfb, h, hb_h, hb_l);

    bgemm64<EPI_PREDT><<<dim3(6,65), blk, 0, stream>>>(
        hb_h, hb_l, wprjT_h, wprjT_l, bproj, pred, nullptr, nullptr, BT, PP, 512);

    sims_k<<<dim3(33,SKC), blk, 0, stream>>>(pred, bank, dotp, nrmp);
    norms_k<<<dim3(3), blk, 0, stream>>>(nrmp, invn);
    simsfin_k<<<dim3(33), blk, 0, stream>>>(dotp, invn, sims);
    topk_k<<<dim3(BB), dim3(64), 0, stream>>>(sims, idxp);
    fuse_k<<<dim3((BB*PN/4)/256), blk, 0, stream>>>(pred, bank, idxp, out);
}

// Round 9
// 1125.220 us; speedup vs baseline: 1.0866x; 1.0264x over previous
//
#include <hip/hip_runtime.h>
#include <stdint.h>
#include <math.h>

#define TT 516
#define BB 16
#define DD 512
#define LL 512
#define NN 512
#define HH 8
#define DHD 64
#define DFFN 2048
#define PP 336
#define MM 512
#define KNN 10
#define BT (BB*TT)      /* 8256 */
#define PN (PP*NN)      /* 172032 */
#define SKC 32          /* sims k-chunks */
#define SCHUNK (PN/SKC) /* 5376 */
#define SSTG (SCHUNK/256) /* 21 stages */
#define VSTR 528        /* transposed-V row stride (uint16 elems) */

using f32x4  = __attribute__((ext_vector_type(4))) float;
using bf16x8 = __attribute__((ext_vector_type(8))) __bf16;
using u16x8  = __attribute__((ext_vector_type(8))) unsigned short;

__device__ __forceinline__ float gelu_tanh(float x){
    float x3 = x*x*x;
    return 0.5f*x*(1.0f + tanhf(0.7978845608028654f*(x + 0.044715f*x3)));
}

__device__ __forceinline__ uint16_t f2bf(float x){
    uint32_t u = __builtin_bit_cast(uint32_t, x);
    uint32_t r = (u + 0x7FFFu + ((u >> 16) & 1u)) >> 16;
    return (uint16_t)r;
}

__device__ __forceinline__ void split_bf(float x, uint16_t& hi, uint16_t& lo){
    uint32_t u  = __builtin_bit_cast(uint32_t, x);
    uint32_t hr = (u + 0x7FFFu + ((u >> 16) & 1u)) & 0xFFFF0000u;
    float hf = __builtin_bit_cast(float, hr);
    hi = (uint16_t)(hr >> 16);
    lo = f2bf(x - hf);
}

__device__ __forceinline__ void gl16(const uint16_t* g, uint16_t* l){
    __builtin_amdgcn_global_load_lds(
        (const __attribute__((address_space(1))) unsigned int*)(const void*)g,
        (__attribute__((address_space(3))) unsigned int*)(void*)l, 16, 0, 0);
}

__device__ __forceinline__ bf16x8 ldb8(const uint16_t* p){
    return __builtin_bit_cast(bf16x8, *(const u16x8*)p);
}

#define EPI_F32   1
#define EPI_BF16  2
#define EPI_GELU  4
#define EPI_PREDT 8
#define EPI_QKV   16

// ---------------------------------------------------------------------------
// Split-bf16 MFMA GEMM, BN=128, BK=32 (unchanged)
// ---------------------------------------------------------------------------
template<int FLAGS>
__global__ __launch_bounds__(256)
void bgemm(const uint16_t* __restrict__ Ah, const uint16_t* __restrict__ Al,
           const uint16_t* __restrict__ Bh, const uint16_t* __restrict__ Bl,
           const float* __restrict__ bias, float* __restrict__ Cf,
           uint16_t* __restrict__ Cbh, uint16_t* __restrict__ Cbl,
           uint16_t* __restrict__ Xkh, uint16_t* __restrict__ Xkl,
           uint16_t* __restrict__ Xvh, uint16_t* __restrict__ Xvl,
           int Msz, int Nsz, int Ksz)
{
    constexpr int BN = 128;
    constexpr int FN = 4;
    __shared__ uint16_t As0[4096], As1[4096];
    __shared__ uint16_t Bs0[BN*32], Bs1[BN*32];

    const int tid  = threadIdx.x;
    const int lane = tid & 63;
    const int wu   = __builtin_amdgcn_readfirstlane(tid >> 6);
    const int wm   = wu >> 1, wn = wu & 1;
    const int m0   = blockIdx.y * 128;
    const int n0   = blockIdx.x * BN;

    const int r0c = tid >> 2;
    const int cc  = tid & 3;
    const int sw  = (r0c ^ (r0c >> 2)) & 3;
    const int csw = (cc ^ sw) * 8;
    int rA0 = m0 + r0c;      if (rA0 > Msz-1) rA0 = Msz-1;
    int rA1 = m0 + r0c + 64; if (rA1 > Msz-1) rA1 = Msz-1;
    int rB0 = n0 + r0c;      if (rB0 > Nsz-1) rB0 = Nsz-1;
    int rB1 = n0 + r0c + 64; if (rB1 > Nsz-1) rB1 = Nsz-1;
    const uint16_t* pAh0 = Ah + (size_t)rA0*Ksz + csw;
    const uint16_t* pAh1 = Ah + (size_t)rA1*Ksz + csw;
    const uint16_t* pAl0 = Al + (size_t)rA0*Ksz + csw;
    const uint16_t* pAl1 = Al + (size_t)rA1*Ksz + csw;
    const uint16_t* pBh0 = Bh + (size_t)rB0*Ksz + csw;
    const uint16_t* pBh1 = Bh + (size_t)rB1*Ksz + csw;
    const uint16_t* pBl0 = Bl + (size_t)rB0*Ksz + csw;
    const uint16_t* pBl1 = Bl + (size_t)rB1*Ksz + csw;

    f32x4 acc[4][FN];
#pragma unroll
    for (int i=0;i<4;i++)
#pragma unroll
        for (int j=0;j<FN;j++) acc[i][j] = (f32x4){0.f,0.f,0.f,0.f};

    const int lc16  = lane & 15;
    const int slot8 = (((lane>>4) ^ (lane&3) ^ ((lane>>2)&3))) * 8;
    const int rAf   = (wm*64 + lc16) * 32 + slot8;
    const int rBf   = (wn*(BN/2) + lc16) * 32 + slot8;

    for (int kt = 0; kt < Ksz; kt += 32){
        gl16(pAh0 + kt, &As0[wu*512]);
        gl16(pAh1 + kt, &As0[2048 + wu*512]);
        gl16(pAl0 + kt, &As1[wu*512]);
        gl16(pAl1 + kt, &As1[2048 + wu*512]);
        gl16(pBh0 + kt, &Bs0[wu*512]);
        gl16(pBh1 + kt, &Bs0[2048 + wu*512]);
        gl16(pBl0 + kt, &Bs1[wu*512]);
        gl16(pBl1 + kt, &Bs1[2048 + wu*512]);
        __syncthreads();

        bf16x8 ah[4], al[4];
#pragma unroll
        for (int fm=0; fm<4; fm++){
            ah[fm] = ldb8(&As0[rAf + fm*512]);
            al[fm] = ldb8(&As1[rAf + fm*512]);
        }
#pragma unroll
        for (int fn=0; fn<FN; fn++){
            bf16x8 bh = ldb8(&Bs0[rBf + fn*512]);
            bf16x8 bl = ldb8(&Bs1[rBf + fn*512]);
#pragma unroll
            for (int fm=0; fm<4; fm++){
                acc[fm][fn] = __builtin_amdgcn_mfma_f32_16x16x32_bf16(ah[fm], bh, acc[fm][fn], 0,0,0);
                acc[fm][fn] = __builtin_amdgcn_mfma_f32_16x16x32_bf16(ah[fm], bl, acc[fm][fn], 0,0,0);
                acc[fm][fn] = __builtin_amdgcn_mfma_f32_16x16x32_bf16(al[fm], bh, acc[fm][fn], 0,0,0);
            }
        }
        __syncthreads();
    }

    const int lr4 = (lane >> 4) * 4;
#pragma unroll
    for (int fm=0; fm<4; fm++){
        const int rbase = m0 + wm*64 + fm*16 + lr4;
#pragma unroll
        for (int fn=0; fn<FN; fn++){
            const int col = n0 + wn*(BN/2) + fn*16 + lc16;
            f32x4 v = acc[fm][fn];
            if (FLAGS & EPI_QKV){
                const int g   = col >> 9;
                const int cc2 = col & 511;
                const int hh2 = cc2 >> 6, dd2 = cc2 & 63;
                const float bcol = bias[col];
#pragma unroll
                for (int r=0;r<4;r++){
                    int row = rbase + r;
                    if (row < Msz){
                        float x = v[r] + bcol;
                        int b2 = row / TT, t2 = row - b2*TT;
                        int bh2 = b2*HH + hh2;
                        uint16_t hi, lo; split_bf(x, hi, lo);
                        if (g == 0){
                            size_t o = ((size_t)bh2*TT + t2)*64 + dd2;
                            Cbh[o] = hi; Cbl[o] = lo;
                        } else if (g == 1){
                            size_t o = ((size_t)bh2*TT + t2)*64 + dd2;
                            Xkh[o] = hi; Xkl[o] = lo;
                        } else {
                            size_t o = ((size_t)bh2*64 + dd2)*VSTR + t2;
                            Xvh[o] = hi; Xvl[o] = lo;
                        }
                    }
                }
            } else {
                const float bcol = bias[col];
#pragma unroll
                for (int r=0;r<4;r++){
                    int row = rbase + r;
                    if (row < Msz){
                        float x = v[r] + bcol;
                        if (FLAGS & EPI_GELU) x = gelu_tanh(x);
                        if (FLAGS & EPI_F32) Cf[(size_t)row*Nsz + col] = x;
                        if (FLAGS & EPI_BF16){
                            uint16_t hi, lo; split_bf(x, hi, lo);
                            Cbh[(size_t)row*Nsz + col] = hi;
                            Cbl[(size_t)row*Nsz + col] = lo;
                        }
                    }
                }
            }
        }
    }
}

// ---------------------------------------------------------------------------
// BN=64, BK=64 split-bf16 GEMM (unchanged from round 8)
// ---------------------------------------------------------------------------
template<int FLAGS>
__global__ __launch_bounds__(256, 3)
void bgemm64(const uint16_t* __restrict__ Ah, const uint16_t* __restrict__ Al,
             const uint16_t* __restrict__ Bh, const uint16_t* __restrict__ Bl,
             const float* __restrict__ bias, float* __restrict__ Cf,
             uint16_t* __restrict__ Cbh, uint16_t* __restrict__ Cbl,
             int Msz, int Nsz, int Ksz)
{
    __shared__ uint16_t As0[8192], As1[8192];
    __shared__ uint16_t Bs0[4096], Bs1[4096];

    const int tid  = threadIdx.x;
    const int lane = tid & 63;
    const int wu   = __builtin_amdgcn_readfirstlane(tid >> 6);
    const int wm   = wu >> 1, wn = wu & 1;
    const int m0   = blockIdx.y * 128;
    const int n0   = blockIdx.x * 64;

    const int sr8 = lane >> 3;
    const int skw = (((lane & 7) ^ sr8) * 8);

    int rA[4], rB[2];
#pragma unroll
    for (int i=0;i<4;i++){
        int r = m0 + (wu*4 + i)*8 + sr8;
        rA[i] = (r > Msz-1) ? Msz-1 : r;
    }
#pragma unroll
    for (int i=0;i<2;i++){
        int r = n0 + (wu*2 + i)*8 + sr8;
        rB[i] = (r > Nsz-1) ? Nsz-1 : r;
    }

    f32x4 acc[4][2];
#pragma unroll
    for (int i=0;i<4;i++)
#pragma unroll
        for (int j=0;j<2;j++) acc[i][j] = (f32x4){0.f,0.f,0.f,0.f};

    const int lc16 = lane & 15;
    const int kgrp = lane >> 4;

    for (int kt = 0; kt < Ksz; kt += 64){
#pragma unroll
        for (int i=0;i<4;i++){
            gl16(Ah + (size_t)rA[i]*Ksz + kt + skw, &As0[(wu*4 + i)*512]);
            gl16(Al + (size_t)rA[i]*Ksz + kt + skw, &As1[(wu*4 + i)*512]);
        }
#pragma unroll
        for (int i=0;i<2;i++){
            gl16(Bh + (size_t)rB[i]*Ksz + kt + skw, &Bs0[(wu*2 + i)*512]);
            gl16(Bl + (size_t)rB[i]*Ksz + kt + skw, &Bs1[(wu*2 + i)*512]);
        }
        __syncthreads();

#pragma unroll
        for (int ks=0; ks<2; ks++){
            bf16x8 ah[4], al[4];
#pragma unroll
            for (int fm=0; fm<4; fm++){
                const int r   = wm*64 + fm*16 + lc16;
                const int off = r*64 + (((ks*4 + kgrp) ^ (r & 7))*8);
                ah[fm] = ldb8(&As0[off]);
                al[fm] = ldb8(&As1[off]);
            }
#pragma unroll
            for (int fn=0; fn<2; fn++){
                const int rb   = wn*32 + fn*16 + lc16;
                const int offb = rb*64 + (((ks*4 + kgrp) ^ (rb & 7))*8);
                bf16x8 bh = ldb8(&Bs0[offb]);
                bf16x8 bl = ldb8(&Bs1[offb]);
#pragma unroll
                for (int fm=0; fm<4; fm++){
                    acc[fm][fn] = __builtin_amdgcn_mfma_f32_16x16x32_bf16(ah[fm], bh, acc[fm][fn], 0,0,0);
                    acc[fm][fn] = __builtin_amdgcn_mfma_f32_16x16x32_bf16(ah[fm], bl, acc[fm][fn], 0,0,0);
                    acc[fm][fn] = __builtin_amdgcn_mfma_f32_16x16x32_bf16(al[fm], bh, acc[fm][fn], 0,0,0);
                }
            }
        }
        __syncthreads();
    }

    const int lr4 = (lane >> 4) * 4;
#pragma unroll
    for (int fm=0; fm<4; fm++){
        const int rbase = m0 + wm*64 + fm*16 + lr4;
#pragma unroll
        for (int fn=0; fn<2; fn++){
            const int col = n0 + wn*32 + fn*16 + lc16;
            f32x4 v = acc[fm][fn];
            if (FLAGS & EPI_PREDT){
#pragma unroll
                for (int r=0;r<4;r++){
                    int row = rbase + r;
                    if (row < Msz && col < PP){
                        int b = row / TT, t = row - b*TT;
                        if (t < NN)
                            Cf[((size_t)b*PP + col)*NN + t] = v[r] + bias[col];
                    }
                }
            } else {
                const float bcol = bias[col];
#pragma unroll
                for (int r=0;r<4;r++){
                    int row = rbase + r;
                    if (row < Msz){
                        float x = v[r] + bcol;
                        if (FLAGS & EPI_GELU) x = gelu_tanh(x);
                        if (FLAGS & EPI_F32) Cf[(size_t)row*Nsz + col] = x;
                        if (FLAGS & EPI_BF16){
                            uint16_t hi, lo; split_bf(x, hi, lo);
                            Cbh[(size_t)row*Nsz + col] = hi;
                            Cbl[(size_t)row*Nsz + col] = lo;
                        }
                    }
                }
            }
        }
    }
}

// ---------------------------------------------------------------------------
// tok transpose + split (unchanged)
// ---------------------------------------------------------------------------
__global__ __launch_bounds__(256)
void tok_k(const float* __restrict__ xe, const float* __restrict__ xm,
           uint16_t* __restrict__ th, uint16_t* __restrict__ tl)
{
    const int b = blockIdx.z;
    const int t0 = blockIdx.x*32, l0 = blockIdx.y*32;
    __shared__ float tile[32][33];
    const int i = threadIdx.x >> 3;
    const int j4 = (threadIdx.x & 7) * 4;
#pragma unroll
    for (int c=0;c<4;c++){
        int t = t0 + j4 + c;
        float v = 0.0f;
        if (t < 512)      v = xe[((size_t)b*LL + l0+i)*NN + t];
        else if (t < 516) v = xm[((size_t)b*LL + l0+i)*4 + (t-512)];
        tile[i][j4+c] = v;
    }
    __syncthreads();
    int t = t0 + i;
    if (t < TT){
#pragma unroll
        for (int c=0;c<4;c++){
            uint16_t hi, lo; split_bf(tile[j4+c][i], hi, lo);
            size_t idx = ((size_t)b*TT + t)*512 + l0 + j4 + c;
            th[idx] = hi; tl[idx] = lo;
        }
    }
}

// ---------------------------------------------------------------------------
// weight transpose-split (unchanged)
// ---------------------------------------------------------------------------
__global__ __launch_bounds__(256)
void wtr_k(const float* __restrict__ src, uint16_t* __restrict__ dh,
           uint16_t* __restrict__ dl, int Ksz, int Nsz, size_t zstride)
{
    const int z = blockIdx.z;
    src += (size_t)z*Ksz*Nsz; dh += (size_t)z*zstride; dl += (size_t)z*zstride;
    __shared__ float tile[32][33];
    const int kt = blockIdx.y*32, nt = blockIdx.x*32;
    const int i = threadIdx.x >> 3;
    const int j4 = (threadIdx.x & 7) * 4;
#pragma unroll
    for (int c=0;c<4;c++){
        int n = nt + j4 + c;
        tile[i][j4+c] = (n < Nsz) ? src[(size_t)(kt+i)*Nsz + n] : 0.0f;
    }
    __syncthreads();
    int n = nt + i;
    if (n < Nsz){
#pragma unroll
        for (int c=0;c<4;c++){
            uint16_t hi, lo; split_bf(tile[j4+c][i], hi, lo);
            size_t idx = (size_t)n*Ksz + kt + j4 + c;
            dh[idx] = hi; dl[idx] = lo;
        }
    }
}

__global__ void catb_k(const float* __restrict__ bq, const float* __restrict__ bk,
                       const float* __restrict__ bv, float* __restrict__ dst){
    int j = blockIdx.x*256 + threadIdx.x;
    if (j >= 3072) return;
    int layer = j / 1536, r = j - layer*1536;
    float v;
    if (r < 512)       v = bq[layer*512 + r];
    else if (r < 1024) v = bk[layer*512 + r - 512];
    else               v = bv[layer*512 + r - 1024];
    dst[j] = v;
}

// ---------------------------------------------------------------------------
// MFMA flash attention — unchanged math; occupancy bump (256,3):
// 48 KB LDS allows 3 blocks/CU, VGPR live set ~110 < 170 cap.
// ---------------------------------------------------------------------------
__global__ __launch_bounds__(256, 3)
void attnm_k(const uint16_t* __restrict__ qh, const uint16_t* __restrict__ ql,
             const uint16_t* __restrict__ kh, const uint16_t* __restrict__ kl,
             const uint16_t* __restrict__ vth, const uint16_t* __restrict__ vtl,
             uint16_t* __restrict__ oh, uint16_t* __restrict__ ol)
{
    const int qt = blockIdx.x;
    const int h  = blockIdx.y;
    const int b  = blockIdx.z;
    const int bh = b*HH + h;
    const int q0 = qt*64;
    const int tid  = threadIdx.x;
    const int lane = tid & 63;
    const int wu   = __builtin_amdgcn_readfirstlane(tid >> 6);
    const int mrow = lane & 15;
    const int kgrp = lane >> 4;

    __shared__ uint16_t Khs[4096], Kls[4096];
    __shared__ uint16_t Vhs[4096], Vls[4096];
    __shared__ uint16_t Phs[4096], Pls[4096];

    int tq = q0 + wu*16 + mrow; if (tq > TT-1) tq = TT-1;
    const uint16_t* qbase = qh + ((size_t)bh*TT + tq)*64 + kgrp*8;
    const uint16_t* qbasl = ql + ((size_t)bh*TT + tq)*64 + kgrp*8;
    bf16x8 qfh[2], qfl[2];
    qfh[0] = ldb8(qbase);      qfh[1] = ldb8(qbase + 32);
    qfl[0] = ldb8(qbasl);      qfl[1] = ldb8(qbasl + 32);

    const int srw = lane >> 3;
    const int sg  = lane & 7;

    f32x4 oacc[4];
#pragma unroll
    for (int f=0;f<4;f++) oacc[f] = (f32x4){0.f,0.f,0.f,0.f};
    float m_r[4] = {-1e30f,-1e30f,-1e30f,-1e30f};
    float l_r[4] = {0.f,0.f,0.f,0.f};

    for (int st=0; st<9; ++st){
        const int s0 = st*64;
        __syncthreads();
#pragma unroll
        for (int c=0;c<2;c++){
            const int r   = wu*16 + c*8 + srw;
            const int gsl = sg ^ (r & 7);
            int sk = s0 + r; if (sk > TT-1) sk = TT-1;
            const uint16_t* ksh_ = kh  + ((size_t)bh*TT + sk)*64 + gsl*8;
            const uint16_t* ksl_ = kl  + ((size_t)bh*TT + sk)*64 + gsl*8;
            int cb = s0 + gsl*8; if (cb > VSTR-8) cb = VSTR-8;
            const uint16_t* vsh_ = vth + ((size_t)bh*64 + r)*VSTR + cb;
            const uint16_t* vsl_ = vtl + ((size_t)bh*64 + r)*VSTR + cb;
            gl16(ksh_, &Khs[(wu*16 + c*8)*64]);
            gl16(ksl_, &Kls[(wu*16 + c*8)*64]);
            gl16(vsh_, &Vhs[(wu*16 + c*8)*64]);
            gl16(vsl_, &Vls[(wu*16 + c*8)*64]);
        }
        __syncthreads();

        f32x4 sacc[4];
#pragma unroll
        for (int f=0;f<4;f++) sacc[f] = (f32x4){0.f,0.f,0.f,0.f};
#pragma unroll
        for (int ks=0; ks<2; ks++){
#pragma unroll
            for (int f=0; f<4; f++){
                const int sr = f*16 + mrow;
                const int sl = ((ks*4 + kgrp) ^ (sr & 7))*8;
                bf16x8 kbh = ldb8(&Khs[sr*64 + sl]);
                bf16x8 kbl = ldb8(&Kls[sr*64 + sl]);
                sacc[f] = __builtin_amdgcn_mfma_f32_16x16x32_bf16(qfh[ks], kbh, sacc[f], 0,0,0);
                sacc[f] = __builtin_amdgcn_mfma_f32_16x16x32_bf16(qfh[ks], kbl, sacc[f], 0,0,0);
                sacc[f] = __builtin_amdgcn_mfma_f32_16x16x32_bf16(qfl[ks], kbh, sacc[f], 0,0,0);
            }
        }

        float alpha[4];
#pragma unroll
        for (int r=0;r<4;r++){
            float mx = -1e30f;
#pragma unroll
            for (int f=0;f<4;f++){
                float sv = sacc[f][r]*0.125f;
                if (s0 + f*16 + mrow >= TT) sv = -1e30f;
                sacc[f][r] = sv;
                mx = fmaxf(mx, sv);
            }
#pragma unroll
            for (int msk=1; msk<16; msk<<=1) mx = fmaxf(mx, __shfl_xor(mx, msk));
            float mn = fmaxf(m_r[r], mx);
            alpha[r] = __expf(m_r[r] - mn);
            m_r[r] = mn;
            float rs = 0.0f;
#pragma unroll
            for (int f=0;f<4;f++){
                float e = __expf(sacc[f][r] - mn);
                sacc[f][r] = e;
                rs += e;
            }
#pragma unroll
            for (int msk=1; msk<16; msk<<=1) rs += __shfl_xor(rs, msk);
            l_r[r] = l_r[r]*alpha[r] + rs;
#pragma unroll
            for (int f=0;f<4;f++) oacc[f][r] *= alpha[r];
        }

#pragma unroll
        for (int r=0;r<4;r++){
            const int tr = wu*16 + kgrp*4 + r;
#pragma unroll
            for (int f=0;f<4;f++){
                const int c = f*16 + mrow;
                const int idx = tr*64 + ((c>>3) ^ (tr&7))*8 + (c&7);
                uint16_t hi, lo; split_bf(sacc[f][r], hi, lo);
                Phs[idx] = hi; Pls[idx] = lo;
            }
        }

#pragma unroll
        for (int ks=0; ks<2; ks++){
            const int trr = wu*16 + mrow;
            const int psl = ((ks*4 + kgrp) ^ (trr & 7))*8;
            bf16x8 pah = ldb8(&Phs[trr*64 + psl]);
            bf16x8 pal = ldb8(&Pls[trr*64 + psl]);
#pragma unroll
            for (int f=0; f<4; f++){
                const int dr = f*16 + mrow;
                const int vsl = ((ks*4 + kgrp) ^ (dr & 7))*8;
                bf16x8 vbh = ldb8(&Vhs[dr*64 + vsl]);
                bf16x8 vbl = ldb8(&Vls[dr*64 + vsl]);
                oacc[f] = __builtin_amdgcn_mfma_f32_16x16x32_bf16(pah, vbh, oacc[f], 0,0,0);
                oacc[f] = __builtin_amdgcn_mfma_f32_16x16x32_bf16(pah, vbl, oacc[f], 0,0,0);
                oacc[f] = __builtin_amdgcn_mfma_f32_16x16x32_bf16(pal, vbh, oacc[f], 0,0,0);
            }
        }
    }

#pragma unroll
    for (int r=0;r<4;r++){
        const int t = q0 + wu*16 + kgrp*4 + r;
        if (t < TT){
            const float inv = 1.0f / l_r[r];
#pragma unroll
            for (int f=0;f<4;f++){
                const int d = f*16 + mrow;
                uint16_t hi, lo; split_bf(oacc[f][r]*inv, hi, lo);
                size_t o = ((size_t)(b*TT + t))*DD + h*DHD + d;
                oh[o] = hi; ol[o] = lo;
            }
        }
    }
}

// ---------------------------------------------------------------------------
// Residual + LayerNorm (unchanged)
// ---------------------------------------------------------------------------
__global__ __launch_bounds__(256)
void ln_k(const float* __restrict__ src, const float* __restrict__ res,
          const float* __restrict__ w, const float* __restrict__ bia,
          float* __restrict__ dst, uint16_t* __restrict__ dbh,
          uint16_t* __restrict__ dbl)
{
    const int r = blockIdx.x;
    const int tid = threadIdx.x;
    const float* sp = src + (size_t)r*DD;
    float x0 = sp[tid], x1 = sp[tid + 256];
    if (res){
        x0 += res[(size_t)r*DD + tid];
        x1 += res[(size_t)r*DD + tid + 256];
    }
    float s  = x0 + x1;
    float sq = x0*x0 + x1*x1;
#pragma unroll
    for (int msk=1; msk<64; msk<<=1){
        s  += __shfl_xor(s,  msk);
        sq += __shfl_xor(sq, msk);
    }
    __shared__ float sm[8];
    int wv = tid >> 6, ln = tid & 63;
    if (ln == 0){ sm[wv] = s; sm[wv+4] = sq; }
    __syncthreads();
    s  = sm[0]+sm[1]+sm[2]+sm[3];
    sq = sm[4]+sm[5]+sm[6]+sm[7];
    float mu  = s * (1.0f/512.0f);
    float var = sq * (1.0f/512.0f) - mu*mu;
    float rsd = rsqrtf(var + 1e-5f);
    float y0 = (x0 - mu)*rsd*w[tid]       + bia[tid];
    float y1 = (x1 - mu)*rsd*w[tid + 256] + bia[tid + 256];
    dst[(size_t)r*DD + tid]       = y0;
    dst[(size_t)r*DD + tid + 256] = y1;
    uint16_t hi, lo;
    split_bf(y0, hi, lo); dbh[(size_t)r*DD + tid] = hi;       dbl[(size_t)r*DD + tid] = lo;
    split_bf(y1, hi, lo); dbh[(size_t)r*DD + tid + 256] = hi; dbl[(size_t)r*DD + tid + 256] = lo;
}

// ---------------------------------------------------------------------------
// sims v4: software-pipelined (issue stage st+1 loads BEFORE computing st,
// so HBM latency hides under compute) + occupancy 4 blocks/CU.
// ---------------------------------------------------------------------------
__global__ __launch_bounds__(256, 4)
void sims_k(const float* __restrict__ pred, const float* __restrict__ bank,
            float* __restrict__ dotp, float* __restrict__ nrmp)
{
    const int jt = blockIdx.x, kt = blockIdx.y;
    const int tid  = threadIdx.x;
    const int qq    = tid & 7;
    const int slice = tid >> 3;
    const int sb    = slice*8;
    const int srow  = tid >> 4;
    const int tau   = tid & 15;

    __shared__ float BS[16*264];

    const int jr = jt*16 + srow;
    const float* bsrc = (jr < MM) ? (bank + (size_t)jr*PN)
                                  : (pred + (size_t)(jr - MM)*PN);
    bsrc += (size_t)kt*SCHUNK + tau*4;
    const float* p0 = pred + (size_t)qq*PN      + (size_t)kt*SCHUNK + sb;
    const float* p1 = pred + (size_t)(qq+8)*PN  + (size_t)kt*SCHUNK + sb;

    float acc0[16], acc1[16];
#pragma unroll
    for (int j=0;j<16;j++){ acc0[j] = 0.0f; acc1[j] = 0.0f; }
    float nr = 0.0f;

    // preload stage 0
    float4 blv[4], pr0[2], pr1[2];
#pragma unroll
    for (int c=0;c<4;c++) blv[c] = *(const float4*)(bsrc + c*64);
    pr0[0] = *(const float4*)(p0); pr0[1] = *(const float4*)(p0 + 4);
    pr1[0] = *(const float4*)(p1); pr1[1] = *(const float4*)(p1 + 4);
    bsrc += 256; p0 += 256; p1 += 256;

    for (int st=0; st<SSTG; ++st){
        // write current stage to LDS (BS free: first iter or bottom barrier)
#pragma unroll
        for (int c=0;c<4;c++){
            *(float4*)&BS[srow*264 + tau*4 + c*64] = blv[c];
            nr = fmaf(blv[c].x, blv[c].x, nr);
            nr = fmaf(blv[c].y, blv[c].y, nr);
            nr = fmaf(blv[c].z, blv[c].z, nr);
            nr = fmaf(blv[c].w, blv[c].w, nr);
        }
        // keep current pred regs for compute
        float4 cp0[2] = {pr0[0], pr0[1]};
        float4 cp1[2] = {pr1[0], pr1[1]};
        // issue next-stage loads (latency hides under compute below)
        if (st + 1 < SSTG){
#pragma unroll
            for (int c=0;c<4;c++) blv[c] = *(const float4*)(bsrc + c*64);
            pr0[0] = *(const float4*)(p0); pr0[1] = *(const float4*)(p0 + 4);
            pr1[0] = *(const float4*)(p1); pr1[1] = *(const float4*)(p1 + 4);
            bsrc += 256; p0 += 256; p1 += 256;
        }
        __syncthreads();   // LDS writes visible
#pragma unroll
        for (int j=0;j<16;j++){
            float4 b0 = *(const float4*)&BS[j*264 + sb];
            float4 b1 = *(const float4*)&BS[j*264 + sb + 4];
            float a0 = acc0[j], a1 = acc1[j];
            a0 = fmaf(b0.x, cp0[0].x, a0); a0 = fmaf(b0.y, cp0[0].y, a0);
            a0 = fmaf(b0.z, cp0[0].z, a0); a0 = fmaf(b0.w, cp0[0].w, a0);
            a0 = fmaf(b1.x, cp0[1].x, a0); a0 = fmaf(b1.y, cp0[1].y, a0);
            a0 = fmaf(b1.z, cp0[1].z, a0); a0 = fmaf(b1.w, cp0[1].w, a0);
            a1 = fmaf(b0.x, cp1[0].x, a1); a1 = fmaf(b0.y, cp1[0].y, a1);
            a1 = fmaf(b0.z, cp1[0].z, a1); a1 = fmaf(b0.w, cp1[0].w, a1);
            a1 = fmaf(b1.x, cp1[1].x, a1); a1 = fmaf(b1.y, cp1[1].y, a1);
            a1 = fmaf(b1.z, cp1[1].z, a1); a1 = fmaf(b1.w, cp1[1].w, a1);
            acc0[j] = a0; acc1[j] = a1;
        }
        __syncthreads();   // compute done; BS free for next write
    }

#pragma unroll
    for (int m=8; m<64; m<<=1){
#pragma unroll
        for (int j=0;j<16;j++){
            acc0[j] += __shfl_xor(acc0[j], m);
            acc1[j] += __shfl_xor(acc1[j], m);
        }
    }
#pragma unroll
    for (int m=1;m<16;m<<=1) nr += __shfl_xor(nr, m);

    __syncthreads();
    float* RED = BS;
    const int wu2  = tid >> 6;
    const int lane = tid & 63;
    if (lane < 8){
#pragma unroll
        for (int j=0;j<16;j++){
            RED[(wu2*16 + j)*16 + lane]     = acc0[j];
            RED[(wu2*16 + j)*16 + lane + 8] = acc1[j];
        }
    }
    __syncthreads();
    const int j2 = tid >> 4, q2 = tid & 15;
    float s = RED[(0*16 + j2)*16 + q2] + RED[(1*16 + j2)*16 + q2]
            + RED[(2*16 + j2)*16 + q2] + RED[(3*16 + j2)*16 + q2];
    dotp[((size_t)kt*528 + jt*16 + j2)*16 + q2] = s;
    if (tau == 0) nrmp[kt*528 + jt*16 + srow] = nr;
}

__global__ void norms_k(const float* __restrict__ nrmp, float* __restrict__ invn){
    int j = blockIdx.x*blockDim.x + threadIdx.x;
    if (j < 528){
        float s = 0.0f;
        for (int kt=0; kt<SKC; kt++) s += nrmp[kt*528 + j];
        invn[j] = 1.0f/(sqrtf(s) + 1e-8f);
    }
}

__global__ void simsfin_k(const float* __restrict__ dotp, const float* __restrict__ invn,
                          float* __restrict__ sims){
    int fid = blockIdx.x*256 + threadIdx.x;
    int j = fid >> 4, q = fid & 15;
    float s = 0.0f;
    for (int kt=0; kt<SKC; kt++) s += dotp[((size_t)kt*528 + j)*16 + q];
    sims[q*528 + j] = s * invn[j] * invn[MM + q];
}

__global__ __launch_bounds__(64)
void topk_k(const float* __restrict__ sims, int* __restrict__ idx){
    const int q = blockIdx.x;
    const int lane = threadIdx.x;
    __shared__ float vals[528];
    for (int j=lane; j<528; j+=64) vals[j] = sims[q*528 + j];
    __syncthreads();
    for (int kk=0; kk<KNN; kk++){
        float bv = -3.0e38f; int bi = 1<<30;
        for (int j=lane; j<528; j+=64){
            float v2 = vals[j];
            if (v2 > bv || (v2 == bv && j < bi)){ bv = v2; bi = j; }
        }
#pragma unroll
        for (int msk=1; msk<64; msk<<=1){
            float ov = __shfl_xor(bv, msk);
            int   oi = __shfl_xor(bi, msk);
            if (ov > bv || (ov == bv && oi < bi)){ bv = ov; bi = oi; }
        }
        if (lane == 0){
            idx[q*KNN + kk] = bi;
            vals[bi] = -3.0e38f;
        }
        __syncthreads();
    }
}

__global__ __launch_bounds__(256)
void fuse_k(const float* __restrict__ pred, const float* __restrict__ bank,
            const int* __restrict__ idx, float* __restrict__ out){
    int u = blockIdx.x*256 + threadIdx.x;
    int b = u / (PN/4);
    int e = (u - b*(PN/4)) * 4;
    int id[KNN];
#pragma unroll
    for (int k2=0;k2<KNN;k2++) id[k2] = idx[b*KNN + k2];
    float4 pv = *(const float4*)(pred + (size_t)b*PN + e);
    float ax = 0.5f*pv.x, ay = 0.5f*pv.y, az = 0.5f*pv.z, aw = 0.5f*pv.w;
#pragma unroll
    for (int k2=0;k2<KNN;k2++){
        const float* rp = (id[k2] < MM) ? (bank + (size_t)id[k2]*PN)
                                        : (pred + (size_t)(id[k2]-MM)*PN);
        float4 rv = *(const float4*)(rp + e);
        ax = fmaf(0.05f, rv.x, ax); ay = fmaf(0.05f, rv.y, ay);
        az = fmaf(0.05f, rv.z, az); aw = fmaf(0.05f, rv.w, aw);
    }
    float4 ov; ov.x=ax; ov.y=ay; ov.z=az; ov.w=aw;
    *(float4*)(out + (size_t)b*PN + e) = ov;
}

// ---------------------------------------------------------------------------
extern "C" void kernel_launch(void* const* d_in, const int* in_sizes, int n_in,
                              void* d_out, int out_size, void* d_ws, size_t ws_size,
                              hipStream_t stream)
{
    (void)in_sizes; (void)n_in; (void)out_size; (void)ws_size;
    const float* x_enc  = (const float*)d_in[0];
    const float* x_mark = (const float*)d_in[1];
    const float* W_emb  = (const float*)d_in[4];
    const float* b_emb  = (const float*)d_in[5];
    const float* Wq  = (const float*)d_in[6];
    const float* Wk  = (const float*)d_in[7];
    const float* Wv  = (const float*)d_in[8];
    const float* Wo  = (const float*)d_in[9];
    const float* bq  = (const float*)d_in[10];
    const float* bk  = (const float*)d_in[11];
    const float* bv_ = (const float*)d_in[12];
    const float* bo  = (const float*)d_in[13];
    const float* ln1w = (const float*)d_in[14];
    const float* ln1b = (const float*)d_in[15];
    const float* ln2w = (const float*)d_in[16];
    const float* ln2b = (const float*)d_in[17];
    const float* Wff1 = (const float*)d_in[18];
    const float* bff1 = (const float*)d_in[19];
    const float* Wff2 = (const float*)d_in[20];
    const float* bff2 = (const float*)d_in[21];
    const float* lnfw = (const float*)d_in[22];
    const float* lnfb = (const float*)d_in[23];
    const float* Wproj = (const float*)d_in[24];
    const float* bproj = (const float*)d_in[25];
    const float* bank  = (const float*)d_in[26];
    float* out = (float*)d_out;

    char* pp = (char*)d_ws;
    auto a16 = [&](size_t elems)->uint16_t*{ uint16_t* r=(uint16_t*)pp; pp += ((elems*2 + 255)/256)*256; return r; };
    auto af  = [&](size_t elems)->float*  { float* r=(float*)pp;  pp += ((elems*4 + 255)/256)*256; return r; };

    uint16_t* wembT_h = a16(262144);        uint16_t* wembT_l = a16(262144);
    uint16_t* wqkvT_h = a16(2*1536*512);    uint16_t* wqkvT_l = a16(2*1536*512);
    uint16_t* woT_h   = a16(2*262144);      uint16_t* woT_l   = a16(2*262144);
    uint16_t* wff1T_h = a16(2*2048*512);    uint16_t* wff1T_l = a16(2*2048*512);
    uint16_t* wff2T_h = a16(2*512*2048);    uint16_t* wff2T_l = a16(2*512*2048);
    uint16_t* wprjT_h = a16(172032);        uint16_t* wprjT_l = a16(172032);
    float*    bqkv    = af(3072);
    uint16_t* hb_h    = a16((size_t)BT*512);
    uint16_t* hb_l    = a16((size_t)BT*512);
    uint16_t* tok_h   = a16((size_t)BT*512);     // og fp32 aliases tok region
    uint16_t* tok_l   = a16((size_t)BT*512);
    float*    og      = (float*)tok_h;
    uint16_t* qsh     = a16((size_t)128*TT*64);
    uint16_t* qsl     = a16((size_t)128*TT*64);
    uint16_t* ksh     = a16((size_t)128*TT*64);
    uint16_t* ksl     = a16((size_t)128*TT*64);
    uint16_t* vsh     = a16((size_t)128*64*VSTR + 4096);
    uint16_t* vsl     = a16((size_t)128*64*VSTR + 4096);
    uint16_t* t1b_h   = a16((size_t)BT*512);
    uint16_t* t1b_l   = a16((size_t)BT*512);
    uint16_t* midb_h  = qsh;                     // mid aliases qsh..t1b region
    uint16_t* midb_l  = midb_h + (size_t)BT*2048;
    float*    h       = af((size_t)BT*512);
    float*    pred    = af((size_t)BB*PN);
    float*    dotp    = af((size_t)SKC*528*16);
    float*    nrmp    = af(SKC*528);
    float*    invn    = af(528);
    float*    sims    = af(16*528);
    int*      idxp    = (int*)af(256);

    dim3 blk(256);

    tok_k<<<dim3(17,16,BB), blk, 0, stream>>>(x_enc, x_mark, tok_h, tok_l);
    wtr_k<<<dim3(16,16,1), blk, 0, stream>>>(W_emb, wembT_h, wembT_l, 512, 512, 262144);
    wtr_k<<<dim3(16,16,2), blk, 0, stream>>>(Wq, wqkvT_h,          wqkvT_l,          512, 512, 786432);
    wtr_k<<<dim3(16,16,2), blk, 0, stream>>>(Wk, wqkvT_h + 262144, wqkvT_l + 262144, 512, 512, 786432);
    wtr_k<<<dim3(16,16,2), blk, 0, stream>>>(Wv, wqkvT_h + 524288, wqkvT_l + 524288, 512, 512, 786432);
    wtr_k<<<dim3(16,16,2), blk, 0, stream>>>(Wo, woT_h, woT_l, 512, 512, 262144);
    wtr_k<<<dim3(64,16,2), blk, 0, stream>>>(Wff1, wff1T_h, wff1T_l, 512, 2048, 1048576);
    wtr_k<<<dim3(16,64,2), blk, 0, stream>>>(Wff2, wff2T_h, wff2T_l, 2048, 512, 1048576);
    wtr_k<<<dim3(11,16,1), blk, 0, stream>>>(Wproj, wprjT_h, wprjT_l, 512, 336, 172032);
    catb_k<<<dim3(12), blk, 0, stream>>>(bq, bk, bv_, bqkv);

    bgemm64<EPI_F32|EPI_BF16><<<dim3(8,65), blk, 0, stream>>>(
        tok_h, tok_l, wembT_h, wembT_l, b_emb, h, hb_h, hb_l, BT, 512, 512);

    for (int i=0;i<2;i++){
        bgemm<EPI_QKV><<<dim3(12,65), blk, 0, stream>>>(
            hb_h, hb_l, wqkvT_h + (size_t)i*786432, wqkvT_l + (size_t)i*786432,
            bqkv + i*1536, nullptr, qsh, qsl, ksh, ksl, vsh, vsl, BT, 1536, 512);
        attnm_k<<<dim3(9,HH,BB), blk, 0, stream>>>(qsh, qsl, ksh, ksl, vsh, vsl, t1b_h, t1b_l);
        bgemm64<EPI_F32><<<dim3(8,65), blk, 0, stream>>>(
            t1b_h, t1b_l, woT_h + (size_t)i*262144, woT_l + (size_t)i*262144,
            bo + i*512, og, nullptr, nullptr, BT, 512, 512);
        ln_k<<<BT, blk, 0, stream>>>(h, og, ln1w + i*512, ln1b + i*512, h, hb_h, hb_l);
        bgemm<EPI_GELU|EPI_BF16><<<dim3(16,65), blk, 0, stream>>>(
            hb_h, hb_l, wff1T_h + (size_t)i*1048576, wff1T_l + (size_t)i*1048576,
            bff1 + i*DFFN, nullptr, midb_h, midb_l,
            nullptr, nullptr, nullptr, nullptr, BT, DFFN, 512);
        bgemm64<EPI_F32><<<dim3(8,65), blk, 0, stream>>>(
            midb_h, midb_l, wff2T_h + (size_t)i*1048576, wff2T_l + (size_t)i*1048576,
            bff2 + i*512, og, nullptr, nullptr, BT, 512, DFFN);
        ln_k<<<BT, blk, 0, stream>>>(h, og, ln2w + i*512, ln2b + i*512, h, hb_h, hb_l);
    }

    ln_k<<<BT, blk, 0, stream>>>(h, nullptr, lnfw, lnfb, h, hb_h, hb_l);

    bgemm64<EPI_PREDT><<<dim3(6,65), blk, 0, stream>>>(
        hb_h, hb_l, wprjT_h, wprjT_l, bproj, pred, nullptr, nullptr, BT, PP, 512);

    sims_k<<<dim3(33,SKC), blk, 0, stream>>>(pred, bank, dotp, nrmp);
    norms_k<<<dim3(3), blk, 0, stream>>>(nrmp, invn);
    simsfin_k<<<dim3(33), blk, 0, stream>>>(dotp, invn, sims);
    topk_k<<<dim3(BB), dim3(64), 0, stream>>>(sims, idxp);
    fuse_k<<<dim3((BB*PN/4)/256), blk, 0, stream>>>(pred, bank, idxp, out);
}

// Round 10
// 1044.809 us; speedup vs baseline: 1.1702x; 1.0770x over previous
//
#include <hip/hip_runtime.h>
#include <stdint.h>
#include <math.h>

#define TT 516
#define BB 16
#define DD 512
#define LL 512
#define NN 512
#define HH 8
#define DHD 64
#define DFFN 2048
#define PP 336
#define MM 512
#define KNN 10
#define BT (BB*TT)      /* 8256 */
#define PN (PP*NN)      /* 172032 */
#define SKC 32          /* sims k-chunks */
#define SCHUNK (PN/SKC) /* 5376 */
#define SSTG (SCHUNK/256) /* 21 stages */
#define VSTR 528        /* transposed-V row stride (uint16 elems) */

using f32x4  = __attribute__((ext_vector_type(4))) float;
using bf16x8 = __attribute__((ext_vector_type(8))) __bf16;
using u16x8  = __attribute__((ext_vector_type(8))) unsigned short;

__device__ __forceinline__ float gelu_tanh(float x){
    float x3 = x*x*x;
    return 0.5f*x*(1.0f + tanhf(0.7978845608028654f*(x + 0.044715f*x3)));
}

__device__ __forceinline__ uint16_t f2bf(float x){
    uint32_t u = __builtin_bit_cast(uint32_t, x);
    uint32_t r = (u + 0x7FFFu + ((u >> 16) & 1u)) >> 16;
    return (uint16_t)r;
}

__device__ __forceinline__ void split_bf(float x, uint16_t& hi, uint16_t& lo){
    uint32_t u  = __builtin_bit_cast(uint32_t, x);
    uint32_t hr = (u + 0x7FFFu + ((u >> 16) & 1u)) & 0xFFFF0000u;
    float hf = __builtin_bit_cast(float, hr);
    hi = (uint16_t)(hr >> 16);
    lo = f2bf(x - hf);
}

__device__ __forceinline__ void gl16(const uint16_t* g, uint16_t* l){
    __builtin_amdgcn_global_load_lds(
        (const __attribute__((address_space(1))) unsigned int*)(const void*)g,
        (__attribute__((address_space(3))) unsigned int*)(void*)l, 16, 0, 0);
}

__device__ __forceinline__ bf16x8 ldb8(const uint16_t* p){
    return __builtin_bit_cast(bf16x8, *(const u16x8*)p);
}

#define EPI_F32   1
#define EPI_BF16  2
#define EPI_GELU  4
#define EPI_PREDT 8
#define EPI_QKV   16

// ---------------------------------------------------------------------------
// Split-bf16 MFMA GEMM, BN=128, BK=32. EPI_QKV now writes PLAIN bf16 q/k/v
// (q pre-scaled by 1/8); attention tolerates bf16 internals (see round-10
// flip-margin analysis: dsim ~5e-6 << gap 1.7e-4).
// ---------------------------------------------------------------------------
template<int FLAGS>
__global__ __launch_bounds__(256)
void bgemm(const uint16_t* __restrict__ Ah, const uint16_t* __restrict__ Al,
           const uint16_t* __restrict__ Bh, const uint16_t* __restrict__ Bl,
           const float* __restrict__ bias, float* __restrict__ Cf,
           uint16_t* __restrict__ Cbh, uint16_t* __restrict__ Cbl,
           uint16_t* __restrict__ Xkh, uint16_t* __restrict__ Xvh,
           int Msz, int Nsz, int Ksz)
{
    constexpr int BN = 128;
    constexpr int FN = 4;
    __shared__ uint16_t As0[4096], As1[4096];
    __shared__ uint16_t Bs0[BN*32], Bs1[BN*32];

    const int tid  = threadIdx.x;
    const int lane = tid & 63;
    const int wu   = __builtin_amdgcn_readfirstlane(tid >> 6);
    const int wm   = wu >> 1, wn = wu & 1;
    const int m0   = blockIdx.y * 128;
    const int n0   = blockIdx.x * BN;

    const int r0c = tid >> 2;
    const int cc  = tid & 3;
    const int sw  = (r0c ^ (r0c >> 2)) & 3;
    const int csw = (cc ^ sw) * 8;
    int rA0 = m0 + r0c;      if (rA0 > Msz-1) rA0 = Msz-1;
    int rA1 = m0 + r0c + 64; if (rA1 > Msz-1) rA1 = Msz-1;
    int rB0 = n0 + r0c;      if (rB0 > Nsz-1) rB0 = Nsz-1;
    int rB1 = n0 + r0c + 64; if (rB1 > Nsz-1) rB1 = Nsz-1;
    const uint16_t* pAh0 = Ah + (size_t)rA0*Ksz + csw;
    const uint16_t* pAh1 = Ah + (size_t)rA1*Ksz + csw;
    const uint16_t* pAl0 = Al + (size_t)rA0*Ksz + csw;
    const uint16_t* pAl1 = Al + (size_t)rA1*Ksz + csw;
    const uint16_t* pBh0 = Bh + (size_t)rB0*Ksz + csw;
    const uint16_t* pBh1 = Bh + (size_t)rB1*Ksz + csw;
    const uint16_t* pBl0 = Bl + (size_t)rB0*Ksz + csw;
    const uint16_t* pBl1 = Bl + (size_t)rB1*Ksz + csw;

    f32x4 acc[4][FN];
#pragma unroll
    for (int i=0;i<4;i++)
#pragma unroll
        for (int j=0;j<FN;j++) acc[i][j] = (f32x4){0.f,0.f,0.f,0.f};

    const int lc16  = lane & 15;
    const int slot8 = (((lane>>4) ^ (lane&3) ^ ((lane>>2)&3))) * 8;
    const int rAf   = (wm*64 + lc16) * 32 + slot8;
    const int rBf   = (wn*(BN/2) + lc16) * 32 + slot8;

    for (int kt = 0; kt < Ksz; kt += 32){
        gl16(pAh0 + kt, &As0[wu*512]);
        gl16(pAh1 + kt, &As0[2048 + wu*512]);
        gl16(pAl0 + kt, &As1[wu*512]);
        gl16(pAl1 + kt, &As1[2048 + wu*512]);
        gl16(pBh0 + kt, &Bs0[wu*512]);
        gl16(pBh1 + kt, &Bs0[2048 + wu*512]);
        gl16(pBl0 + kt, &Bs1[wu*512]);
        gl16(pBl1 + kt, &Bs1[2048 + wu*512]);
        __syncthreads();

        bf16x8 ah[4], al[4];
#pragma unroll
        for (int fm=0; fm<4; fm++){
            ah[fm] = ldb8(&As0[rAf + fm*512]);
            al[fm] = ldb8(&As1[rAf + fm*512]);
        }
#pragma unroll
        for (int fn=0; fn<FN; fn++){
            bf16x8 bh = ldb8(&Bs0[rBf + fn*512]);
            bf16x8 bl = ldb8(&Bs1[rBf + fn*512]);
#pragma unroll
            for (int fm=0; fm<4; fm++){
                acc[fm][fn] = __builtin_amdgcn_mfma_f32_16x16x32_bf16(ah[fm], bh, acc[fm][fn], 0,0,0);
                acc[fm][fn] = __builtin_amdgcn_mfma_f32_16x16x32_bf16(ah[fm], bl, acc[fm][fn], 0,0,0);
                acc[fm][fn] = __builtin_amdgcn_mfma_f32_16x16x32_bf16(al[fm], bh, acc[fm][fn], 0,0,0);
            }
        }
        __syncthreads();
    }

    const int lr4 = (lane >> 4) * 4;
#pragma unroll
    for (int fm=0; fm<4; fm++){
        const int rbase = m0 + wm*64 + fm*16 + lr4;
#pragma unroll
        for (int fn=0; fn<FN; fn++){
            const int col = n0 + wn*(BN/2) + fn*16 + lc16;
            f32x4 v = acc[fm][fn];
            if (FLAGS & EPI_QKV){
                const int g   = col >> 9;
                const int cc2 = col & 511;
                const int hh2 = cc2 >> 6, dd2 = cc2 & 63;
                const float bcol = bias[col];
#pragma unroll
                for (int r=0;r<4;r++){
                    int row = rbase + r;
                    if (row < Msz){
                        float x = v[r] + bcol;
                        int b2 = row / TT, t2 = row - b2*TT;
                        int bh2 = b2*HH + hh2;
                        if (g == 0){
                            size_t o = ((size_t)bh2*TT + t2)*64 + dd2;
                            Cbh[o] = f2bf(x * 0.125f);     // fold softmax scale into Q
                        } else if (g == 1){
                            size_t o = ((size_t)bh2*TT + t2)*64 + dd2;
                            Xkh[o] = f2bf(x);
                        } else {
                            size_t o = ((size_t)bh2*64 + dd2)*VSTR + t2;
                            Xvh[o] = f2bf(x);
                        }
                    }
                }
            } else {
                const float bcol = bias[col];
#pragma unroll
                for (int r=0;r<4;r++){
                    int row = rbase + r;
                    if (row < Msz){
                        float x = v[r] + bcol;
                        if (FLAGS & EPI_GELU) x = gelu_tanh(x);
                        if (FLAGS & EPI_F32) Cf[(size_t)row*Nsz + col] = x;
                        if (FLAGS & EPI_BF16){
                            uint16_t hi, lo; split_bf(x, hi, lo);
                            Cbh[(size_t)row*Nsz + col] = hi;
                            Cbl[(size_t)row*Nsz + col] = lo;
                        }
                    }
                }
            }
        }
    }
}

// ---------------------------------------------------------------------------
// BN=64, BK=64 split-bf16 GEMM (unchanged from round 8)
// ---------------------------------------------------------------------------
template<int FLAGS>
__global__ __launch_bounds__(256, 3)
void bgemm64(const uint16_t* __restrict__ Ah, const uint16_t* __restrict__ Al,
             const uint16_t* __restrict__ Bh, const uint16_t* __restrict__ Bl,
             const float* __restrict__ bias, float* __restrict__ Cf,
             uint16_t* __restrict__ Cbh, uint16_t* __restrict__ Cbl,
             int Msz, int Nsz, int Ksz)
{
    __shared__ uint16_t As0[8192], As1[8192];
    __shared__ uint16_t Bs0[4096], Bs1[4096];

    const int tid  = threadIdx.x;
    const int lane = tid & 63;
    const int wu   = __builtin_amdgcn_readfirstlane(tid >> 6);
    const int wm   = wu >> 1, wn = wu & 1;
    const int m0   = blockIdx.y * 128;
    const int n0   = blockIdx.x * 64;

    const int sr8 = lane >> 3;
    const int skw = (((lane & 7) ^ sr8) * 8);

    int rA[4], rB[2];
#pragma unroll
    for (int i=0;i<4;i++){
        int r = m0 + (wu*4 + i)*8 + sr8;
        rA[i] = (r > Msz-1) ? Msz-1 : r;
    }
#pragma unroll
    for (int i=0;i<2;i++){
        int r = n0 + (wu*2 + i)*8 + sr8;
        rB[i] = (r > Nsz-1) ? Nsz-1 : r;
    }

    f32x4 acc[4][2];
#pragma unroll
    for (int i=0;i<4;i++)
#pragma unroll
        for (int j=0;j<2;j++) acc[i][j] = (f32x4){0.f,0.f,0.f,0.f};

    const int lc16 = lane & 15;
    const int kgrp = lane >> 4;

    for (int kt = 0; kt < Ksz; kt += 64){
#pragma unroll
        for (int i=0;i<4;i++){
            gl16(Ah + (size_t)rA[i]*Ksz + kt + skw, &As0[(wu*4 + i)*512]);
            gl16(Al + (size_t)rA[i]*Ksz + kt + skw, &As1[(wu*4 + i)*512]);
        }
#pragma unroll
        for (int i=0;i<2;i++){
            gl16(Bh + (size_t)rB[i]*Ksz + kt + skw, &Bs0[(wu*2 + i)*512]);
            gl16(Bl + (size_t)rB[i]*Ksz + kt + skw, &Bs1[(wu*2 + i)*512]);
        }
        __syncthreads();

#pragma unroll
        for (int ks=0; ks<2; ks++){
            bf16x8 ah[4], al[4];
#pragma unroll
            for (int fm=0; fm<4; fm++){
                const int r   = wm*64 + fm*16 + lc16;
                const int off = r*64 + (((ks*4 + kgrp) ^ (r & 7))*8);
                ah[fm] = ldb8(&As0[off]);
                al[fm] = ldb8(&As1[off]);
            }
#pragma unroll
            for (int fn=0; fn<2; fn++){
                const int rb   = wn*32 + fn*16 + lc16;
                const int offb = rb*64 + (((ks*4 + kgrp) ^ (rb & 7))*8);
                bf16x8 bh = ldb8(&Bs0[offb]);
                bf16x8 bl = ldb8(&Bs1[offb]);
#pragma unroll
                for (int fm=0; fm<4; fm++){
                    acc[fm][fn] = __builtin_amdgcn_mfma_f32_16x16x32_bf16(ah[fm], bh, acc[fm][fn], 0,0,0);
                    acc[fm][fn] = __builtin_amdgcn_mfma_f32_16x16x32_bf16(ah[fm], bl, acc[fm][fn], 0,0,0);
                    acc[fm][fn] = __builtin_amdgcn_mfma_f32_16x16x32_bf16(al[fm], bh, acc[fm][fn], 0,0,0);
                }
            }
        }
        __syncthreads();
    }

    const int lr4 = (lane >> 4) * 4;
#pragma unroll
    for (int fm=0; fm<4; fm++){
        const int rbase = m0 + wm*64 + fm*16 + lr4;
#pragma unroll
        for (int fn=0; fn<2; fn++){
            const int col = n0 + wn*32 + fn*16 + lc16;
            f32x4 v = acc[fm][fn];
            if (FLAGS & EPI_PREDT){
#pragma unroll
                for (int r=0;r<4;r++){
                    int row = rbase + r;
                    if (row < Msz && col < PP){
                        int b = row / TT, t = row - b*TT;
                        if (t < NN)
                            Cf[((size_t)b*PP + col)*NN + t] = v[r] + bias[col];
                    }
                }
            } else {
                const float bcol = bias[col];
#pragma unroll
                for (int r=0;r<4;r++){
                    int row = rbase + r;
                    if (row < Msz){
                        float x = v[r] + bcol;
                        if (FLAGS & EPI_GELU) x = gelu_tanh(x);
                        if (FLAGS & EPI_F32) Cf[(size_t)row*Nsz + col] = x;
                        if (FLAGS & EPI_BF16){
                            uint16_t hi, lo; split_bf(x, hi, lo);
                            Cbh[(size_t)row*Nsz + col] = hi;
                            Cbl[(size_t)row*Nsz + col] = lo;
                        }
                    }
                }
            }
        }
    }
}

// ---------------------------------------------------------------------------
// tok transpose + split (unchanged)
// ---------------------------------------------------------------------------
__global__ __launch_bounds__(256)
void tok_k(const float* __restrict__ xe, const float* __restrict__ xm,
           uint16_t* __restrict__ th, uint16_t* __restrict__ tl)
{
    const int b = blockIdx.z;
    const int t0 = blockIdx.x*32, l0 = blockIdx.y*32;
    __shared__ float tile[32][33];
    const int i = threadIdx.x >> 3;
    const int j4 = (threadIdx.x & 7) * 4;
#pragma unroll
    for (int c=0;c<4;c++){
        int t = t0 + j4 + c;
        float v = 0.0f;
        if (t < 512)      v = xe[((size_t)b*LL + l0+i)*NN + t];
        else if (t < 516) v = xm[((size_t)b*LL + l0+i)*4 + (t-512)];
        tile[i][j4+c] = v;
    }
    __syncthreads();
    int t = t0 + i;
    if (t < TT){
#pragma unroll
        for (int c=0;c<4;c++){
            uint16_t hi, lo; split_bf(tile[j4+c][i], hi, lo);
            size_t idx = ((size_t)b*TT + t)*512 + l0 + j4 + c;
            th[idx] = hi; tl[idx] = lo;
        }
    }
}

// ---------------------------------------------------------------------------
// weight transpose-split (unchanged)
// ---------------------------------------------------------------------------
__global__ __launch_bounds__(256)
void wtr_k(const float* __restrict__ src, uint16_t* __restrict__ dh,
           uint16_t* __restrict__ dl, int Ksz, int Nsz, size_t zstride)
{
    const int z = blockIdx.z;
    src += (size_t)z*Ksz*Nsz; dh += (size_t)z*zstride; dl += (size_t)z*zstride;
    __shared__ float tile[32][33];
    const int kt = blockIdx.y*32, nt = blockIdx.x*32;
    const int i = threadIdx.x >> 3;
    const int j4 = (threadIdx.x & 7) * 4;
#pragma unroll
    for (int c=0;c<4;c++){
        int n = nt + j4 + c;
        tile[i][j4+c] = (n < Nsz) ? src[(size_t)(kt+i)*Nsz + n] : 0.0f;
    }
    __syncthreads();
    int n = nt + i;
    if (n < Nsz){
#pragma unroll
        for (int c=0;c<4;c++){
            uint16_t hi, lo; split_bf(tile[j4+c][i], hi, lo);
            size_t idx = (size_t)n*Ksz + kt + j4 + c;
            dh[idx] = hi; dl[idx] = lo;
        }
    }
}

__global__ void catb_k(const float* __restrict__ bq, const float* __restrict__ bk,
                       const float* __restrict__ bv, float* __restrict__ dst){
    int j = blockIdx.x*256 + threadIdx.x;
    if (j >= 3072) return;
    int layer = j / 1536, r = j - layer*1536;
    float v;
    if (r < 512)       v = bq[layer*512 + r];
    else if (r < 1024) v = bk[layer*512 + r - 512];
    else               v = bv[layer*512 + r - 1024];
    dst[j] = v;
}

// ---------------------------------------------------------------------------
// MFMA flash attention, PLAIN bf16 Q/K/V/P (1-pass MFMA), fp32 softmax,
// split-bf16 output. 24 KB LDS -> 4 blocks/CU. Q pre-scaled by 1/8.
// ---------------------------------------------------------------------------
__global__ __launch_bounds__(256, 4)
void attnm_k(const uint16_t* __restrict__ qs, const uint16_t* __restrict__ ks,
             const uint16_t* __restrict__ vts,
             uint16_t* __restrict__ oh, uint16_t* __restrict__ ol)
{
    const int qt = blockIdx.x;
    const int h  = blockIdx.y;
    const int b  = blockIdx.z;
    const int bh = b*HH + h;
    const int q0 = qt*64;
    const int tid  = threadIdx.x;
    const int lane = tid & 63;
    const int wu   = __builtin_amdgcn_readfirstlane(tid >> 6);
    const int mrow = lane & 15;
    const int kgrp = lane >> 4;

    __shared__ uint16_t Khs[4096];
    __shared__ uint16_t Vhs[4096];
    __shared__ uint16_t Phs[4096];

    int tq = q0 + wu*16 + mrow; if (tq > TT-1) tq = TT-1;
    const uint16_t* qbase = qs + ((size_t)bh*TT + tq)*64 + kgrp*8;
    bf16x8 qfh[2];
    qfh[0] = ldb8(qbase);      qfh[1] = ldb8(qbase + 32);

    const int srw = lane >> 3;
    const int sg  = lane & 7;

    f32x4 oacc[4];
#pragma unroll
    for (int f=0;f<4;f++) oacc[f] = (f32x4){0.f,0.f,0.f,0.f};
    float m_r[4] = {-1e30f,-1e30f,-1e30f,-1e30f};
    float l_r[4] = {0.f,0.f,0.f,0.f};

    for (int st=0; st<9; ++st){
        const int s0 = st*64;
        __syncthreads();
#pragma unroll
        for (int c=0;c<2;c++){
            const int r   = wu*16 + c*8 + srw;
            const int gsl = sg ^ (r & 7);
            int sk = s0 + r; if (sk > TT-1) sk = TT-1;
            const uint16_t* ksh_ = ks  + ((size_t)bh*TT + sk)*64 + gsl*8;
            int cb = s0 + gsl*8; if (cb > VSTR-8) cb = VSTR-8;
            const uint16_t* vsh_ = vts + ((size_t)bh*64 + r)*VSTR + cb;
            gl16(ksh_, &Khs[(wu*16 + c*8)*64]);
            gl16(vsh_, &Vhs[(wu*16 + c*8)*64]);
        }
        __syncthreads();

        f32x4 sacc[4];
#pragma unroll
        for (int f=0;f<4;f++) sacc[f] = (f32x4){0.f,0.f,0.f,0.f};
#pragma unroll
        for (int ks2=0; ks2<2; ks2++){
#pragma unroll
            for (int f=0; f<4; f++){
                const int sr = f*16 + mrow;
                const int sl = ((ks2*4 + kgrp) ^ (sr & 7))*8;
                bf16x8 kbh = ldb8(&Khs[sr*64 + sl]);
                sacc[f] = __builtin_amdgcn_mfma_f32_16x16x32_bf16(qfh[ks2], kbh, sacc[f], 0,0,0);
            }
        }

        float alpha[4];
#pragma unroll
        for (int r=0;r<4;r++){
            float mx = -1e30f;
#pragma unroll
            for (int f=0;f<4;f++){
                float sv = sacc[f][r];              // Q pre-scaled by 1/8
                if (s0 + f*16 + mrow >= TT) sv = -1e30f;
                sacc[f][r] = sv;
                mx = fmaxf(mx, sv);
            }
#pragma unroll
            for (int msk=1; msk<16; msk<<=1) mx = fmaxf(mx, __shfl_xor(mx, msk));
            float mn = fmaxf(m_r[r], mx);
            alpha[r] = __expf(m_r[r] - mn);
            m_r[r] = mn;
            float rs = 0.0f;
#pragma unroll
            for (int f=0;f<4;f++){
                float e = __expf(sacc[f][r] - mn);
                sacc[f][r] = e;
                rs += e;
            }
#pragma unroll
            for (int msk=1; msk<16; msk<<=1) rs += __shfl_xor(rs, msk);
            l_r[r] = l_r[r]*alpha[r] + rs;
#pragma unroll
            for (int f=0;f<4;f++) oacc[f][r] *= alpha[r];
        }

#pragma unroll
        for (int r=0;r<4;r++){
            const int tr = wu*16 + kgrp*4 + r;
#pragma unroll
            for (int f=0;f<4;f++){
                const int c = f*16 + mrow;
                const int idx = tr*64 + ((c>>3) ^ (tr&7))*8 + (c&7);
                Phs[idx] = f2bf(sacc[f][r]);
            }
        }
        // same-wave DS ordering: reads below touch only rows this wave wrote

#pragma unroll
        for (int ks2=0; ks2<2; ks2++){
            const int trr = wu*16 + mrow;
            const int psl = ((ks2*4 + kgrp) ^ (trr & 7))*8;
            bf16x8 pah = ldb8(&Phs[trr*64 + psl]);
#pragma unroll
            for (int f=0; f<4; f++){
                const int dr = f*16 + mrow;
                const int vsl = ((ks2*4 + kgrp) ^ (dr & 7))*8;
                bf16x8 vbh = ldb8(&Vhs[dr*64 + vsl]);
                oacc[f] = __builtin_amdgcn_mfma_f32_16x16x32_bf16(pah, vbh, oacc[f], 0,0,0);
            }
        }
    }

#pragma unroll
    for (int r=0;r<4;r++){
        const int t = q0 + wu*16 + kgrp*4 + r;
        if (t < TT){
            const float inv = 1.0f / l_r[r];
#pragma unroll
            for (int f=0;f<4;f++){
                const int d = f*16 + mrow;
                uint16_t hi, lo; split_bf(oacc[f][r]*inv, hi, lo);
                size_t o = ((size_t)(b*TT + t))*DD + h*DHD + d;
                oh[o] = hi; ol[o] = lo;
            }
        }
    }
}

// ---------------------------------------------------------------------------
// Residual + LayerNorm (unchanged)
// ---------------------------------------------------------------------------
__global__ __launch_bounds__(256)
void ln_k(const float* __restrict__ src, const float* __restrict__ res,
          const float* __restrict__ w, const float* __restrict__ bia,
          float* __restrict__ dst, uint16_t* __restrict__ dbh,
          uint16_t* __restrict__ dbl)
{
    const int r = blockIdx.x;
    const int tid = threadIdx.x;
    const float* sp = src + (size_t)r*DD;
    float x0 = sp[tid], x1 = sp[tid + 256];
    if (res){
        x0 += res[(size_t)r*DD + tid];
        x1 += res[(size_t)r*DD + tid + 256];
    }
    float s  = x0 + x1;
    float sq = x0*x0 + x1*x1;
#pragma unroll
    for (int msk=1; msk<64; msk<<=1){
        s  += __shfl_xor(s,  msk);
        sq += __shfl_xor(sq, msk);
    }
    __shared__ float sm[8];
    int wv = tid >> 6, ln = tid & 63;
    if (ln == 0){ sm[wv] = s; sm[wv+4] = sq; }
    __syncthreads();
    s  = sm[0]+sm[1]+sm[2]+sm[3];
    sq = sm[4]+sm[5]+sm[6]+sm[7];
    float mu  = s * (1.0f/512.0f);
    float var = sq * (1.0f/512.0f) - mu*mu;
    float rsd = rsqrtf(var + 1e-5f);
    float y0 = (x0 - mu)*rsd*w[tid]       + bia[tid];
    float y1 = (x1 - mu)*rsd*w[tid + 256] + bia[tid + 256];
    dst[(size_t)r*DD + tid]       = y0;
    dst[(size_t)r*DD + tid + 256] = y1;
    uint16_t hi, lo;
    split_bf(y0, hi, lo); dbh[(size_t)r*DD + tid] = hi;       dbl[(size_t)r*DD + tid] = lo;
    split_bf(y1, hi, lo); dbh[(size_t)r*DD + tid + 256] = hi; dbl[(size_t)r*DD + tid + 256] = lo;
}

// ---------------------------------------------------------------------------
// sims v4 (unchanged from round 9)
// ---------------------------------------------------------------------------
__global__ __launch_bounds__(256, 4)
void sims_k(const float* __restrict__ pred, const float* __restrict__ bank,
            float* __restrict__ dotp, float* __restrict__ nrmp)
{
    const int jt = blockIdx.x, kt = blockIdx.y;
    const int tid  = threadIdx.x;
    const int qq    = tid & 7;
    const int slice = tid >> 3;
    const int sb    = slice*8;
    const int srow  = tid >> 4;
    const int tau   = tid & 15;

    __shared__ float BS[16*264];

    const int jr = jt*16 + srow;
    const float* bsrc = (jr < MM) ? (bank + (size_t)jr*PN)
                                  : (pred + (size_t)(jr - MM)*PN);
    bsrc += (size_t)kt*SCHUNK + tau*4;
    const float* p0 = pred + (size_t)qq*PN      + (size_t)kt*SCHUNK + sb;
    const float* p1 = pred + (size_t)(qq+8)*PN  + (size_t)kt*SCHUNK + sb;

    float acc0[16], acc1[16];
#pragma unroll
    for (int j=0;j<16;j++){ acc0[j] = 0.0f; acc1[j] = 0.0f; }
    float nr = 0.0f;

    float4 blv[4], pr0[2], pr1[2];
#pragma unroll
    for (int c=0;c<4;c++) blv[c] = *(const float4*)(bsrc + c*64);
    pr0[0] = *(const float4*)(p0); pr0[1] = *(const float4*)(p0 + 4);
    pr1[0] = *(const float4*)(p1); pr1[1] = *(const float4*)(p1 + 4);
    bsrc += 256; p0 += 256; p1 += 256;

    for (int st=0; st<SSTG; ++st){
#pragma unroll
        for (int c=0;c<4;c++){
            *(float4*)&BS[srow*264 + tau*4 + c*64] = blv[c];
            nr = fmaf(blv[c].x, blv[c].x, nr);
            nr = fmaf(blv[c].y, blv[c].y, nr);
            nr = fmaf(blv[c].z, blv[c].z, nr);
            nr = fmaf(blv[c].w, blv[c].w, nr);
        }
        float4 cp0[2] = {pr0[0], pr0[1]};
        float4 cp1[2] = {pr1[0], pr1[1]};
        if (st + 1 < SSTG){
#pragma unroll
            for (int c=0;c<4;c++) blv[c] = *(const float4*)(bsrc + c*64);
            pr0[0] = *(const float4*)(p0); pr0[1] = *(const float4*)(p0 + 4);
            pr1[0] = *(const float4*)(p1); pr1[1] = *(const float4*)(p1 + 4);
            bsrc += 256; p0 += 256; p1 += 256;
        }
        __syncthreads();
#pragma unroll
        for (int j=0;j<16;j++){
            float4 b0 = *(const float4*)&BS[j*264 + sb];
            float4 b1 = *(const float4*)&BS[j*264 + sb + 4];
            float a0 = acc0[j], a1 = acc1[j];
            a0 = fmaf(b0.x, cp0[0].x, a0); a0 = fmaf(b0.y, cp0[0].y, a0);
            a0 = fmaf(b0.z, cp0[0].z, a0); a0 = fmaf(b0.w, cp0[0].w, a0);
            a0 = fmaf(b1.x, cp0[1].x, a0); a0 = fmaf(b1.y, cp0[1].y, a0);
            a0 = fmaf(b1.z, cp0[1].z, a0); a0 = fmaf(b1.w, cp0[1].w, a0);
            a1 = fmaf(b0.x, cp1[0].x, a1); a1 = fmaf(b0.y, cp1[0].y, a1);
            a1 = fmaf(b0.z, cp1[0].z, a1); a1 = fmaf(b0.w, cp1[0].w, a1);
            a1 = fmaf(b1.x, cp1[1].x, a1); a1 = fmaf(b1.y, cp1[1].y, a1);
            a1 = fmaf(b1.z, cp1[1].z, a1); a1 = fmaf(b1.w, cp1[1].w, a1);
            acc0[j] = a0; acc1[j] = a1;
        }
        __syncthreads();
    }

#pragma unroll
    for (int m=8; m<64; m<<=1){
#pragma unroll
        for (int j=0;j<16;j++){
            acc0[j] += __shfl_xor(acc0[j], m);
            acc1[j] += __shfl_xor(acc1[j], m);
        }
    }
#pragma unroll
    for (int m=1;m<16;m<<=1) nr += __shfl_xor(nr, m);

    __syncthreads();
    float* RED = BS;
    const int wu2  = tid >> 6;
    const int lane = tid & 63;
    if (lane < 8){
#pragma unroll
        for (int j=0;j<16;j++){
            RED[(wu2*16 + j)*16 + lane]     = acc0[j];
            RED[(wu2*16 + j)*16 + lane + 8] = acc1[j];
        }
    }
    __syncthreads();
    const int j2 = tid >> 4, q2 = tid & 15;
    float s = RED[(0*16 + j2)*16 + q2] + RED[(1*16 + j2)*16 + q2]
            + RED[(2*16 + j2)*16 + q2] + RED[(3*16 + j2)*16 + q2];
    dotp[((size_t)kt*528 + jt*16 + j2)*16 + q2] = s;
    if (tau == 0) nrmp[kt*528 + jt*16 + srow] = nr;
}

__global__ void norms_k(const float* __restrict__ nrmp, float* __restrict__ invn){
    int j = blockIdx.x*blockDim.x + threadIdx.x;
    if (j < 528){
        float s = 0.0f;
        for (int kt=0; kt<SKC; kt++) s += nrmp[kt*528 + j];
        invn[j] = 1.0f/(sqrtf(s) + 1e-8f);
    }
}

__global__ void simsfin_k(const float* __restrict__ dotp, const float* __restrict__ invn,
                          float* __restrict__ sims){
    int fid = blockIdx.x*256 + threadIdx.x;
    int j = fid >> 4, q = fid & 15;
    float s = 0.0f;
    for (int kt=0; kt<SKC; kt++) s += dotp[((size_t)kt*528 + j)*16 + q];
    sims[q*528 + j] = s * invn[j] * invn[MM + q];
}

__global__ __launch_bounds__(64)
void topk_k(const float* __restrict__ sims, int* __restrict__ idx){
    const int q = blockIdx.x;
    const int lane = threadIdx.x;
    __shared__ float vals[528];
    for (int j=lane; j<528; j+=64) vals[j] = sims[q*528 + j];
    __syncthreads();
    for (int kk=0; kk<KNN; kk++){
        float bv = -3.0e38f; int bi = 1<<30;
        for (int j=lane; j<528; j+=64){
            float v2 = vals[j];
            if (v2 > bv || (v2 == bv && j < bi)){ bv = v2; bi = j; }
        }
#pragma unroll
        for (int msk=1; msk<64; msk<<=1){
            float ov = __shfl_xor(bv, msk);
            int   oi = __shfl_xor(bi, msk);
            if (ov > bv || (ov == bv && oi < bi)){ bv = ov; bi = oi; }
        }
        if (lane == 0){
            idx[q*KNN + kk] = bi;
            vals[bi] = -3.0e38f;
        }
        __syncthreads();
    }
}

__global__ __launch_bounds__(256)
void fuse_k(const float* __restrict__ pred, const float* __restrict__ bank,
            const int* __restrict__ idx, float* __restrict__ out){
    int u = blockIdx.x*256 + threadIdx.x;
    int b = u / (PN/4);
    int e = (u - b*(PN/4)) * 4;
    int id[KNN];
#pragma unroll
    for (int k2=0;k2<KNN;k2++) id[k2] = idx[b*KNN + k2];
    float4 pv = *(const float4*)(pred + (size_t)b*PN + e);
    float ax = 0.5f*pv.x, ay = 0.5f*pv.y, az = 0.5f*pv.z, aw = 0.5f*pv.w;
#pragma unroll
    for (int k2=0;k2<KNN;k2++){
        const float* rp = (id[k2] < MM) ? (bank + (size_t)id[k2]*PN)
                                        : (pred + (size_t)(id[k2]-MM)*PN);
        float4 rv = *(const float4*)(rp + e);
        ax = fmaf(0.05f, rv.x, ax); ay = fmaf(0.05f, rv.y, ay);
        az = fmaf(0.05f, rv.z, az); aw = fmaf(0.05f, rv.w, aw);
    }
    float4 ov; ov.x=ax; ov.y=ay; ov.z=az; ov.w=aw;
    *(float4*)(out + (size_t)b*PN + e) = ov;
}

// ---------------------------------------------------------------------------
extern "C" void kernel_launch(void* const* d_in, const int* in_sizes, int n_in,
                              void* d_out, int out_size, void* d_ws, size_t ws_size,
                              hipStream_t stream)
{
    (void)in_sizes; (void)n_in; (void)out_size; (void)ws_size;
    const float* x_enc  = (const float*)d_in[0];
    const float* x_mark = (const float*)d_in[1];
    const float* W_emb  = (const float*)d_in[4];
    const float* b_emb  = (const float*)d_in[5];
    const float* Wq  = (const float*)d_in[6];
    const float* Wk  = (const float*)d_in[7];
    const float* Wv  = (const float*)d_in[8];
    const float* Wo  = (const float*)d_in[9];
    const float* bq  = (const float*)d_in[10];
    const float* bk  = (const float*)d_in[11];
    const float* bv_ = (const float*)d_in[12];
    const float* bo  = (const float*)d_in[13];
    const float* ln1w = (const float*)d_in[14];
    const float* ln1b = (const float*)d_in[15];
    const float* ln2w = (const float*)d_in[16];
    const float* ln2b = (const float*)d_in[17];
    const float* Wff1 = (const float*)d_in[18];
    const float* bff1 = (const float*)d_in[19];
    const float* Wff2 = (const float*)d_in[20];
    const float* bff2 = (const float*)d_in[21];
    const float* lnfw = (const float*)d_in[22];
    const float* lnfb = (const float*)d_in[23];
    const float* Wproj = (const float*)d_in[24];
    const float* bproj = (const float*)d_in[25];
    const float* bank  = (const float*)d_in[26];
    float* out = (float*)d_out;

    char* pp = (char*)d_ws;
    auto a16 = [&](size_t elems)->uint16_t*{ uint16_t* r=(uint16_t*)pp; pp += ((elems*2 + 255)/256)*256; return r; };
    auto af  = [&](size_t elems)->float*  { float* r=(float*)pp;  pp += ((elems*4 + 255)/256)*256; return r; };

    uint16_t* wembT_h = a16(262144);        uint16_t* wembT_l = a16(262144);
    uint16_t* wqkvT_h = a16(2*1536*512);    uint16_t* wqkvT_l = a16(2*1536*512);
    uint16_t* woT_h   = a16(2*262144);      uint16_t* woT_l   = a16(2*262144);
    uint16_t* wff1T_h = a16(2*2048*512);    uint16_t* wff1T_l = a16(2*2048*512);
    uint16_t* wff2T_h = a16(2*512*2048);    uint16_t* wff2T_l = a16(2*512*2048);
    uint16_t* wprjT_h = a16(172032);        uint16_t* wprjT_l = a16(172032);
    float*    bqkv    = af(3072);
    uint16_t* hb_h    = a16((size_t)BT*512);
    uint16_t* hb_l    = a16((size_t)BT*512);
    uint16_t* tok_h   = a16((size_t)BT*512);     // og fp32 aliases tok region
    uint16_t* tok_l   = a16((size_t)BT*512);
    float*    og      = (float*)tok_h;
    // keep round-9 layout (midb aliasing depends on it); lo-planes unused now
    uint16_t* qsh     = a16((size_t)128*TT*64);
    uint16_t* qsl     = a16((size_t)128*TT*64);  (void)qsl;
    uint16_t* ksh     = a16((size_t)128*TT*64);
    uint16_t* ksl     = a16((size_t)128*TT*64);  (void)ksl;
    uint16_t* vsh     = a16((size_t)128*64*VSTR + 4096);
    uint16_t* vsl     = a16((size_t)128*64*VSTR + 4096);  (void)vsl;
    uint16_t* t1b_h   = a16((size_t)BT*512);
    uint16_t* t1b_l   = a16((size_t)BT*512);
    uint16_t* midb_h  = qsh;                     // mid aliases qsh..t1b region
    uint16_t* midb_l  = midb_h + (size_t)BT*2048;
    float*    h       = af((size_t)BT*512);
    float*    pred    = af((size_t)BB*PN);
    float*    dotp    = af((size_t)SKC*528*16);
    float*    nrmp    = af(SKC*528);
    float*    invn    = af(528);
    float*    sims    = af(16*528);
    int*      idxp    = (int*)af(256);

    dim3 blk(256);

    tok_k<<<dim3(17,16,BB), blk, 0, stream>>>(x_enc, x_mark, tok_h, tok_l);
    wtr_k<<<dim3(16,16,1), blk, 0, stream>>>(W_emb, wembT_h, wembT_l, 512, 512, 262144);
    wtr_k<<<dim3(16,16,2), blk, 0, stream>>>(Wq, wqkvT_h,          wqkvT_l,          512, 512, 786432);
    wtr_k<<<dim3(16,16,2), blk, 0, stream>>>(Wk, wqkvT_h + 262144, wqkvT_l + 262144, 512, 512, 786432);
    wtr_k<<<dim3(16,16,2), blk, 0, stream>>>(Wv, wqkvT_h + 524288, wqkvT_l + 524288, 512, 512, 786432);
    wtr_k<<<dim3(16,16,2), blk, 0, stream>>>(Wo, woT_h, woT_l, 512, 512, 262144);
    wtr_k<<<dim3(64,16,2), blk, 0, stream>>>(Wff1, wff1T_h, wff1T_l, 512, 2048, 1048576);
    wtr_k<<<dim3(16,64,2), blk, 0, stream>>>(Wff2, wff2T_h, wff2T_l, 2048, 512, 1048576);
    wtr_k<<<dim3(11,16,1), blk, 0, stream>>>(Wproj, wprjT_h, wprjT_l, 512, 336, 172032);
    catb_k<<<dim3(12), blk, 0, stream>>>(bq, bk, bv_, bqkv);

    bgemm64<EPI_F32|EPI_BF16><<<dim3(8,65), blk, 0, stream>>>(
        tok_h, tok_l, wembT_h, wembT_l, b_emb, h, hb_h, hb_l, BT, 512, 512);

    for (int i=0;i<2;i++){
        bgemm<EPI_QKV><<<dim3(12,65), blk, 0, stream>>>(
            hb_h, hb_l, wqkvT_h + (size_t)i*786432, wqkvT_l + (size_t)i*786432,
            bqkv + i*1536, nullptr, qsh, nullptr, ksh, vsh, BT, 1536, 512);
        attnm_k<<<dim3(9,HH,BB), blk, 0, stream>>>(qsh, ksh, vsh, t1b_h, t1b_l);
        bgemm64<EPI_F32><<<dim3(8,65), blk, 0, stream>>>(
            t1b_h, t1b_l, woT_h + (size_t)i*262144, woT_l + (size_t)i*262144,
            bo + i*512, og, nullptr, nullptr, BT, 512, 512);
        ln_k<<<BT, blk, 0, stream>>>(h, og, ln1w + i*512, ln1b + i*512, h, hb_h, hb_l);
        bgemm<EPI_GELU|EPI_BF16><<<dim3(16,65), blk, 0, stream>>>(
            hb_h, hb_l, wff1T_h + (size_t)i*1048576, wff1T_l + (size_t)i*1048576,
            bff1 + i*DFFN, nullptr, midb_h, midb_l,
            nullptr, nullptr, BT, DFFN, 512);
        bgemm64<EPI_F32><<<dim3(8,65), blk, 0, stream>>>(
            midb_h, midb_l, wff2T_h + (size_t)i*1048576, wff2T_l + (size_t)i*1048576,
            bff2 + i*512, og, nullptr, nullptr, BT, 512, DFFN);
        ln_k<<<BT, blk, 0, stream>>>(h, og, ln2w + i*512, ln2b + i*512, h, hb_h, hb_l);
    }

    ln_k<<<BT, blk, 0, stream>>>(h, nullptr, lnfw, lnfb, h, hb_h, hb_l);

    bgemm64<EPI_PREDT><<<dim3(6,65), blk, 0, stream>>>(
        hb_h, hb_l, wprjT_h, wprjT_l, bproj, pred, nullptr, nullptr, BT, PP, 512);

    sims_k<<<dim3(33,SKC), blk, 0, stream>>>(pred, bank, dotp, nrmp);
    norms_k<<<dim3(3), blk, 0, stream>>>(nrmp, invn);
    simsfin_k<<<dim3(33), blk, 0, stream>>>(dotp, invn, sims);
    topk_k<<<dim3(BB), dim3(64), 0, stream>>>(sims, idxp);
    fuse_k<<<dim3((BB*PN/4)/256), blk, 0, stream>>>(pred, bank, idxp, out);
}

// Round 11
// 1040.740 us; speedup vs baseline: 1.1748x; 1.0039x over previous
//
#include <hip/hip_runtime.h>
#include <stdint.h>
#include <math.h>

#define TT 516
#define BB 16
#define DD 512
#define LL 512
#define NN 512
#define HH 8
#define DHD 64
#define DFFN 2048
#define PP 336
#define MM 512
#define KNN 10
#define BT (BB*TT)      /* 8256 */
#define PN (PP*NN)      /* 172032 */
#define SKC 32          /* sims k-chunks */
#define SCHUNK (PN/SKC) /* 5376 */
#define SSTG (SCHUNK/256) /* 21 stages */
#define VSTR 528        /* transposed-V row stride (uint16 elems) */

using f32x4  = __attribute__((ext_vector_type(4))) float;
using bf16x8 = __attribute__((ext_vector_type(8))) __bf16;
using u16x8  = __attribute__((ext_vector_type(8))) unsigned short;

__device__ __forceinline__ float gelu_tanh(float x){
    float x3 = x*x*x;
    return 0.5f*x*(1.0f + tanhf(0.7978845608028654f*(x + 0.044715f*x3)));
}

__device__ __forceinline__ uint16_t f2bf(float x){
    uint32_t u = __builtin_bit_cast(uint32_t, x);
    uint32_t r = (u + 0x7FFFu + ((u >> 16) & 1u)) >> 16;
    return (uint16_t)r;
}

__device__ __forceinline__ void split_bf(float x, uint16_t& hi, uint16_t& lo){
    uint32_t u  = __builtin_bit_cast(uint32_t, x);
    uint32_t hr = (u + 0x7FFFu + ((u >> 16) & 1u)) & 0xFFFF0000u;
    float hf = __builtin_bit_cast(float, hr);
    hi = (uint16_t)(hr >> 16);
    lo = f2bf(x - hf);
}

__device__ __forceinline__ void gl16(const uint16_t* g, uint16_t* l){
    __builtin_amdgcn_global_load_lds(
        (const __attribute__((address_space(1))) unsigned int*)(const void*)g,
        (__attribute__((address_space(3))) unsigned int*)(void*)l, 16, 0, 0);
}

__device__ __forceinline__ bf16x8 ldb8(const uint16_t* p){
    return __builtin_bit_cast(bf16x8, *(const u16x8*)p);
}

#define EPI_F32   1
#define EPI_BF16  2
#define EPI_GELU  4
#define EPI_PREDT 8
#define EPI_QKV   16

// ---------------------------------------------------------------------------
// Split-bf16 MFMA GEMM, BN=128, BK=32 (unchanged from round 10)
// ---------------------------------------------------------------------------
template<int FLAGS>
__global__ __launch_bounds__(256)
void bgemm(const uint16_t* __restrict__ Ah, const uint16_t* __restrict__ Al,
           const uint16_t* __restrict__ Bh, const uint16_t* __restrict__ Bl,
           const float* __restrict__ bias, float* __restrict__ Cf,
           uint16_t* __restrict__ Cbh, uint16_t* __restrict__ Cbl,
           uint16_t* __restrict__ Xkh, uint16_t* __restrict__ Xvh,
           int Msz, int Nsz, int Ksz)
{
    constexpr int BN = 128;
    constexpr int FN = 4;
    __shared__ uint16_t As0[4096], As1[4096];
    __shared__ uint16_t Bs0[BN*32], Bs1[BN*32];

    const int tid  = threadIdx.x;
    const int lane = tid & 63;
    const int wu   = __builtin_amdgcn_readfirstlane(tid >> 6);
    const int wm   = wu >> 1, wn = wu & 1;
    const int m0   = blockIdx.y * 128;
    const int n0   = blockIdx.x * BN;

    const int r0c = tid >> 2;
    const int cc  = tid & 3;
    const int sw  = (r0c ^ (r0c >> 2)) & 3;
    const int csw = (cc ^ sw) * 8;
    int rA0 = m0 + r0c;      if (rA0 > Msz-1) rA0 = Msz-1;
    int rA1 = m0 + r0c + 64; if (rA1 > Msz-1) rA1 = Msz-1;
    int rB0 = n0 + r0c;      if (rB0 > Nsz-1) rB0 = Nsz-1;
    int rB1 = n0 + r0c + 64; if (rB1 > Nsz-1) rB1 = Nsz-1;
    const uint16_t* pAh0 = Ah + (size_t)rA0*Ksz + csw;
    const uint16_t* pAh1 = Ah + (size_t)rA1*Ksz + csw;
    const uint16_t* pAl0 = Al + (size_t)rA0*Ksz + csw;
    const uint16_t* pAl1 = Al + (size_t)rA1*Ksz + csw;
    const uint16_t* pBh0 = Bh + (size_t)rB0*Ksz + csw;
    const uint16_t* pBh1 = Bh + (size_t)rB1*Ksz + csw;
    const uint16_t* pBl0 = Bl + (size_t)rB0*Ksz + csw;
    const uint16_t* pBl1 = Bl + (size_t)rB1*Ksz + csw;

    f32x4 acc[4][FN];
#pragma unroll
    for (int i=0;i<4;i++)
#pragma unroll
        for (int j=0;j<FN;j++) acc[i][j] = (f32x4){0.f,0.f,0.f,0.f};

    const int lc16  = lane & 15;
    const int slot8 = (((lane>>4) ^ (lane&3) ^ ((lane>>2)&3))) * 8;
    const int rAf   = (wm*64 + lc16) * 32 + slot8;
    const int rBf   = (wn*(BN/2) + lc16) * 32 + slot8;

    for (int kt = 0; kt < Ksz; kt += 32){
        gl16(pAh0 + kt, &As0[wu*512]);
        gl16(pAh1 + kt, &As0[2048 + wu*512]);
        gl16(pAl0 + kt, &As1[wu*512]);
        gl16(pAl1 + kt, &As1[2048 + wu*512]);
        gl16(pBh0 + kt, &Bs0[wu*512]);
        gl16(pBh1 + kt, &Bs0[2048 + wu*512]);
        gl16(pBl0 + kt, &Bs1[wu*512]);
        gl16(pBl1 + kt, &Bs1[2048 + wu*512]);
        __syncthreads();

        bf16x8 ah[4], al[4];
#pragma unroll
        for (int fm=0; fm<4; fm++){
            ah[fm] = ldb8(&As0[rAf + fm*512]);
            al[fm] = ldb8(&As1[rAf + fm*512]);
        }
#pragma unroll
        for (int fn=0; fn<FN; fn++){
            bf16x8 bh = ldb8(&Bs0[rBf + fn*512]);
            bf16x8 bl = ldb8(&Bs1[rBf + fn*512]);
#pragma unroll
            for (int fm=0; fm<4; fm++){
                acc[fm][fn] = __builtin_amdgcn_mfma_f32_16x16x32_bf16(ah[fm], bh, acc[fm][fn], 0,0,0);
                acc[fm][fn] = __builtin_amdgcn_mfma_f32_16x16x32_bf16(ah[fm], bl, acc[fm][fn], 0,0,0);
                acc[fm][fn] = __builtin_amdgcn_mfma_f32_16x16x32_bf16(al[fm], bh, acc[fm][fn], 0,0,0);
            }
        }
        __syncthreads();
    }

    const int lr4 = (lane >> 4) * 4;
#pragma unroll
    for (int fm=0; fm<4; fm++){
        const int rbase = m0 + wm*64 + fm*16 + lr4;
#pragma unroll
        for (int fn=0; fn<FN; fn++){
            const int col = n0 + wn*(BN/2) + fn*16 + lc16;
            f32x4 v = acc[fm][fn];
            if (FLAGS & EPI_QKV){
                const int g   = col >> 9;
                const int cc2 = col & 511;
                const int hh2 = cc2 >> 6, dd2 = cc2 & 63;
                const float bcol = bias[col];
#pragma unroll
                for (int r=0;r<4;r++){
                    int row = rbase + r;
                    if (row < Msz){
                        float x = v[r] + bcol;
                        int b2 = row / TT, t2 = row - b2*TT;
                        int bh2 = b2*HH + hh2;
                        if (g == 0){
                            size_t o = ((size_t)bh2*TT + t2)*64 + dd2;
                            Cbh[o] = f2bf(x * 0.125f);
                        } else if (g == 1){
                            size_t o = ((size_t)bh2*TT + t2)*64 + dd2;
                            Xkh[o] = f2bf(x);
                        } else {
                            size_t o = ((size_t)bh2*64 + dd2)*VSTR + t2;
                            Xvh[o] = f2bf(x);
                        }
                    }
                }
            } else {
                const float bcol = bias[col];
#pragma unroll
                for (int r=0;r<4;r++){
                    int row = rbase + r;
                    if (row < Msz){
                        float x = v[r] + bcol;
                        if (FLAGS & EPI_GELU) x = gelu_tanh(x);
                        if (FLAGS & EPI_F32) Cf[(size_t)row*Nsz + col] = x;
                        if (FLAGS & EPI_BF16){
                            uint16_t hi, lo; split_bf(x, hi, lo);
                            Cbh[(size_t)row*Nsz + col] = hi;
                            Cbl[(size_t)row*Nsz + col] = lo;
                        }
                    }
                }
            }
        }
    }
}

// ---------------------------------------------------------------------------
// BN=64, BK=64 split-bf16 GEMM (unchanged)
// ---------------------------------------------------------------------------
template<int FLAGS>
__global__ __launch_bounds__(256, 3)
void bgemm64(const uint16_t* __restrict__ Ah, const uint16_t* __restrict__ Al,
             const uint16_t* __restrict__ Bh, const uint16_t* __restrict__ Bl,
             const float* __restrict__ bias, float* __restrict__ Cf,
             uint16_t* __restrict__ Cbh, uint16_t* __restrict__ Cbl,
             int Msz, int Nsz, int Ksz)
{
    __shared__ uint16_t As0[8192], As1[8192];
    __shared__ uint16_t Bs0[4096], Bs1[4096];

    const int tid  = threadIdx.x;
    const int lane = tid & 63;
    const int wu   = __builtin_amdgcn_readfirstlane(tid >> 6);
    const int wm   = wu >> 1, wn = wu & 1;
    const int m0   = blockIdx.y * 128;
    const int n0   = blockIdx.x * 64;

    const int sr8 = lane >> 3;
    const int skw = (((lane & 7) ^ sr8) * 8);

    int rA[4], rB[2];
#pragma unroll
    for (int i=0;i<4;i++){
        int r = m0 + (wu*4 + i)*8 + sr8;
        rA[i] = (r > Msz-1) ? Msz-1 : r;
    }
#pragma unroll
    for (int i=0;i<2;i++){
        int r = n0 + (wu*2 + i)*8 + sr8;
        rB[i] = (r > Nsz-1) ? Nsz-1 : r;
    }

    f32x4 acc[4][2];
#pragma unroll
    for (int i=0;i<4;i++)
#pragma unroll
        for (int j=0;j<2;j++) acc[i][j] = (f32x4){0.f,0.f,0.f,0.f};

    const int lc16 = lane & 15;
    const int kgrp = lane >> 4;

    for (int kt = 0; kt < Ksz; kt += 64){
#pragma unroll
        for (int i=0;i<4;i++){
            gl16(Ah + (size_t)rA[i]*Ksz + kt + skw, &As0[(wu*4 + i)*512]);
            gl16(Al + (size_t)rA[i]*Ksz + kt + skw, &As1[(wu*4 + i)*512]);
        }
#pragma unroll
        for (int i=0;i<2;i++){
            gl16(Bh + (size_t)rB[i]*Ksz + kt + skw, &Bs0[(wu*2 + i)*512]);
            gl16(Bl + (size_t)rB[i]*Ksz + kt + skw, &Bs1[(wu*2 + i)*512]);
        }
        __syncthreads();

#pragma unroll
        for (int ks=0; ks<2; ks++){
            bf16x8 ah[4], al[4];
#pragma unroll
            for (int fm=0; fm<4; fm++){
                const int r   = wm*64 + fm*16 + lc16;
                const int off = r*64 + (((ks*4 + kgrp) ^ (r & 7))*8);
                ah[fm] = ldb8(&As0[off]);
                al[fm] = ldb8(&As1[off]);
            }
#pragma unroll
            for (int fn=0; fn<2; fn++){
                const int rb   = wn*32 + fn*16 + lc16;
                const int offb = rb*64 + (((ks*4 + kgrp) ^ (rb & 7))*8);
                bf16x8 bh = ldb8(&Bs0[offb]);
                bf16x8 bl = ldb8(&Bs1[offb]);
#pragma unroll
                for (int fm=0; fm<4; fm++){
                    acc[fm][fn] = __builtin_amdgcn_mfma_f32_16x16x32_bf16(ah[fm], bh, acc[fm][fn], 0,0,0);
                    acc[fm][fn] = __builtin_amdgcn_mfma_f32_16x16x32_bf16(ah[fm], bl, acc[fm][fn], 0,0,0);
                    acc[fm][fn] = __builtin_amdgcn_mfma_f32_16x16x32_bf16(al[fm], bh, acc[fm][fn], 0,0,0);
                }
            }
        }
        __syncthreads();
    }

    const int lr4 = (lane >> 4) * 4;
#pragma unroll
    for (int fm=0; fm<4; fm++){
        const int rbase = m0 + wm*64 + fm*16 + lr4;
#pragma unroll
        for (int fn=0; fn<2; fn++){
            const int col = n0 + wn*32 + fn*16 + lc16;
            f32x4 v = acc[fm][fn];
            if (FLAGS & EPI_PREDT){
#pragma unroll
                for (int r=0;r<4;r++){
                    int row = rbase + r;
                    if (row < Msz && col < PP){
                        int b = row / TT, t = row - b*TT;
                        if (t < NN)
                            Cf[((size_t)b*PP + col)*NN + t] = v[r] + bias[col];
                    }
                }
            } else {
                const float bcol = bias[col];
#pragma unroll
                for (int r=0;r<4;r++){
                    int row = rbase + r;
                    if (row < Msz){
                        float x = v[r] + bcol;
                        if (FLAGS & EPI_GELU) x = gelu_tanh(x);
                        if (FLAGS & EPI_F32) Cf[(size_t)row*Nsz + col] = x;
                        if (FLAGS & EPI_BF16){
                            uint16_t hi, lo; split_bf(x, hi, lo);
                            Cbh[(size_t)row*Nsz + col] = hi;
                            Cbl[(size_t)row*Nsz + col] = lo;
                        }
                    }
                }
            }
        }
    }
}

// ---------------------------------------------------------------------------
// tok transpose + split (unchanged)
// ---------------------------------------------------------------------------
__global__ __launch_bounds__(256)
void tok_k(const float* __restrict__ xe, const float* __restrict__ xm,
           uint16_t* __restrict__ th, uint16_t* __restrict__ tl)
{
    const int b = blockIdx.z;
    const int t0 = blockIdx.x*32, l0 = blockIdx.y*32;
    __shared__ float tile[32][33];
    const int i = threadIdx.x >> 3;
    const int j4 = (threadIdx.x & 7) * 4;
#pragma unroll
    for (int c=0;c<4;c++){
        int t = t0 + j4 + c;
        float v = 0.0f;
        if (t < 512)      v = xe[((size_t)b*LL + l0+i)*NN + t];
        else if (t < 516) v = xm[((size_t)b*LL + l0+i)*4 + (t-512)];
        tile[i][j4+c] = v;
    }
    __syncthreads();
    int t = t0 + i;
    if (t < TT){
#pragma unroll
        for (int c=0;c<4;c++){
            uint16_t hi, lo; split_bf(tile[j4+c][i], hi, lo);
            size_t idx = ((size_t)b*TT + t)*512 + l0 + j4 + c;
            th[idx] = hi; tl[idx] = lo;
        }
    }
}

// ---------------------------------------------------------------------------
// ALL weight transposes in one launch (table-driven, 6576 tiles)
// ---------------------------------------------------------------------------
struct WtrDesc {
    const float* src; uint16_t* dh; uint16_t* dl;
    int Ksz, Nsz, ntx, nty; size_t zstride; int base;
};
struct WtrTab { WtrDesc d[8]; };

__global__ __launch_bounds__(256)
void wtrall_k(WtrTab tab)
{
    const int bid = blockIdx.x;
    int e = 0;
#pragma unroll
    for (int i=1;i<8;i++) if (bid >= tab.d[i].base) e = i;
    const float* src = tab.d[e].src;
    uint16_t* dh = tab.d[e].dh;
    uint16_t* dl = tab.d[e].dl;
    const int Ksz = tab.d[e].Ksz, Nsz = tab.d[e].Nsz;
    const int ntx = tab.d[e].ntx, nty = tab.d[e].nty;
    const size_t zs = tab.d[e].zstride;
    int local = bid - tab.d[e].base;
    const int tilesper = ntx*nty;
    const int z = local / tilesper;
    local -= z*tilesper;
    const int tyi = local / ntx;
    const int txi = local - tyi*ntx;
    src += (size_t)z*Ksz*Nsz; dh += (size_t)z*zs; dl += (size_t)z*zs;
    const int kt = tyi*32, nt = txi*32;

    __shared__ float tile[32][33];
    const int i = threadIdx.x >> 3;
    const int j4 = (threadIdx.x & 7) * 4;
#pragma unroll
    for (int c=0;c<4;c++){
        int n = nt + j4 + c;
        tile[i][j4+c] = (n < Nsz) ? src[(size_t)(kt+i)*Nsz + n] : 0.0f;
    }
    __syncthreads();
    int n = nt + i;
    if (n < Nsz){
#pragma unroll
        for (int c=0;c<4;c++){
            uint16_t hi, lo; split_bf(tile[j4+c][i], hi, lo);
            size_t idx = (size_t)n*Ksz + kt + j4 + c;
            dh[idx] = hi; dl[idx] = lo;
        }
    }
}

__global__ void catb_k(const float* __restrict__ bq, const float* __restrict__ bk,
                       const float* __restrict__ bv, float* __restrict__ dst){
    int j = blockIdx.x*256 + threadIdx.x;
    if (j >= 3072) return;
    int layer = j / 1536, r = j - layer*1536;
    float v;
    if (r < 512)       v = bq[layer*512 + r];
    else if (r < 1024) v = bk[layer*512 + r - 512];
    else               v = bv[layer*512 + r - 1024];
    dst[j] = v;
}

// ---------------------------------------------------------------------------
// MFMA flash attention, plain bf16 internals (unchanged from round 10)
// ---------------------------------------------------------------------------
__global__ __launch_bounds__(256, 4)
void attnm_k(const uint16_t* __restrict__ qs, const uint16_t* __restrict__ ks,
             const uint16_t* __restrict__ vts,
             uint16_t* __restrict__ oh, uint16_t* __restrict__ ol)
{
    const int qt = blockIdx.x;
    const int h  = blockIdx.y;
    const int b  = blockIdx.z;
    const int bh = b*HH + h;
    const int q0 = qt*64;
    const int tid  = threadIdx.x;
    const int lane = tid & 63;
    const int wu   = __builtin_amdgcn_readfirstlane(tid >> 6);
    const int mrow = lane & 15;
    const int kgrp = lane >> 4;

    __shared__ uint16_t Khs[4096];
    __shared__ uint16_t Vhs[4096];
    __shared__ uint16_t Phs[4096];

    int tq = q0 + wu*16 + mrow; if (tq > TT-1) tq = TT-1;
    const uint16_t* qbase = qs + ((size_t)bh*TT + tq)*64 + kgrp*8;
    bf16x8 qfh[2];
    qfh[0] = ldb8(qbase);      qfh[1] = ldb8(qbase + 32);

    const int srw = lane >> 3;
    const int sg  = lane & 7;

    f32x4 oacc[4];
#pragma unroll
    for (int f=0;f<4;f++) oacc[f] = (f32x4){0.f,0.f,0.f,0.f};
    float m_r[4] = {-1e30f,-1e30f,-1e30f,-1e30f};
    float l_r[4] = {0.f,0.f,0.f,0.f};

    for (int st=0; st<9; ++st){
        const int s0 = st*64;
        __syncthreads();
#pragma unroll
        for (int c=0;c<2;c++){
            const int r   = wu*16 + c*8 + srw;
            const int gsl = sg ^ (r & 7);
            int sk = s0 + r; if (sk > TT-1) sk = TT-1;
            const uint16_t* ksh_ = ks  + ((size_t)bh*TT + sk)*64 + gsl*8;
            int cb = s0 + gsl*8; if (cb > VSTR-8) cb = VSTR-8;
            const uint16_t* vsh_ = vts + ((size_t)bh*64 + r)*VSTR + cb;
            gl16(ksh_, &Khs[(wu*16 + c*8)*64]);
            gl16(vsh_, &Vhs[(wu*16 + c*8)*64]);
        }
        __syncthreads();

        f32x4 sacc[4];
#pragma unroll
        for (int f=0;f<4;f++) sacc[f] = (f32x4){0.f,0.f,0.f,0.f};
#pragma unroll
        for (int ks2=0; ks2<2; ks2++){
#pragma unroll
            for (int f=0; f<4; f++){
                const int sr = f*16 + mrow;
                const int sl = ((ks2*4 + kgrp) ^ (sr & 7))*8;
                bf16x8 kbh = ldb8(&Khs[sr*64 + sl]);
                sacc[f] = __builtin_amdgcn_mfma_f32_16x16x32_bf16(qfh[ks2], kbh, sacc[f], 0,0,0);
            }
        }

        float alpha[4];
#pragma unroll
        for (int r=0;r<4;r++){
            float mx = -1e30f;
#pragma unroll
            for (int f=0;f<4;f++){
                float sv = sacc[f][r];
                if (s0 + f*16 + mrow >= TT) sv = -1e30f;
                sacc[f][r] = sv;
                mx = fmaxf(mx, sv);
            }
#pragma unroll
            for (int msk=1; msk<16; msk<<=1) mx = fmaxf(mx, __shfl_xor(mx, msk));
            float mn = fmaxf(m_r[r], mx);
            alpha[r] = __expf(m_r[r] - mn);
            m_r[r] = mn;
            float rs = 0.0f;
#pragma unroll
            for (int f=0;f<4;f++){
                float e = __expf(sacc[f][r] - mn);
                sacc[f][r] = e;
                rs += e;
            }
#pragma unroll
            for (int msk=1; msk<16; msk<<=1) rs += __shfl_xor(rs, msk);
            l_r[r] = l_r[r]*alpha[r] + rs;
#pragma unroll
            for (int f=0;f<4;f++) oacc[f][r] *= alpha[r];
        }

#pragma unroll
        for (int r=0;r<4;r++){
            const int tr = wu*16 + kgrp*4 + r;
#pragma unroll
            for (int f=0;f<4;f++){
                const int c = f*16 + mrow;
                const int idx = tr*64 + ((c>>3) ^ (tr&7))*8 + (c&7);
                Phs[idx] = f2bf(sacc[f][r]);
            }
        }

#pragma unroll
        for (int ks2=0; ks2<2; ks2++){
            const int trr = wu*16 + mrow;
            const int psl = ((ks2*4 + kgrp) ^ (trr & 7))*8;
            bf16x8 pah = ldb8(&Phs[trr*64 + psl]);
#pragma unroll
            for (int f=0; f<4; f++){
                const int dr = f*16 + mrow;
                const int vsl = ((ks2*4 + kgrp) ^ (dr & 7))*8;
                bf16x8 vbh = ldb8(&Vhs[dr*64 + vsl]);
                oacc[f] = __builtin_amdgcn_mfma_f32_16x16x32_bf16(pah, vbh, oacc[f], 0,0,0);
            }
        }
    }

#pragma unroll
    for (int r=0;r<4;r++){
        const int t = q0 + wu*16 + kgrp*4 + r;
        if (t < TT){
            const float inv = 1.0f / l_r[r];
#pragma unroll
            for (int f=0;f<4;f++){
                const int d = f*16 + mrow;
                uint16_t hi, lo; split_bf(oacc[f][r]*inv, hi, lo);
                size_t o = ((size_t)(b*TT + t))*DD + h*DHD + d;
                oh[o] = hi; ol[o] = lo;
            }
        }
    }
}

// ---------------------------------------------------------------------------
// Residual + LayerNorm v2: wave-per-row (4 rows/block), float4 loads,
// shuffle-only reduce, u16x8 plane stores.
// ---------------------------------------------------------------------------
__global__ __launch_bounds__(256)
void ln_k(const float* __restrict__ src, const float* __restrict__ res,
          const float* __restrict__ w, const float* __restrict__ bia,
          float* __restrict__ dst, uint16_t* __restrict__ dbh,
          uint16_t* __restrict__ dbl)
{
    const int r    = blockIdx.x*4 + (threadIdx.x >> 6);
    const int lane = threadIdx.x & 63;
    const int c0   = lane*8;
    const size_t off = (size_t)r*DD + c0;

    float4 x0 = *(const float4*)(src + off);
    float4 x1 = *(const float4*)(src + off + 4);
    if (res){
        float4 r0 = *(const float4*)(res + off);
        float4 r1 = *(const float4*)(res + off + 4);
        x0.x+=r0.x; x0.y+=r0.y; x0.z+=r0.z; x0.w+=r0.w;
        x1.x+=r1.x; x1.y+=r1.y; x1.z+=r1.z; x1.w+=r1.w;
    }
    float s  = x0.x+x0.y+x0.z+x0.w + x1.x+x1.y+x1.z+x1.w;
    float sq = x0.x*x0.x+x0.y*x0.y+x0.z*x0.z+x0.w*x0.w
             + x1.x*x1.x+x1.y*x1.y+x1.z*x1.z+x1.w*x1.w;
#pragma unroll
    for (int msk=1; msk<64; msk<<=1){
        s  += __shfl_xor(s,  msk);
        sq += __shfl_xor(sq, msk);
    }
    float mu  = s * (1.0f/512.0f);
    float var = sq * (1.0f/512.0f) - mu*mu;
    float rsd = rsqrtf(var + 1e-5f);

    float4 w0 = *(const float4*)(w + c0);
    float4 w1 = *(const float4*)(w + c0 + 4);
    float4 b0 = *(const float4*)(bia + c0);
    float4 b1 = *(const float4*)(bia + c0 + 4);
    float y[8];
    y[0]=(x0.x-mu)*rsd*w0.x+b0.x; y[1]=(x0.y-mu)*rsd*w0.y+b0.y;
    y[2]=(x0.z-mu)*rsd*w0.z+b0.z; y[3]=(x0.w-mu)*rsd*w0.w+b0.w;
    y[4]=(x1.x-mu)*rsd*w1.x+b1.x; y[5]=(x1.y-mu)*rsd*w1.y+b1.y;
    y[6]=(x1.z-mu)*rsd*w1.z+b1.z; y[7]=(x1.w-mu)*rsd*w1.w+b1.w;

    float4 o0; o0.x=y[0]; o0.y=y[1]; o0.z=y[2]; o0.w=y[3];
    float4 o1; o1.x=y[4]; o1.y=y[5]; o1.z=y[6]; o1.w=y[7];
    *(float4*)(dst + off)     = o0;
    *(float4*)(dst + off + 4) = o1;

    u16x8 vh, vl;
#pragma unroll
    for (int i=0;i<8;i++){
        uint16_t hi, lo; split_bf(y[i], hi, lo);
        vh[i] = hi; vl[i] = lo;
    }
    *(u16x8*)(dbh + off) = vh;
    *(u16x8*)(dbl + off) = vl;
}

// ---------------------------------------------------------------------------
// sims v4 (unchanged)
// ---------------------------------------------------------------------------
__global__ __launch_bounds__(256, 4)
void sims_k(const float* __restrict__ pred, const float* __restrict__ bank,
            float* __restrict__ dotp, float* __restrict__ nrmp)
{
    const int jt = blockIdx.x, kt = blockIdx.y;
    const int tid  = threadIdx.x;
    const int qq    = tid & 7;
    const int slice = tid >> 3;
    const int sb    = slice*8;
    const int srow  = tid >> 4;
    const int tau   = tid & 15;

    __shared__ float BS[16*264];

    const int jr = jt*16 + srow;
    const float* bsrc = (jr < MM) ? (bank + (size_t)jr*PN)
                                  : (pred + (size_t)(jr - MM)*PN);
    bsrc += (size_t)kt*SCHUNK + tau*4;
    const float* p0 = pred + (size_t)qq*PN      + (size_t)kt*SCHUNK + sb;
    const float* p1 = pred + (size_t)(qq+8)*PN  + (size_t)kt*SCHUNK + sb;

    float acc0[16], acc1[16];
#pragma unroll
    for (int j=0;j<16;j++){ acc0[j] = 0.0f; acc1[j] = 0.0f; }
    float nr = 0.0f;

    float4 blv[4], pr0[2], pr1[2];
#pragma unroll
    for (int c=0;c<4;c++) blv[c] = *(const float4*)(bsrc + c*64);
    pr0[0] = *(const float4*)(p0); pr0[1] = *(const float4*)(p0 + 4);
    pr1[0] = *(const float4*)(p1); pr1[1] = *(const float4*)(p1 + 4);
    bsrc += 256; p0 += 256; p1 += 256;

    for (int st=0; st<SSTG; ++st){
#pragma unroll
        for (int c=0;c<4;c++){
            *(float4*)&BS[srow*264 + tau*4 + c*64] = blv[c];
            nr = fmaf(blv[c].x, blv[c].x, nr);
            nr = fmaf(blv[c].y, blv[c].y, nr);
            nr = fmaf(blv[c].z, blv[c].z, nr);
            nr = fmaf(blv[c].w, blv[c].w, nr);
        }
        float4 cp0[2] = {pr0[0], pr0[1]};
        float4 cp1[2] = {pr1[0], pr1[1]};
        if (st + 1 < SSTG){
#pragma unroll
            for (int c=0;c<4;c++) blv[c] = *(const float4*)(bsrc + c*64);
            pr0[0] = *(const float4*)(p0); pr0[1] = *(const float4*)(p0 + 4);
            pr1[0] = *(const float4*)(p1); pr1[1] = *(const float4*)(p1 + 4);
            bsrc += 256; p0 += 256; p1 += 256;
        }
        __syncthreads();
#pragma unroll
        for (int j=0;j<16;j++){
            float4 b0 = *(const float4*)&BS[j*264 + sb];
            float4 b1 = *(const float4*)&BS[j*264 + sb + 4];
            float a0 = acc0[j], a1 = acc1[j];
            a0 = fmaf(b0.x, cp0[0].x, a0); a0 = fmaf(b0.y, cp0[0].y, a0);
            a0 = fmaf(b0.z, cp0[0].z, a0); a0 = fmaf(b0.w, cp0[0].w, a0);
            a0 = fmaf(b1.x, cp0[1].x, a0); a0 = fmaf(b1.y, cp0[1].y, a0);
            a0 = fmaf(b1.z, cp0[1].z, a0); a0 = fmaf(b1.w, cp0[1].w, a0);
            a1 = fmaf(b0.x, cp1[0].x, a1); a1 = fmaf(b0.y, cp1[0].y, a1);
            a1 = fmaf(b0.z, cp1[0].z, a1); a1 = fmaf(b0.w, cp1[0].w, a1);
            a1 = fmaf(b1.x, cp1[1].x, a1); a1 = fmaf(b1.y, cp1[1].y, a1);
            a1 = fmaf(b1.z, cp1[1].z, a1); a1 = fmaf(b1.w, cp1[1].w, a1);
            acc0[j] = a0; acc1[j] = a1;
        }
        __syncthreads();
    }

#pragma unroll
    for (int m=8; m<64; m<<=1){
#pragma unroll
        for (int j=0;j<16;j++){
            acc0[j] += __shfl_xor(acc0[j], m);
            acc1[j] += __shfl_xor(acc1[j], m);
        }
    }
#pragma unroll
    for (int m=1;m<16;m<<=1) nr += __shfl_xor(nr, m);

    __syncthreads();
    float* RED = BS;
    const int wu2  = tid >> 6;
    const int lane = tid & 63;
    if (lane < 8){
#pragma unroll
        for (int j=0;j<16;j++){
            RED[(wu2*16 + j)*16 + lane]     = acc0[j];
            RED[(wu2*16 + j)*16 + lane + 8] = acc1[j];
        }
    }
    __syncthreads();
    const int j2 = tid >> 4, q2 = tid & 15;
    float s = RED[(0*16 + j2)*16 + q2] + RED[(1*16 + j2)*16 + q2]
            + RED[(2*16 + j2)*16 + q2] + RED[(3*16 + j2)*16 + q2];
    dotp[((size_t)kt*528 + jt*16 + j2)*16 + q2] = s;
    if (tau == 0) nrmp[kt*528 + jt*16 + srow] = nr;
}

// ---------------------------------------------------------------------------
// Fused sims tail: per-query block computes invn (redundant), sims row,
// then exact top-K (single wave). Replaces norms_k + simsfin_k + topk_k.
// ---------------------------------------------------------------------------
__global__ __launch_bounds__(256)
void simstail_k(const float* __restrict__ dotp, const float* __restrict__ nrmp,
                int* __restrict__ idx)
{
    const int q   = blockIdx.x;
    const int tid = threadIdx.x;
    __shared__ float invn[528];
    __shared__ float vals[528];

    for (int j=tid; j<528; j+=256){
        float s = 0.0f;
        for (int kt=0; kt<SKC; kt++) s += nrmp[kt*528 + j];
        invn[j] = 1.0f/(sqrtf(s) + 1e-8f);
    }
    __syncthreads();
    const float invq = invn[MM + q];
    for (int j=tid; j<528; j+=256){
        float s = 0.0f;
        for (int kt=0; kt<SKC; kt++) s += dotp[((size_t)kt*528 + j)*16 + q];
        vals[j] = s * invn[j] * invq;
    }
    __syncthreads();
    if (tid < 64){
        const int lane = tid;
        for (int kk=0; kk<KNN; kk++){
            float bv = -3.0e38f; int bi = 1<<30;
            for (int j=lane; j<528; j+=64){
                float v2 = vals[j];
                if (v2 > bv || (v2 == bv && j < bi)){ bv = v2; bi = j; }
            }
#pragma unroll
            for (int msk=1; msk<64; msk<<=1){
                float ov = __shfl_xor(bv, msk);
                int   oi = __shfl_xor(bi, msk);
                if (ov > bv || (ov == bv && oi < bi)){ bv = ov; bi = oi; }
            }
            if (lane == 0){
                idx[q*KNN + kk] = bi;
                vals[bi] = -3.0e38f;
            }
            // same-wave DS ordering makes lane0's write visible next iteration
        }
    }
}

__global__ __launch_bounds__(256)
void fuse_k(const float* __restrict__ pred, const float* __restrict__ bank,
            const int* __restrict__ idx, float* __restrict__ out){
    int u = blockIdx.x*256 + threadIdx.x;
    int b = u / (PN/4);
    int e = (u - b*(PN/4)) * 4;
    int id[KNN];
#pragma unroll
    for (int k2=0;k2<KNN;k2++) id[k2] = idx[b*KNN + k2];
    float4 pv = *(const float4*)(pred + (size_t)b*PN + e);
    float ax = 0.5f*pv.x, ay = 0.5f*pv.y, az = 0.5f*pv.z, aw = 0.5f*pv.w;
#pragma unroll
    for (int k2=0;k2<KNN;k2++){
        const float* rp = (id[k2] < MM) ? (bank + (size_t)id[k2]*PN)
                                        : (pred + (size_t)(id[k2]-MM)*PN);
        float4 rv = *(const float4*)(rp + e);
        ax = fmaf(0.05f, rv.x, ax); ay = fmaf(0.05f, rv.y, ay);
        az = fmaf(0.05f, rv.z, az); aw = fmaf(0.05f, rv.w, aw);
    }
    float4 ov; ov.x=ax; ov.y=ay; ov.z=az; ov.w=aw;
    *(float4*)(out + (size_t)b*PN + e) = ov;
}

// ---------------------------------------------------------------------------
extern "C" void kernel_launch(void* const* d_in, const int* in_sizes, int n_in,
                              void* d_out, int out_size, void* d_ws, size_t ws_size,
                              hipStream_t stream)
{
    (void)in_sizes; (void)n_in; (void)out_size; (void)ws_size;
    const float* x_enc  = (const float*)d_in[0];
    const float* x_mark = (const float*)d_in[1];
    const float* W_emb  = (const float*)d_in[4];
    const float* b_emb  = (const float*)d_in[5];
    const float* Wq  = (const float*)d_in[6];
    const float* Wk  = (const float*)d_in[7];
    const float* Wv  = (const float*)d_in[8];
    const float* Wo  = (const float*)d_in[9];
    const float* bq  = (const float*)d_in[10];
    const float* bk  = (const float*)d_in[11];
    const float* bv_ = (const float*)d_in[12];
    const float* bo  = (const float*)d_in[13];
    const float* ln1w = (const float*)d_in[14];
    const float* ln1b = (const float*)d_in[15];
    const float* ln2w = (const float*)d_in[16];
    const float* ln2b = (const float*)d_in[17];
    const float* Wff1 = (const float*)d_in[18];
    const float* bff1 = (const float*)d_in[19];
    const float* Wff2 = (const float*)d_in[20];
    const float* bff2 = (const float*)d_in[21];
    const float* lnfw = (const float*)d_in[22];
    const float* lnfb = (const float*)d_in[23];
    const float* Wproj = (const float*)d_in[24];
    const float* bproj = (const float*)d_in[25];
    const float* bank  = (const float*)d_in[26];
    float* out = (float*)d_out;

    char* pp = (char*)d_ws;
    auto a16 = [&](size_t elems)->uint16_t*{ uint16_t* r=(uint16_t*)pp; pp += ((elems*2 + 255)/256)*256; return r; };
    auto af  = [&](size_t elems)->float*  { float* r=(float*)pp;  pp += ((elems*4 + 255)/256)*256; return r; };

    uint16_t* wembT_h = a16(262144);        uint16_t* wembT_l = a16(262144);
    uint16_t* wqkvT_h = a16(2*1536*512);    uint16_t* wqkvT_l = a16(2*1536*512);
    uint16_t* woT_h   = a16(2*262144);      uint16_t* woT_l   = a16(2*262144);
    uint16_t* wff1T_h = a16(2*2048*512);    uint16_t* wff1T_l = a16(2*2048*512);
    uint16_t* wff2T_h = a16(2*512*2048);    uint16_t* wff2T_l = a16(2*512*2048);
    uint16_t* wprjT_h = a16(172032);        uint16_t* wprjT_l = a16(172032);
    float*    bqkv    = af(3072);
    uint16_t* hb_h    = a16((size_t)BT*512);
    uint16_t* hb_l    = a16((size_t)BT*512);
    uint16_t* tok_h   = a16((size_t)BT*512);     // og fp32 aliases tok region
    uint16_t* tok_l   = a16((size_t)BT*512);
    float*    og      = (float*)tok_h;
    uint16_t* qsh     = a16((size_t)128*TT*64);
    uint16_t* qsl     = a16((size_t)128*TT*64);  (void)qsl;
    uint16_t* ksh     = a16((size_t)128*TT*64);
    uint16_t* ksl     = a16((size_t)128*TT*64);  (void)ksl;
    uint16_t* vsh     = a16((size_t)128*64*VSTR + 4096);
    uint16_t* vsl     = a16((size_t)128*64*VSTR + 4096);  (void)vsl;
    uint16_t* t1b_h   = a16((size_t)BT*512);
    uint16_t* t1b_l   = a16((size_t)BT*512);
    uint16_t* midb_h  = qsh;                     // mid aliases qsh..t1b region
    uint16_t* midb_l  = midb_h + (size_t)BT*2048;
    float*    h       = af((size_t)BT*512);
    float*    pred    = af((size_t)BB*PN);
    float*    dotp    = af((size_t)SKC*528*16);
    float*    nrmp    = af(SKC*528);
    float*    invn    = af(528);  (void)invn;
    float*    sims    = af(16*528);  (void)sims;
    int*      idxp    = (int*)af(256);

    dim3 blk(256);

    tok_k<<<dim3(17,16,BB), blk, 0, stream>>>(x_enc, x_mark, tok_h, tok_l);

    WtrTab tab;
    tab.d[0] = { W_emb, wembT_h, wembT_l, 512, 512, 16, 16, 262144, 0 };
    tab.d[1] = { Wq, wqkvT_h,          wqkvT_l,          512, 512, 16, 16, 786432, 256 };
    tab.d[2] = { Wk, wqkvT_h + 262144, wqkvT_l + 262144, 512, 512, 16, 16, 786432, 768 };
    tab.d[3] = { Wv, wqkvT_h + 524288, wqkvT_l + 524288, 512, 512, 16, 16, 786432, 1280 };
    tab.d[4] = { Wo, woT_h, woT_l, 512, 512, 16, 16, 262144, 1792 };
    tab.d[5] = { Wff1, wff1T_h, wff1T_l, 512, 2048, 64, 16, 1048576, 2304 };
    tab.d[6] = { Wff2, wff2T_h, wff2T_l, 2048, 512, 16, 64, 1048576, 4352 };
    tab.d[7] = { Wproj, wprjT_h, wprjT_l, 512, 336, 11, 16, 172032, 6400 };
    wtrall_k<<<dim3(6576), blk, 0, stream>>>(tab);
    catb_k<<<dim3(12), blk, 0, stream>>>(bq, bk, bv_, bqkv);

    bgemm64<EPI_F32|EPI_BF16><<<dim3(8,65), blk, 0, stream>>>(
        tok_h, tok_l, wembT_h, wembT_l, b_emb, h, hb_h, hb_l, BT, 512, 512);

    for (int i=0;i<2;i++){
        bgemm<EPI_QKV><<<dim3(12,65), blk, 0, stream>>>(
            hb_h, hb_l, wqkvT_h + (size_t)i*786432, wqkvT_l + (size_t)i*786432,
            bqkv + i*1536, nullptr, qsh, nullptr, ksh, vsh, BT, 1536, 512);
        attnm_k<<<dim3(9,HH,BB), blk, 0, stream>>>(qsh, ksh, vsh, t1b_h, t1b_l);
        bgemm64<EPI_F32><<<dim3(8,65), blk, 0, stream>>>(
            t1b_h, t1b_l, woT_h + (size_t)i*262144, woT_l + (size_t)i*262144,
            bo + i*512, og, nullptr, nullptr, BT, 512, 512);
        ln_k<<<dim3(BT/4), blk, 0, stream>>>(h, og, ln1w + i*512, ln1b + i*512, h, hb_h, hb_l);
        bgemm<EPI_GELU|EPI_BF16><<<dim3(16,65), blk, 0, stream>>>(
            hb_h, hb_l, wff1T_h + (size_t)i*1048576, wff1T_l + (size_t)i*1048576,
            bff1 + i*DFFN, nullptr, midb_h, midb_l,
            nullptr, nullptr, BT, DFFN, 512);
        bgemm64<EPI_F32><<<dim3(8,65), blk, 0, stream>>>(
            midb_h, midb_l, wff2T_h + (size_t)i*1048576, wff2T_l + (size_t)i*1048576,
            bff2 + i*512, og, nullptr, nullptr, BT, 512, DFFN);
        ln_k<<<dim3(BT/4), blk, 0, stream>>>(h, og, ln2w + i*512, ln2b + i*512, h, hb_h, hb_l);
    }

    ln_k<<<dim3(BT/4), blk, 0, stream>>>(h, nullptr, lnfw, lnfb, h, hb_h, hb_l);

    bgemm64<EPI_PREDT><<<dim3(6,65), blk, 0, stream>>>(
        hb_h, hb_l, wprjT_h, wprjT_l, bproj, pred, nullptr, nullptr, BT, PP, 512);

    sims_k<<<dim3(33,SKC), blk, 0, stream>>>(pred, bank, dotp, nrmp);
    simstail_k<<<dim3(BB), blk, 0, stream>>>(dotp, nrmp, idxp);
    fuse_k<<<dim3((BB*PN/4)/256), blk, 0, stream>>>(pred, bank, idxp, out);
}

// Round 12
// 691.179 us; speedup vs baseline: 1.7689x; 1.5057x over previous
//
#include <hip/hip_runtime.h>
#include <stdint.h>
#include <math.h>

#define TT 516
#define BB 16
#define DD 512
#define LL 512
#define NN 512
#define HH 8
#define DHD 64
#define DFFN 2048
#define PP 336
#define MM 512
#define KNN 10
#define BT (BB*TT)      /* 8256 */
#define PN (PP*NN)      /* 172032 */
#define SKC 32          /* sims k-chunks */
#define SCHUNK (PN/SKC) /* 5376 */
#define SSTG (SCHUNK/256) /* 21 stages */
#define VSTR 528        /* transposed-V row stride (uint16 elems) */

using f32x4 = __attribute__((ext_vector_type(4))) float;
using f16x8 = __attribute__((ext_vector_type(8))) _Float16;
using u16x8 = __attribute__((ext_vector_type(8))) unsigned short;

__device__ __forceinline__ float gelu_tanh(float x){
    float x3 = x*x*x;
    return 0.5f*x*(1.0f + tanhf(0.7978845608028654f*(x + 0.044715f*x3)));
}

__device__ __forceinline__ uint16_t f2h(float x){
    _Float16 h = (_Float16)x;
    return __builtin_bit_cast(uint16_t, h);
}

__device__ __forceinline__ void gl16(const uint16_t* g, uint16_t* l){
    __builtin_amdgcn_global_load_lds(
        (const __attribute__((address_space(1))) unsigned int*)(const void*)g,
        (__attribute__((address_space(3))) unsigned int*)(void*)l, 16, 0, 0);
}

__device__ __forceinline__ f16x8 ldh8(const uint16_t* p){
    return __builtin_bit_cast(f16x8, *(const u16x8*)p);
}

#define EPI_F32   1
#define EPI_H16   2
#define EPI_GELU  4
#define EPI_PREDT 8
#define EPI_QKV   16

// ---------------------------------------------------------------------------
// fp16 single-pass MFMA GEMM, BN=128, BK=32 (same schedule as split version;
// half the staging, 1/3 the MFMA). Used for QKV (N=1536) and FF1 (N=2048).
// ---------------------------------------------------------------------------
template<int FLAGS>
__global__ __launch_bounds__(256)
void bgemm(const uint16_t* __restrict__ Ah, const uint16_t* __restrict__ Bh,
           const float* __restrict__ bias, float* __restrict__ Cf,
           uint16_t* __restrict__ Cb, uint16_t* __restrict__ Xkh,
           uint16_t* __restrict__ Xvh, int Msz, int Nsz, int Ksz)
{
    constexpr int FN = 4;
    __shared__ uint16_t As0[4096];
    __shared__ uint16_t Bs0[4096];

    const int tid  = threadIdx.x;
    const int lane = tid & 63;
    const int wu   = __builtin_amdgcn_readfirstlane(tid >> 6);
    const int wm   = wu >> 1, wn = wu & 1;
    const int m0   = blockIdx.y * 128;
    const int n0   = blockIdx.x * 128;

    const int r0c = tid >> 2;
    const int cc  = tid & 3;
    const int sw  = (r0c ^ (r0c >> 2)) & 3;
    const int csw = (cc ^ sw) * 8;
    int rA0 = m0 + r0c;      if (rA0 > Msz-1) rA0 = Msz-1;
    int rA1 = m0 + r0c + 64; if (rA1 > Msz-1) rA1 = Msz-1;
    int rB0 = n0 + r0c;      if (rB0 > Nsz-1) rB0 = Nsz-1;
    int rB1 = n0 + r0c + 64; if (rB1 > Nsz-1) rB1 = Nsz-1;
    const uint16_t* pAh0 = Ah + (size_t)rA0*Ksz + csw;
    const uint16_t* pAh1 = Ah + (size_t)rA1*Ksz + csw;
    const uint16_t* pBh0 = Bh + (size_t)rB0*Ksz + csw;
    const uint16_t* pBh1 = Bh + (size_t)rB1*Ksz + csw;

    f32x4 acc[4][FN];
#pragma unroll
    for (int i=0;i<4;i++)
#pragma unroll
        for (int j=0;j<FN;j++) acc[i][j] = (f32x4){0.f,0.f,0.f,0.f};

    const int lc16  = lane & 15;
    const int slot8 = (((lane>>4) ^ (lane&3) ^ ((lane>>2)&3))) * 8;
    const int rAf   = (wm*64 + lc16) * 32 + slot8;
    const int rBf   = (wn*64 + lc16) * 32 + slot8;

    for (int kt = 0; kt < Ksz; kt += 32){
        gl16(pAh0 + kt, &As0[wu*512]);
        gl16(pAh1 + kt, &As0[2048 + wu*512]);
        gl16(pBh0 + kt, &Bs0[wu*512]);
        gl16(pBh1 + kt, &Bs0[2048 + wu*512]);
        __syncthreads();

        f16x8 ah[4];
#pragma unroll
        for (int fm=0; fm<4; fm++) ah[fm] = ldh8(&As0[rAf + fm*512]);
#pragma unroll
        for (int fn=0; fn<FN; fn++){
            f16x8 bh = ldh8(&Bs0[rBf + fn*512]);
#pragma unroll
            for (int fm=0; fm<4; fm++)
                acc[fm][fn] = __builtin_amdgcn_mfma_f32_16x16x32_f16(ah[fm], bh, acc[fm][fn], 0,0,0);
        }
        __syncthreads();
    }

    const int lr4 = (lane >> 4) * 4;
#pragma unroll
    for (int fm=0; fm<4; fm++){
        const int rbase = m0 + wm*64 + fm*16 + lr4;
#pragma unroll
        for (int fn=0; fn<FN; fn++){
            const int col = n0 + wn*64 + fn*16 + lc16;
            f32x4 v = acc[fm][fn];
            if (FLAGS & EPI_QKV){
                const int g   = col >> 9;
                const int cc2 = col & 511;
                const int hh2 = cc2 >> 6, dd2 = cc2 & 63;
                const float bcol = bias[col];
#pragma unroll
                for (int r=0;r<4;r++){
                    int row = rbase + r;
                    if (row < Msz){
                        float x = v[r] + bcol;
                        int b2 = row / TT, t2 = row - b2*TT;
                        int bh2 = b2*HH + hh2;
                        if (g == 0){
                            size_t o = ((size_t)bh2*TT + t2)*64 + dd2;
                            Cb[o] = f2h(x * 0.125f);     // fold softmax scale into Q
                        } else if (g == 1){
                            size_t o = ((size_t)bh2*TT + t2)*64 + dd2;
                            Xkh[o] = f2h(x);
                        } else {
                            size_t o = ((size_t)bh2*64 + dd2)*VSTR + t2;
                            Xvh[o] = f2h(x);
                        }
                    }
                }
            } else {
                const float bcol = bias[col];
#pragma unroll
                for (int r=0;r<4;r++){
                    int row = rbase + r;
                    if (row < Msz){
                        float x = v[r] + bcol;
                        if (FLAGS & EPI_GELU) x = gelu_tanh(x);
                        if (FLAGS & EPI_F32) Cf[(size_t)row*Nsz + col] = x;
                        if (FLAGS & EPI_H16) Cb[(size_t)row*Nsz + col] = f2h(x);
                    }
                }
            }
        }
    }
}

// ---------------------------------------------------------------------------
// fp16 single-pass BN=64, BK=64 GEMM (round-8 schedule). emb/Wo/FF2/proj.
// 24 KB LDS -> 4 blocks/CU.
// ---------------------------------------------------------------------------
template<int FLAGS>
__global__ __launch_bounds__(256, 4)
void bgemm64(const uint16_t* __restrict__ Ah, const uint16_t* __restrict__ Bh,
             const float* __restrict__ bias, float* __restrict__ Cf,
             uint16_t* __restrict__ Cb, int Msz, int Nsz, int Ksz)
{
    __shared__ uint16_t As0[8192];   // 128 rows x 64 k
    __shared__ uint16_t Bs0[4096];   // 64 rows x 64 k

    const int tid  = threadIdx.x;
    const int lane = tid & 63;
    const int wu   = __builtin_amdgcn_readfirstlane(tid >> 6);
    const int wm   = wu >> 1, wn = wu & 1;
    const int m0   = blockIdx.y * 128;
    const int n0   = blockIdx.x * 64;

    const int sr8 = lane >> 3;
    const int skw = (((lane & 7) ^ sr8) * 8);

    int rA[4], rB[2];
#pragma unroll
    for (int i=0;i<4;i++){
        int r = m0 + (wu*4 + i)*8 + sr8;
        rA[i] = (r > Msz-1) ? Msz-1 : r;
    }
#pragma unroll
    for (int i=0;i<2;i++){
        int r = n0 + (wu*2 + i)*8 + sr8;
        rB[i] = (r > Nsz-1) ? Nsz-1 : r;
    }

    f32x4 acc[4][2];
#pragma unroll
    for (int i=0;i<4;i++)
#pragma unroll
        for (int j=0;j<2;j++) acc[i][j] = (f32x4){0.f,0.f,0.f,0.f};

    const int lc16 = lane & 15;
    const int kgrp = lane >> 4;

    for (int kt = 0; kt < Ksz; kt += 64){
#pragma unroll
        for (int i=0;i<4;i++)
            gl16(Ah + (size_t)rA[i]*Ksz + kt + skw, &As0[(wu*4 + i)*512]);
#pragma unroll
        for (int i=0;i<2;i++)
            gl16(Bh + (size_t)rB[i]*Ksz + kt + skw, &Bs0[(wu*2 + i)*512]);
        __syncthreads();

#pragma unroll
        for (int ks=0; ks<2; ks++){
            f16x8 ah[4];
#pragma unroll
            for (int fm=0; fm<4; fm++){
                const int r   = wm*64 + fm*16 + lc16;
                const int off = r*64 + (((ks*4 + kgrp) ^ (r & 7))*8);
                ah[fm] = ldh8(&As0[off]);
            }
#pragma unroll
            for (int fn=0; fn<2; fn++){
                const int rb   = wn*32 + fn*16 + lc16;
                const int offb = rb*64 + (((ks*4 + kgrp) ^ (rb & 7))*8);
                f16x8 bh = ldh8(&Bs0[offb]);
#pragma unroll
                for (int fm=0; fm<4; fm++)
                    acc[fm][fn] = __builtin_amdgcn_mfma_f32_16x16x32_f16(ah[fm], bh, acc[fm][fn], 0,0,0);
            }
        }
        __syncthreads();
    }

    const int lr4 = (lane >> 4) * 4;
#pragma unroll
    for (int fm=0; fm<4; fm++){
        const int rbase = m0 + wm*64 + fm*16 + lr4;
#pragma unroll
        for (int fn=0; fn<2; fn++){
            const int col = n0 + wn*32 + fn*16 + lc16;
            f32x4 v = acc[fm][fn];
            if (FLAGS & EPI_PREDT){
#pragma unroll
                for (int r=0;r<4;r++){
                    int row = rbase + r;
                    if (row < Msz && col < PP){
                        int b = row / TT, t = row - b*TT;
                        if (t < NN)
                            Cf[((size_t)b*PP + col)*NN + t] = v[r] + bias[col];
                    }
                }
            } else {
                const float bcol = bias[col];
#pragma unroll
                for (int r=0;r<4;r++){
                    int row = rbase + r;
                    if (row < Msz){
                        float x = v[r] + bcol;
                        if (FLAGS & EPI_GELU) x = gelu_tanh(x);
                        if (FLAGS & EPI_F32) Cf[(size_t)row*Nsz + col] = x;
                        if (FLAGS & EPI_H16) Cb[(size_t)row*Nsz + col] = f2h(x);
                    }
                }
            }
        }
    }
}

// ---------------------------------------------------------------------------
// tok transpose -> fp16 single plane
// ---------------------------------------------------------------------------
__global__ __launch_bounds__(256)
void tok_k(const float* __restrict__ xe, const float* __restrict__ xm,
           uint16_t* __restrict__ th)
{
    const int b = blockIdx.z;
    const int t0 = blockIdx.x*32, l0 = blockIdx.y*32;
    __shared__ float tile[32][33];
    const int i = threadIdx.x >> 3;
    const int j4 = (threadIdx.x & 7) * 4;
#pragma unroll
    for (int c=0;c<4;c++){
        int t = t0 + j4 + c;
        float v = 0.0f;
        if (t < 512)      v = xe[((size_t)b*LL + l0+i)*NN + t];
        else if (t < 516) v = xm[((size_t)b*LL + l0+i)*4 + (t-512)];
        tile[i][j4+c] = v;
    }
    __syncthreads();
    int t = t0 + i;
    if (t < TT){
#pragma unroll
        for (int c=0;c<4;c++){
            size_t idx = ((size_t)b*TT + t)*512 + l0 + j4 + c;
            th[idx] = f2h(tile[j4+c][i]);
        }
    }
}

// ---------------------------------------------------------------------------
// ALL weight transposes in one launch, fp16 single plane
// ---------------------------------------------------------------------------
struct WtrDesc {
    const float* src; uint16_t* dh;
    int Ksz, Nsz, ntx, nty; size_t zstride; int base;
};
struct WtrTab { WtrDesc d[8]; };

__global__ __launch_bounds__(256)
void wtrall_k(WtrTab tab)
{
    const int bid = blockIdx.x;
    int e = 0;
#pragma unroll
    for (int i=1;i<8;i++) if (bid >= tab.d[i].base) e = i;
    const float* src = tab.d[e].src;
    uint16_t* dh = tab.d[e].dh;
    const int Ksz = tab.d[e].Ksz, Nsz = tab.d[e].Nsz;
    const int ntx = tab.d[e].ntx, nty = tab.d[e].nty;
    const size_t zs = tab.d[e].zstride;
    int local = bid - tab.d[e].base;
    const int tilesper = ntx*nty;
    const int z = local / tilesper;
    local -= z*tilesper;
    const int tyi = local / ntx;
    const int txi = local - tyi*ntx;
    src += (size_t)z*Ksz*Nsz; dh += (size_t)z*zs;
    const int kt = tyi*32, nt = txi*32;

    __shared__ float tile[32][33];
    const int i = threadIdx.x >> 3;
    const int j4 = (threadIdx.x & 7) * 4;
#pragma unroll
    for (int c=0;c<4;c++){
        int n = nt + j4 + c;
        tile[i][j4+c] = (n < Nsz) ? src[(size_t)(kt+i)*Nsz + n] : 0.0f;
    }
    __syncthreads();
    int n = nt + i;
    if (n < Nsz){
#pragma unroll
        for (int c=0;c<4;c++)
            dh[(size_t)n*Ksz + kt + j4 + c] = f2h(tile[j4+c][i]);
    }
}

__global__ void catb_k(const float* __restrict__ bq, const float* __restrict__ bk,
                       const float* __restrict__ bv, float* __restrict__ dst){
    int j = blockIdx.x*256 + threadIdx.x;
    if (j >= 3072) return;
    int layer = j / 1536, r = j - layer*1536;
    float v;
    if (r < 512)       v = bq[layer*512 + r];
    else if (r < 1024) v = bk[layer*512 + r - 512];
    else               v = bv[layer*512 + r - 1024];
    dst[j] = v;
}

// ---------------------------------------------------------------------------
// MFMA flash attention, fp16 Q/K/V/P, fp32 softmax, fp16 output.
// ---------------------------------------------------------------------------
__global__ __launch_bounds__(256, 4)
void attnm_k(const uint16_t* __restrict__ qs, const uint16_t* __restrict__ ks,
             const uint16_t* __restrict__ vts, uint16_t* __restrict__ oh)
{
    const int qt = blockIdx.x;
    const int h  = blockIdx.y;
    const int b  = blockIdx.z;
    const int bh = b*HH + h;
    const int q0 = qt*64;
    const int tid  = threadIdx.x;
    const int lane = tid & 63;
    const int wu   = __builtin_amdgcn_readfirstlane(tid >> 6);
    const int mrow = lane & 15;
    const int kgrp = lane >> 4;

    __shared__ uint16_t Khs[4096];
    __shared__ uint16_t Vhs[4096];
    __shared__ uint16_t Phs[4096];

    int tq = q0 + wu*16 + mrow; if (tq > TT-1) tq = TT-1;
    const uint16_t* qbase = qs + ((size_t)bh*TT + tq)*64 + kgrp*8;
    f16x8 qfh[2];
    qfh[0] = ldh8(qbase);      qfh[1] = ldh8(qbase + 32);

    const int srw = lane >> 3;
    const int sg  = lane & 7;

    f32x4 oacc[4];
#pragma unroll
    for (int f=0;f<4;f++) oacc[f] = (f32x4){0.f,0.f,0.f,0.f};
    float m_r[4] = {-1e30f,-1e30f,-1e30f,-1e30f};
    float l_r[4] = {0.f,0.f,0.f,0.f};

    for (int st=0; st<9; ++st){
        const int s0 = st*64;
        __syncthreads();
#pragma unroll
        for (int c=0;c<2;c++){
            const int r   = wu*16 + c*8 + srw;
            const int gsl = sg ^ (r & 7);
            int sk = s0 + r; if (sk > TT-1) sk = TT-1;
            const uint16_t* ksh_ = ks  + ((size_t)bh*TT + sk)*64 + gsl*8;
            int cb = s0 + gsl*8; if (cb > VSTR-8) cb = VSTR-8;
            const uint16_t* vsh_ = vts + ((size_t)bh*64 + r)*VSTR + cb;
            gl16(ksh_, &Khs[(wu*16 + c*8)*64]);
            gl16(vsh_, &Vhs[(wu*16 + c*8)*64]);
        }
        __syncthreads();

        f32x4 sacc[4];
#pragma unroll
        for (int f=0;f<4;f++) sacc[f] = (f32x4){0.f,0.f,0.f,0.f};
#pragma unroll
        for (int ks2=0; ks2<2; ks2++){
#pragma unroll
            for (int f=0; f<4; f++){
                const int sr = f*16 + mrow;
                const int sl = ((ks2*4 + kgrp) ^ (sr & 7))*8;
                f16x8 kbh = ldh8(&Khs[sr*64 + sl]);
                sacc[f] = __builtin_amdgcn_mfma_f32_16x16x32_f16(qfh[ks2], kbh, sacc[f], 0,0,0);
            }
        }

        float alpha[4];
#pragma unroll
        for (int r=0;r<4;r++){
            float mx = -1e30f;
#pragma unroll
            for (int f=0;f<4;f++){
                float sv = sacc[f][r];              // Q pre-scaled by 1/8
                if (s0 + f*16 + mrow >= TT) sv = -1e30f;
                sacc[f][r] = sv;
                mx = fmaxf(mx, sv);
            }
#pragma unroll
            for (int msk=1; msk<16; msk<<=1) mx = fmaxf(mx, __shfl_xor(mx, msk));
            float mn = fmaxf(m_r[r], mx);
            alpha[r] = __expf(m_r[r] - mn);
            m_r[r] = mn;
            float rs = 0.0f;
#pragma unroll
            for (int f=0;f<4;f++){
                float e = __expf(sacc[f][r] - mn);
                sacc[f][r] = e;
                rs += e;
            }
#pragma unroll
            for (int msk=1; msk<16; msk<<=1) rs += __shfl_xor(rs, msk);
            l_r[r] = l_r[r]*alpha[r] + rs;
#pragma unroll
            for (int f=0;f<4;f++) oacc[f][r] *= alpha[r];
        }

#pragma unroll
        for (int r=0;r<4;r++){
            const int tr = wu*16 + kgrp*4 + r;
#pragma unroll
            for (int f=0;f<4;f++){
                const int c = f*16 + mrow;
                const int idx = tr*64 + ((c>>3) ^ (tr&7))*8 + (c&7);
                Phs[idx] = f2h(sacc[f][r]);
            }
        }
        // same-wave DS ordering: reads below touch only rows this wave wrote

#pragma unroll
        for (int ks2=0; ks2<2; ks2++){
            const int trr = wu*16 + mrow;
            const int psl = ((ks2*4 + kgrp) ^ (trr & 7))*8;
            f16x8 pah = ldh8(&Phs[trr*64 + psl]);
#pragma unroll
            for (int f=0; f<4; f++){
                const int dr = f*16 + mrow;
                const int vsl = ((ks2*4 + kgrp) ^ (dr & 7))*8;
                f16x8 vbh = ldh8(&Vhs[dr*64 + vsl]);
                oacc[f] = __builtin_amdgcn_mfma_f32_16x16x32_f16(pah, vbh, oacc[f], 0,0,0);
            }
        }
    }

#pragma unroll
    for (int r=0;r<4;r++){
        const int t = q0 + wu*16 + kgrp*4 + r;
        if (t < TT){
            const float inv = 1.0f / l_r[r];
#pragma unroll
            for (int f=0;f<4;f++){
                const int d = f*16 + mrow;
                size_t o = ((size_t)(b*TT + t))*DD + h*DHD + d;
                oh[o] = f2h(oacc[f][r]*inv);
            }
        }
    }
}

// ---------------------------------------------------------------------------
// Residual + LayerNorm: wave-per-row, fp32 in/out + fp16 plane out
// ---------------------------------------------------------------------------
__global__ __launch_bounds__(256)
void ln_k(const float* __restrict__ src, const float* __restrict__ res,
          const float* __restrict__ w, const float* __restrict__ bia,
          float* __restrict__ dst, uint16_t* __restrict__ dbh)
{
    const int r    = blockIdx.x*4 + (threadIdx.x >> 6);
    const int lane = threadIdx.x & 63;
    const int c0   = lane*8;
    const size_t off = (size_t)r*DD + c0;

    float4 x0 = *(const float4*)(src + off);
    float4 x1 = *(const float4*)(src + off + 4);
    if (res){
        float4 r0 = *(const float4*)(res + off);
        float4 r1 = *(const float4*)(res + off + 4);
        x0.x+=r0.x; x0.y+=r0.y; x0.z+=r0.z; x0.w+=r0.w;
        x1.x+=r1.x; x1.y+=r1.y; x1.z+=r1.z; x1.w+=r1.w;
    }
    float s  = x0.x+x0.y+x0.z+x0.w + x1.x+x1.y+x1.z+x1.w;
    float sq = x0.x*x0.x+x0.y*x0.y+x0.z*x0.z+x0.w*x0.w
             + x1.x*x1.x+x1.y*x1.y+x1.z*x1.z+x1.w*x1.w;
#pragma unroll
    for (int msk=1; msk<64; msk<<=1){
        s  += __shfl_xor(s,  msk);
        sq += __shfl_xor(sq, msk);
    }
    float mu  = s * (1.0f/512.0f);
    float var = sq * (1.0f/512.0f) - mu*mu;
    float rsd = rsqrtf(var + 1e-5f);

    float4 w0 = *(const float4*)(w + c0);
    float4 w1 = *(const float4*)(w + c0 + 4);
    float4 b0 = *(const float4*)(bia + c0);
    float4 b1 = *(const float4*)(bia + c0 + 4);
    float y[8];
    y[0]=(x0.x-mu)*rsd*w0.x+b0.x; y[1]=(x0.y-mu)*rsd*w0.y+b0.y;
    y[2]=(x0.z-mu)*rsd*w0.z+b0.z; y[3]=(x0.w-mu)*rsd*w0.w+b0.w;
    y[4]=(x1.x-mu)*rsd*w1.x+b1.x; y[5]=(x1.y-mu)*rsd*w1.y+b1.y;
    y[6]=(x1.z-mu)*rsd*w1.z+b1.z; y[7]=(x1.w-mu)*rsd*w1.w+b1.w;

    float4 o0; o0.x=y[0]; o0.y=y[1]; o0.z=y[2]; o0.w=y[3];
    float4 o1; o1.x=y[4]; o1.y=y[5]; o1.z=y[6]; o1.w=y[7];
    *(float4*)(dst + off)     = o0;
    *(float4*)(dst + off + 4) = o1;

    u16x8 vh;
#pragma unroll
    for (int i=0;i<8;i++) vh[i] = f2h(y[i]);
    *(u16x8*)(dbh + off) = vh;
}

// ---------------------------------------------------------------------------
// sims v4 (unchanged, fp32)
// ---------------------------------------------------------------------------
__global__ __launch_bounds__(256, 4)
void sims_k(const float* __restrict__ pred, const float* __restrict__ bank,
            float* __restrict__ dotp, float* __restrict__ nrmp)
{
    const int jt = blockIdx.x, kt = blockIdx.y;
    const int tid  = threadIdx.x;
    const int qq    = tid & 7;
    const int slice = tid >> 3;
    const int sb    = slice*8;
    const int srow  = tid >> 4;
    const int tau   = tid & 15;

    __shared__ float BS[16*264];

    const int jr = jt*16 + srow;
    const float* bsrc = (jr < MM) ? (bank + (size_t)jr*PN)
                                  : (pred + (size_t)(jr - MM)*PN);
    bsrc += (size_t)kt*SCHUNK + tau*4;
    const float* p0 = pred + (size_t)qq*PN      + (size_t)kt*SCHUNK + sb;
    const float* p1 = pred + (size_t)(qq+8)*PN  + (size_t)kt*SCHUNK + sb;

    float acc0[16], acc1[16];
#pragma unroll
    for (int j=0;j<16;j++){ acc0[j] = 0.0f; acc1[j] = 0.0f; }
    float nr = 0.0f;

    float4 blv[4], pr0[2], pr1[2];
#pragma unroll
    for (int c=0;c<4;c++) blv[c] = *(const float4*)(bsrc + c*64);
    pr0[0] = *(const float4*)(p0); pr0[1] = *(const float4*)(p0 + 4);
    pr1[0] = *(const float4*)(p1); pr1[1] = *(const float4*)(p1 + 4);
    bsrc += 256; p0 += 256; p1 += 256;

    for (int st=0; st<SSTG; ++st){
#pragma unroll
        for (int c=0;c<4;c++){
            *(float4*)&BS[srow*264 + tau*4 + c*64] = blv[c];
            nr = fmaf(blv[c].x, blv[c].x, nr);
            nr = fmaf(blv[c].y, blv[c].y, nr);
            nr = fmaf(blv[c].z, blv[c].z, nr);
            nr = fmaf(blv[c].w, blv[c].w, nr);
        }
        float4 cp0[2] = {pr0[0], pr0[1]};
        float4 cp1[2] = {pr1[0], pr1[1]};
        if (st + 1 < SSTG){
#pragma unroll
            for (int c=0;c<4;c++) blv[c] = *(const float4*)(bsrc + c*64);
            pr0[0] = *(const float4*)(p0); pr0[1] = *(const float4*)(p0 + 4);
            pr1[0] = *(const float4*)(p1); pr1[1] = *(const float4*)(p1 + 4);
            bsrc += 256; p0 += 256; p1 += 256;
        }
        __syncthreads();
#pragma unroll
        for (int j=0;j<16;j++){
            float4 b0 = *(const float4*)&BS[j*264 + sb];
            float4 b1 = *(const float4*)&BS[j*264 + sb + 4];
            float a0 = acc0[j], a1 = acc1[j];
            a0 = fmaf(b0.x, cp0[0].x, a0); a0 = fmaf(b0.y, cp0[0].y, a0);
            a0 = fmaf(b0.z, cp0[0].z, a0); a0 = fmaf(b0.w, cp0[0].w, a0);
            a0 = fmaf(b1.x, cp0[1].x, a0); a0 = fmaf(b1.y, cp0[1].y, a0);
            a0 = fmaf(b1.z, cp0[1].z, a0); a0 = fmaf(b1.w, cp0[1].w, a0);
            a1 = fmaf(b0.x, cp1[0].x, a1); a1 = fmaf(b0.y, cp1[0].y, a1);
            a1 = fmaf(b0.z, cp1[0].z, a1); a1 = fmaf(b0.w, cp1[0].w, a1);
            a1 = fmaf(b1.x, cp1[1].x, a1); a1 = fmaf(b1.y, cp1[1].y, a1);
            a1 = fmaf(b1.z, cp1[1].z, a1); a1 = fmaf(b1.w, cp1[1].w, a1);
            acc0[j] = a0; acc1[j] = a1;
        }
        __syncthreads();
    }

#pragma unroll
    for (int m=8; m<64; m<<=1){
#pragma unroll
        for (int j=0;j<16;j++){
            acc0[j] += __shfl_xor(acc0[j], m);
            acc1[j] += __shfl_xor(acc1[j], m);
        }
    }
#pragma unroll
    for (int m=1;m<16;m<<=1) nr += __shfl_xor(nr, m);

    __syncthreads();
    float* RED = BS;
    const int wu2  = tid >> 6;
    const int lane = tid & 63;
    if (lane < 8){
#pragma unroll
        for (int j=0;j<16;j++){
            RED[(wu2*16 + j)*16 + lane]     = acc0[j];
            RED[(wu2*16 + j)*16 + lane + 8] = acc1[j];
        }
    }
    __syncthreads();
    const int j2 = tid >> 4, q2 = tid & 15;
    float s = RED[(0*16 + j2)*16 + q2] + RED[(1*16 + j2)*16 + q2]
            + RED[(2*16 + j2)*16 + q2] + RED[(3*16 + j2)*16 + q2];
    dotp[((size_t)kt*528 + jt*16 + j2)*16 + q2] = s;
    if (tau == 0) nrmp[kt*528 + jt*16 + srow] = nr;
}

// ---------------------------------------------------------------------------
// Fused sims tail (unchanged)
// ---------------------------------------------------------------------------
__global__ __launch_bounds__(256)
void simstail_k(const float* __restrict__ dotp, const float* __restrict__ nrmp,
                int* __restrict__ idx)
{
    const int q   = blockIdx.x;
    const int tid = threadIdx.x;
    __shared__ float invn[528];
    __shared__ float vals[528];

    for (int j=tid; j<528; j+=256){
        float s = 0.0f;
        for (int kt=0; kt<SKC; kt++) s += nrmp[kt*528 + j];
        invn[j] = 1.0f/(sqrtf(s) + 1e-8f);
    }
    __syncthreads();
    const float invq = invn[MM + q];
    for (int j=tid; j<528; j+=256){
        float s = 0.0f;
        for (int kt=0; kt<SKC; kt++) s += dotp[((size_t)kt*528 + j)*16 + q];
        vals[j] = s * invn[j] * invq;
    }
    __syncthreads();
    if (tid < 64){
        const int lane = tid;
        for (int kk=0; kk<KNN; kk++){
            float bv = -3.0e38f; int bi = 1<<30;
            for (int j=lane; j<528; j+=64){
                float v2 = vals[j];
                if (v2 > bv || (v2 == bv && j < bi)){ bv = v2; bi = j; }
            }
#pragma unroll
            for (int msk=1; msk<64; msk<<=1){
                float ov = __shfl_xor(bv, msk);
                int   oi = __shfl_xor(bi, msk);
                if (ov > bv || (ov == bv && oi < bi)){ bv = ov; bi = oi; }
            }
            if (lane == 0){
                idx[q*KNN + kk] = bi;
                vals[bi] = -3.0e38f;
            }
        }
    }
}

__global__ __launch_bounds__(256)
void fuse_k(const float* __restrict__ pred, const float* __restrict__ bank,
            const int* __restrict__ idx, float* __restrict__ out){
    int u = blockIdx.x*256 + threadIdx.x;
    int b = u / (PN/4);
    int e = (u - b*(PN/4)) * 4;
    int id[KNN];
#pragma unroll
    for (int k2=0;k2<KNN;k2++) id[k2] = idx[b*KNN + k2];
    float4 pv = *(const float4*)(pred + (size_t)b*PN + e);
    float ax = 0.5f*pv.x, ay = 0.5f*pv.y, az = 0.5f*pv.z, aw = 0.5f*pv.w;
#pragma unroll
    for (int k2=0;k2<KNN;k2++){
        const float* rp = (id[k2] < MM) ? (bank + (size_t)id[k2]*PN)
                                        : (pred + (size_t)(id[k2]-MM)*PN);
        float4 rv = *(const float4*)(rp + e);
        ax = fmaf(0.05f, rv.x, ax); ay = fmaf(0.05f, rv.y, ay);
        az = fmaf(0.05f, rv.z, az); aw = fmaf(0.05f, rv.w, aw);
    }
    float4 ov; ov.x=ax; ov.y=ay; ov.z=az; ov.w=aw;
    *(float4*)(out + (size_t)b*PN + e) = ov;
}

// ---------------------------------------------------------------------------
extern "C" void kernel_launch(void* const* d_in, const int* in_sizes, int n_in,
                              void* d_out, int out_size, void* d_ws, size_t ws_size,
                              hipStream_t stream)
{
    (void)in_sizes; (void)n_in; (void)out_size; (void)ws_size;
    const float* x_enc  = (const float*)d_in[0];
    const float* x_mark = (const float*)d_in[1];
    const float* W_emb  = (const float*)d_in[4];
    const float* b_emb  = (const float*)d_in[5];
    const float* Wq  = (const float*)d_in[6];
    const float* Wk  = (const float*)d_in[7];
    const float* Wv  = (const float*)d_in[8];
    const float* Wo  = (const float*)d_in[9];
    const float* bq  = (const float*)d_in[10];
    const float* bk  = (const float*)d_in[11];
    const float* bv_ = (const float*)d_in[12];
    const float* bo  = (const float*)d_in[13];
    const float* ln1w = (const float*)d_in[14];
    const float* ln1b = (const float*)d_in[15];
    const float* ln2w = (const float*)d_in[16];
    const float* ln2b = (const float*)d_in[17];
    const float* Wff1 = (const float*)d_in[18];
    const float* bff1 = (const float*)d_in[19];
    const float* Wff2 = (const float*)d_in[20];
    const float* bff2 = (const float*)d_in[21];
    const float* lnfw = (const float*)d_in[22];
    const float* lnfb = (const float*)d_in[23];
    const float* Wproj = (const float*)d_in[24];
    const float* bproj = (const float*)d_in[25];
    const float* bank  = (const float*)d_in[26];
    float* out = (float*)d_out;

    char* pp = (char*)d_ws;
    auto a16 = [&](size_t elems)->uint16_t*{ uint16_t* r=(uint16_t*)pp; pp += ((elems*2 + 255)/256)*256; return r; };
    auto af  = [&](size_t elems)->float*  { float* r=(float*)pp;  pp += ((elems*4 + 255)/256)*256; return r; };

    uint16_t* wembT = a16(262144);
    uint16_t* wqkvT = a16((size_t)2*1536*512);
    uint16_t* woT   = a16((size_t)2*262144);
    uint16_t* wff1T = a16((size_t)2*2048*512);
    uint16_t* wff2T = a16((size_t)2*512*2048);
    uint16_t* wprjT = a16(172032);
    float*    bqkv  = af(3072);
    uint16_t* hb    = a16((size_t)BT*512);
    uint16_t* tok   = a16((size_t)BT*512);
    float*    og    = af((size_t)BT*512);
    uint16_t* qsh   = a16((size_t)128*TT*64);
    uint16_t* ksh   = a16((size_t)128*TT*64);
    uint16_t* vsh   = a16((size_t)128*64*VSTR + 4096);
    uint16_t* t1b   = a16((size_t)BT*512);
    uint16_t* midb  = qsh;   // FF1 out aliases qsh..t1b (all dead at FF1 time)
    float*    h     = af((size_t)BT*512);
    float*    pred  = af((size_t)BB*PN);
    float*    dotp  = af((size_t)SKC*528*16);
    float*    nrmp  = af(SKC*528);
    int*      idxp  = (int*)af(256);

    dim3 blk(256);

    tok_k<<<dim3(17,16,BB), blk, 0, stream>>>(x_enc, x_mark, tok);

    WtrTab tab;
    tab.d[0] = { W_emb, wembT, 512, 512, 16, 16, 262144, 0 };
    tab.d[1] = { Wq, wqkvT,          512, 512, 16, 16, 786432, 256 };
    tab.d[2] = { Wk, wqkvT + 262144, 512, 512, 16, 16, 786432, 768 };
    tab.d[3] = { Wv, wqkvT + 524288, 512, 512, 16, 16, 786432, 1280 };
    tab.d[4] = { Wo, woT, 512, 512, 16, 16, 262144, 1792 };
    tab.d[5] = { Wff1, wff1T, 512, 2048, 64, 16, 1048576, 2304 };
    tab.d[6] = { Wff2, wff2T, 2048, 512, 16, 64, 1048576, 4352 };
    tab.d[7] = { Wproj, wprjT, 512, 336, 11, 16, 172032, 6400 };
    wtrall_k<<<dim3(6576), blk, 0, stream>>>(tab);
    catb_k<<<dim3(12), blk, 0, stream>>>(bq, bk, bv_, bqkv);

    bgemm64<EPI_F32|EPI_H16><<<dim3(8,65), blk, 0, stream>>>(
        tok, wembT, b_emb, h, hb, BT, 512, 512);

    for (int i=0;i<2;i++){
        bgemm<EPI_QKV><<<dim3(12,65), blk, 0, stream>>>(
            hb, wqkvT + (size_t)i*786432, bqkv + i*1536,
            nullptr, qsh, ksh, vsh, BT, 1536, 512);
        attnm_k<<<dim3(9,HH,BB), blk, 0, stream>>>(qsh, ksh, vsh, t1b);
        bgemm64<EPI_F32><<<dim3(8,65), blk, 0, stream>>>(
            t1b, woT + (size_t)i*262144, bo + i*512, og, nullptr, BT, 512, 512);
        ln_k<<<dim3(BT/4), blk, 0, stream>>>(h, og, ln1w + i*512, ln1b + i*512, h, hb);
        bgemm<EPI_GELU|EPI_H16><<<dim3(16,65), blk, 0, stream>>>(
            hb, wff1T + (size_t)i*1048576, bff1 + i*DFFN,
            nullptr, midb, nullptr, nullptr, BT, DFFN, 512);
        bgemm64<EPI_F32><<<dim3(8,65), blk, 0, stream>>>(
            midb, wff2T + (size_t)i*1048576, bff2 + i*512, og, nullptr, BT, 512, DFFN);
        ln_k<<<dim3(BT/4), blk, 0, stream>>>(h, og, ln2w + i*512, ln2b + i*512, h, hb);
    }

    ln_k<<<dim3(BT/4), blk, 0, stream>>>(h, nullptr, lnfw, lnfb, h, hb);

    bgemm64<EPI_PREDT><<<dim3(6,65), blk, 0, stream>>>(
        hb, wprjT, bproj, pred, nullptr, BT, PP, 512);

    sims_k<<<dim3(33,SKC), blk, 0, stream>>>(pred, bank, dotp, nrmp);
    simstail_k<<<dim3(BB), blk, 0, stream>>>(dotp, nrmp, idxp);
    fuse_k<<<dim3((BB*PN/4)/256), blk, 0, stream>>>(pred, bank, idxp, out);
}

// Round 13
// 668.242 us; speedup vs baseline: 1.8296x; 1.0343x over previous
//
#include <hip/hip_runtime.h>
#include <stdint.h>
#include <math.h>

#define TT 516
#define BB 16
#define DD 512
#define LL 512
#define NN 512
#define HH 8
#define DHD 64
#define DFFN 2048
#define PP 336
#define MM 512
#define KNN 10
#define BT (BB*TT)      /* 8256 */
#define PN (PP*NN)      /* 172032 */
#define SKC 32          /* sims k-chunks */
#define SCHUNK (PN/SKC) /* 5376 */
#define SSTG (SCHUNK/256) /* 21 stages */
#define VSTR 528        /* transposed-V row stride (uint16 elems) */

using f32x4 = __attribute__((ext_vector_type(4))) float;
using f16x8 = __attribute__((ext_vector_type(8))) _Float16;
using u16x8 = __attribute__((ext_vector_type(8))) unsigned short;

__device__ __forceinline__ float gelu_tanh(float x){
    float x3 = x*x*x;
    return 0.5f*x*(1.0f + tanhf(0.7978845608028654f*(x + 0.044715f*x3)));
}

__device__ __forceinline__ uint16_t f2h(float x){
    _Float16 h = (_Float16)x;
    return __builtin_bit_cast(uint16_t, h);
}

__device__ __forceinline__ void gl16(const uint16_t* g, uint16_t* l){
    __builtin_amdgcn_global_load_lds(
        (const __attribute__((address_space(1))) unsigned int*)(const void*)g,
        (__attribute__((address_space(3))) unsigned int*)(void*)l, 16, 0, 0);
}

__device__ __forceinline__ f16x8 ldh8(const uint16_t* p){
    return __builtin_bit_cast(f16x8, *(const u16x8*)p);
}

#define EPI_F32   1
#define EPI_H16   2
#define EPI_GELU  4
#define EPI_PREDT 8
#define EPI_QKV   16

// ---------------------------------------------------------------------------
// Unified fp16 single-pass MFMA GEMM: 128xBN tile, BK=64 (one barrier pair
// per 64 K — round-8-proven schedule, now for all shapes). BN in {64,128}.
// LDS = 16 + BN/8 KB -> 4 blocks/CU.
// ---------------------------------------------------------------------------
template<int BN, int FLAGS>
__global__ __launch_bounds__(256, 4)
void ggemm(const uint16_t* __restrict__ Ah, const uint16_t* __restrict__ Bh,
           const float* __restrict__ bias, float* __restrict__ Cf,
           uint16_t* __restrict__ Cb, uint16_t* __restrict__ Xkh,
           uint16_t* __restrict__ Xvh, int Msz, int Nsz, int Ksz)
{
    constexpr int FN = BN/32;            // frags per wave in N; also B groups/wave
    __shared__ uint16_t As0[8192];       // 128 rows x 64 k
    __shared__ uint16_t Bs0[BN*64];      // BN rows x 64 k

    const int tid  = threadIdx.x;
    const int lane = tid & 63;
    const int wu   = __builtin_amdgcn_readfirstlane(tid >> 6);
    const int wm   = wu >> 1, wn = wu & 1;
    const int m0   = blockIdx.y * 128;
    const int n0   = blockIdx.x * BN;

    // staging: each gl16 moves 512 contig elems = 8 rows x 64 k (linear LDS
    // dest); source k-granule pre-swizzled: LDS[r][g] <- global g^(r&7).
    const int sr8 = lane >> 3;
    const int skw = (((lane & 7) ^ sr8) * 8);

    int rA[4], rB[FN];
#pragma unroll
    for (int i=0;i<4;i++){
        int r = m0 + (wu*4 + i)*8 + sr8;
        rA[i] = (r > Msz-1) ? Msz-1 : r;
    }
#pragma unroll
    for (int i=0;i<FN;i++){
        int r = n0 + (wu*FN + i)*8 + sr8;
        rB[i] = (r > Nsz-1) ? Nsz-1 : r;
    }

    f32x4 acc[4][FN];
#pragma unroll
    for (int i=0;i<4;i++)
#pragma unroll
        for (int j=0;j<FN;j++) acc[i][j] = (f32x4){0.f,0.f,0.f,0.f};

    const int lc16 = lane & 15;
    const int kgrp = lane >> 4;

    for (int kt = 0; kt < Ksz; kt += 64){
#pragma unroll
        for (int i=0;i<4;i++)
            gl16(Ah + (size_t)rA[i]*Ksz + kt + skw, &As0[(wu*4 + i)*512]);
#pragma unroll
        for (int i=0;i<FN;i++)
            gl16(Bh + (size_t)rB[i]*Ksz + kt + skw, &Bs0[(wu*FN + i)*512]);
        __syncthreads();

#pragma unroll
        for (int ks=0; ks<2; ks++){
            f16x8 ah[4];
#pragma unroll
            for (int fm=0; fm<4; fm++){
                const int r   = wm*64 + fm*16 + lc16;
                const int off = r*64 + (((ks*4 + kgrp) ^ (r & 7))*8);
                ah[fm] = ldh8(&As0[off]);
            }
#pragma unroll
            for (int fn=0; fn<FN; fn++){
                const int rb   = wn*(BN/2) + fn*16 + lc16;
                const int offb = rb*64 + (((ks*4 + kgrp) ^ (rb & 7))*8);
                f16x8 bh = ldh8(&Bs0[offb]);
#pragma unroll
                for (int fm=0; fm<4; fm++)
                    acc[fm][fn] = __builtin_amdgcn_mfma_f32_16x16x32_f16(ah[fm], bh, acc[fm][fn], 0,0,0);
            }
        }
        __syncthreads();
    }

    const int lr4 = (lane >> 4) * 4;
#pragma unroll
    for (int fm=0; fm<4; fm++){
        const int rbase = m0 + wm*64 + fm*16 + lr4;
#pragma unroll
        for (int fn=0; fn<FN; fn++){
            const int col = n0 + wn*(BN/2) + fn*16 + lc16;
            f32x4 v = acc[fm][fn];
            if (FLAGS & EPI_QKV){
                const int g   = col >> 9;
                const int cc2 = col & 511;
                const int hh2 = cc2 >> 6, dd2 = cc2 & 63;
                const float bcol = bias[col];
#pragma unroll
                for (int r=0;r<4;r++){
                    int row = rbase + r;
                    if (row < Msz){
                        float x = v[r] + bcol;
                        int b2 = row / TT, t2 = row - b2*TT;
                        int bh2 = b2*HH + hh2;
                        if (g == 0){
                            size_t o = ((size_t)bh2*TT + t2)*64 + dd2;
                            Cb[o] = f2h(x * 0.125f);     // fold softmax scale into Q
                        } else if (g == 1){
                            size_t o = ((size_t)bh2*TT + t2)*64 + dd2;
                            Xkh[o] = f2h(x);
                        } else {
                            size_t o = ((size_t)bh2*64 + dd2)*VSTR + t2;
                            Xvh[o] = f2h(x);
                        }
                    }
                }
            } else if (FLAGS & EPI_PREDT){
#pragma unroll
                for (int r=0;r<4;r++){
                    int row = rbase + r;
                    if (row < Msz && col < PP){
                        int b = row / TT, t = row - b*TT;
                        if (t < NN)
                            Cf[((size_t)b*PP + col)*NN + t] = v[r] + bias[col];
                    }
                }
            } else {
                const float bcol = bias[col];
#pragma unroll
                for (int r=0;r<4;r++){
                    int row = rbase + r;
                    if (row < Msz){
                        float x = v[r] + bcol;
                        if (FLAGS & EPI_GELU) x = gelu_tanh(x);
                        if (FLAGS & EPI_F32) Cf[(size_t)row*Nsz + col] = x;
                        if (FLAGS & EPI_H16) Cb[(size_t)row*Nsz + col] = f2h(x);
                    }
                }
            }
        }
    }
}

// ---------------------------------------------------------------------------
// tok transpose -> fp16 single plane (unchanged)
// ---------------------------------------------------------------------------
__global__ __launch_bounds__(256)
void tok_k(const float* __restrict__ xe, const float* __restrict__ xm,
           uint16_t* __restrict__ th)
{
    const int b = blockIdx.z;
    const int t0 = blockIdx.x*32, l0 = blockIdx.y*32;
    __shared__ float tile[32][33];
    const int i = threadIdx.x >> 3;
    const int j4 = (threadIdx.x & 7) * 4;
#pragma unroll
    for (int c=0;c<4;c++){
        int t = t0 + j4 + c;
        float v = 0.0f;
        if (t < 512)      v = xe[((size_t)b*LL + l0+i)*NN + t];
        else if (t < 516) v = xm[((size_t)b*LL + l0+i)*4 + (t-512)];
        tile[i][j4+c] = v;
    }
    __syncthreads();
    int t = t0 + i;
    if (t < TT){
#pragma unroll
        for (int c=0;c<4;c++){
            size_t idx = ((size_t)b*TT + t)*512 + l0 + j4 + c;
            th[idx] = f2h(tile[j4+c][i]);
        }
    }
}

// ---------------------------------------------------------------------------
// ALL weight transposes in one launch, fp16 single plane (unchanged)
// ---------------------------------------------------------------------------
struct WtrDesc {
    const float* src; uint16_t* dh;
    int Ksz, Nsz, ntx, nty; size_t zstride; int base;
};
struct WtrTab { WtrDesc d[8]; };

__global__ __launch_bounds__(256)
void wtrall_k(WtrTab tab)
{
    const int bid = blockIdx.x;
    int e = 0;
#pragma unroll
    for (int i=1;i<8;i++) if (bid >= tab.d[i].base) e = i;
    const float* src = tab.d[e].src;
    uint16_t* dh = tab.d[e].dh;
    const int Ksz = tab.d[e].Ksz, Nsz = tab.d[e].Nsz;
    const int ntx = tab.d[e].ntx, nty = tab.d[e].nty;
    const size_t zs = tab.d[e].zstride;
    int local = bid - tab.d[e].base;
    const int tilesper = ntx*nty;
    const int z = local / tilesper;
    local -= z*tilesper;
    const int tyi = local / ntx;
    const int txi = local - tyi*ntx;
    src += (size_t)z*Ksz*Nsz; dh += (size_t)z*zs;
    const int kt = tyi*32, nt = txi*32;

    __shared__ float tile[32][33];
    const int i = threadIdx.x >> 3;
    const int j4 = (threadIdx.x & 7) * 4;
#pragma unroll
    for (int c=0;c<4;c++){
        int n = nt + j4 + c;
        tile[i][j4+c] = (n < Nsz) ? src[(size_t)(kt+i)*Nsz + n] : 0.0f;
    }
    __syncthreads();
    int n = nt + i;
    if (n < Nsz){
#pragma unroll
        for (int c=0;c<4;c++)
            dh[(size_t)n*Ksz + kt + j4 + c] = f2h(tile[j4+c][i]);
    }
}

__global__ void catb_k(const float* __restrict__ bq, const float* __restrict__ bk,
                       const float* __restrict__ bv, float* __restrict__ dst){
    int j = blockIdx.x*256 + threadIdx.x;
    if (j >= 3072) return;
    int layer = j / 1536, r = j - layer*1536;
    float v;
    if (r < 512)       v = bq[layer*512 + r];
    else if (r < 1024) v = bk[layer*512 + r - 512];
    else               v = bv[layer*512 + r - 1024];
    dst[j] = v;
}

// ---------------------------------------------------------------------------
// MFMA flash attention, fp16 (unchanged from round 12)
// ---------------------------------------------------------------------------
__global__ __launch_bounds__(256, 4)
void attnm_k(const uint16_t* __restrict__ qs, const uint16_t* __restrict__ ks,
             const uint16_t* __restrict__ vts, uint16_t* __restrict__ oh)
{
    const int qt = blockIdx.x;
    const int h  = blockIdx.y;
    const int b  = blockIdx.z;
    const int bh = b*HH + h;
    const int q0 = qt*64;
    const int tid  = threadIdx.x;
    const int lane = tid & 63;
    const int wu   = __builtin_amdgcn_readfirstlane(tid >> 6);
    const int mrow = lane & 15;
    const int kgrp = lane >> 4;

    __shared__ uint16_t Khs[4096];
    __shared__ uint16_t Vhs[4096];
    __shared__ uint16_t Phs[4096];

    int tq = q0 + wu*16 + mrow; if (tq > TT-1) tq = TT-1;
    const uint16_t* qbase = qs + ((size_t)bh*TT + tq)*64 + kgrp*8;
    f16x8 qfh[2];
    qfh[0] = ldh8(qbase);      qfh[1] = ldh8(qbase + 32);

    const int srw = lane >> 3;
    const int sg  = lane & 7;

    f32x4 oacc[4];
#pragma unroll
    for (int f=0;f<4;f++) oacc[f] = (f32x4){0.f,0.f,0.f,0.f};
    float m_r[4] = {-1e30f,-1e30f,-1e30f,-1e30f};
    float l_r[4] = {0.f,0.f,0.f,0.f};

    for (int st=0; st<9; ++st){
        const int s0 = st*64;
        __syncthreads();
#pragma unroll
        for (int c=0;c<2;c++){
            const int r   = wu*16 + c*8 + srw;
            const int gsl = sg ^ (r & 7);
            int sk = s0 + r; if (sk > TT-1) sk = TT-1;
            const uint16_t* ksh_ = ks  + ((size_t)bh*TT + sk)*64 + gsl*8;
            int cb = s0 + gsl*8; if (cb > VSTR-8) cb = VSTR-8;
            const uint16_t* vsh_ = vts + ((size_t)bh*64 + r)*VSTR + cb;
            gl16(ksh_, &Khs[(wu*16 + c*8)*64]);
            gl16(vsh_, &Vhs[(wu*16 + c*8)*64]);
        }
        __syncthreads();

        f32x4 sacc[4];
#pragma unroll
        for (int f=0;f<4;f++) sacc[f] = (f32x4){0.f,0.f,0.f,0.f};
#pragma unroll
        for (int ks2=0; ks2<2; ks2++){
#pragma unroll
            for (int f=0; f<4; f++){
                const int sr = f*16 + mrow;
                const int sl = ((ks2*4 + kgrp) ^ (sr & 7))*8;
                f16x8 kbh = ldh8(&Khs[sr*64 + sl]);
                sacc[f] = __builtin_amdgcn_mfma_f32_16x16x32_f16(qfh[ks2], kbh, sacc[f], 0,0,0);
            }
        }

        float alpha[4];
#pragma unroll
        for (int r=0;r<4;r++){
            float mx = -1e30f;
#pragma unroll
            for (int f=0;f<4;f++){
                float sv = sacc[f][r];              // Q pre-scaled by 1/8
                if (s0 + f*16 + mrow >= TT) sv = -1e30f;
                sacc[f][r] = sv;
                mx = fmaxf(mx, sv);
            }
#pragma unroll
            for (int msk=1; msk<16; msk<<=1) mx = fmaxf(mx, __shfl_xor(mx, msk));
            float mn = fmaxf(m_r[r], mx);
            alpha[r] = __expf(m_r[r] - mn);
            m_r[r] = mn;
            float rs = 0.0f;
#pragma unroll
            for (int f=0;f<4;f++){
                float e = __expf(sacc[f][r] - mn);
                sacc[f][r] = e;
                rs += e;
            }
#pragma unroll
            for (int msk=1; msk<16; msk<<=1) rs += __shfl_xor(rs, msk);
            l_r[r] = l_r[r]*alpha[r] + rs;
#pragma unroll
            for (int f=0;f<4;f++) oacc[f][r] *= alpha[r];
        }

#pragma unroll
        for (int r=0;r<4;r++){
            const int tr = wu*16 + kgrp*4 + r;
#pragma unroll
            for (int f=0;f<4;f++){
                const int c = f*16 + mrow;
                const int idx = tr*64 + ((c>>3) ^ (tr&7))*8 + (c&7);
                Phs[idx] = f2h(sacc[f][r]);
            }
        }
        // same-wave DS ordering: reads below touch only rows this wave wrote

#pragma unroll
        for (int ks2=0; ks2<2; ks2++){
            const int trr = wu*16 + mrow;
            const int psl = ((ks2*4 + kgrp) ^ (trr & 7))*8;
            f16x8 pah = ldh8(&Phs[trr*64 + psl]);
#pragma unroll
            for (int f=0; f<4; f++){
                const int dr = f*16 + mrow;
                const int vsl = ((ks2*4 + kgrp) ^ (dr & 7))*8;
                f16x8 vbh = ldh8(&Vhs[dr*64 + vsl]);
                oacc[f] = __builtin_amdgcn_mfma_f32_16x16x32_f16(pah, vbh, oacc[f], 0,0,0);
            }
        }
    }

#pragma unroll
    for (int r=0;r<4;r++){
        const int t = q0 + wu*16 + kgrp*4 + r;
        if (t < TT){
            const float inv = 1.0f / l_r[r];
#pragma unroll
            for (int f=0;f<4;f++){
                const int d = f*16 + mrow;
                size_t o = ((size_t)(b*TT + t))*DD + h*DHD + d;
                oh[o] = f2h(oacc[f][r]*inv);
            }
        }
    }
}

// ---------------------------------------------------------------------------
// Residual + LayerNorm (unchanged)
// ---------------------------------------------------------------------------
__global__ __launch_bounds__(256)
void ln_k(const float* __restrict__ src, const float* __restrict__ res,
          const float* __restrict__ w, const float* __restrict__ bia,
          float* __restrict__ dst, uint16_t* __restrict__ dbh)
{
    const int r    = blockIdx.x*4 + (threadIdx.x >> 6);
    const int lane = threadIdx.x & 63;
    const int c0   = lane*8;
    const size_t off = (size_t)r*DD + c0;

    float4 x0 = *(const float4*)(src + off);
    float4 x1 = *(const float4*)(src + off + 4);
    if (res){
        float4 r0 = *(const float4*)(res + off);
        float4 r1 = *(const float4*)(res + off + 4);
        x0.x+=r0.x; x0.y+=r0.y; x0.z+=r0.z; x0.w+=r0.w;
        x1.x+=r1.x; x1.y+=r1.y; x1.z+=r1.z; x1.w+=r1.w;
    }
    float s  = x0.x+x0.y+x0.z+x0.w + x1.x+x1.y+x1.z+x1.w;
    float sq = x0.x*x0.x+x0.y*x0.y+x0.z*x0.z+x0.w*x0.w
             + x1.x*x1.x+x1.y*x1.y+x1.z*x1.z+x1.w*x1.w;
#pragma unroll
    for (int msk=1; msk<64; msk<<=1){
        s  += __shfl_xor(s,  msk);
        sq += __shfl_xor(sq, msk);
    }
    float mu  = s * (1.0f/512.0f);
    float var = sq * (1.0f/512.0f) - mu*mu;
    float rsd = rsqrtf(var + 1e-5f);

    float4 w0 = *(const float4*)(w + c0);
    float4 w1 = *(const float4*)(w + c0 + 4);
    float4 b0 = *(const float4*)(bia + c0);
    float4 b1 = *(const float4*)(bia + c0 + 4);
    float y[8];
    y[0]=(x0.x-mu)*rsd*w0.x+b0.x; y[1]=(x0.y-mu)*rsd*w0.y+b0.y;
    y[2]=(x0.z-mu)*rsd*w0.z+b0.z; y[3]=(x0.w-mu)*rsd*w0.w+b0.w;
    y[4]=(x1.x-mu)*rsd*w1.x+b1.x; y[5]=(x1.y-mu)*rsd*w1.y+b1.y;
    y[6]=(x1.z-mu)*rsd*w1.z+b1.z; y[7]=(x1.w-mu)*rsd*w1.w+b1.w;

    float4 o0; o0.x=y[0]; o0.y=y[1]; o0.z=y[2]; o0.w=y[3];
    float4 o1; o1.x=y[4]; o1.y=y[5]; o1.z=y[6]; o1.w=y[7];
    *(float4*)(dst + off)     = o0;
    *(float4*)(dst + off + 4) = o1;

    u16x8 vh;
#pragma unroll
    for (int i=0;i<8;i++) vh[i] = f2h(y[i]);
    *(u16x8*)(dbh + off) = vh;
}

// ---------------------------------------------------------------------------
// sims v4 (unchanged, fp32)
// ---------------------------------------------------------------------------
__global__ __launch_bounds__(256, 4)
void sims_k(const float* __restrict__ pred, const float* __restrict__ bank,
            float* __restrict__ dotp, float* __restrict__ nrmp)
{
    const int jt = blockIdx.x, kt = blockIdx.y;
    const int tid  = threadIdx.x;
    const int qq    = tid & 7;
    const int slice = tid >> 3;
    const int sb    = slice*8;
    const int srow  = tid >> 4;
    const int tau   = tid & 15;

    __shared__ float BS[16*264];

    const int jr = jt*16 + srow;
    const float* bsrc = (jr < MM) ? (bank + (size_t)jr*PN)
                                  : (pred + (size_t)(jr - MM)*PN);
    bsrc += (size_t)kt*SCHUNK + tau*4;
    const float* p0 = pred + (size_t)qq*PN      + (size_t)kt*SCHUNK + sb;
    const float* p1 = pred + (size_t)(qq+8)*PN  + (size_t)kt*SCHUNK + sb;

    float acc0[16], acc1[16];
#pragma unroll
    for (int j=0;j<16;j++){ acc0[j] = 0.0f; acc1[j] = 0.0f; }
    float nr = 0.0f;

    float4 blv[4], pr0[2], pr1[2];
#pragma unroll
    for (int c=0;c<4;c++) blv[c] = *(const float4*)(bsrc + c*64);
    pr0[0] = *(const float4*)(p0); pr0[1] = *(const float4*)(p0 + 4);
    pr1[0] = *(const float4*)(p1); pr1[1] = *(const float4*)(p1 + 4);
    bsrc += 256; p0 += 256; p1 += 256;

    for (int st=0; st<SSTG; ++st){
#pragma unroll
        for (int c=0;c<4;c++){
            *(float4*)&BS[srow*264 + tau*4 + c*64] = blv[c];
            nr = fmaf(blv[c].x, blv[c].x, nr);
            nr = fmaf(blv[c].y, blv[c].y, nr);
            nr = fmaf(blv[c].z, blv[c].z, nr);
            nr = fmaf(blv[c].w, blv[c].w, nr);
        }
        float4 cp0[2] = {pr0[0], pr0[1]};
        float4 cp1[2] = {pr1[0], pr1[1]};
        if (st + 1 < SSTG){
#pragma unroll
            for (int c=0;c<4;c++) blv[c] = *(const float4*)(bsrc + c*64);
            pr0[0] = *(const float4*)(p0); pr0[1] = *(const float4*)(p0 + 4);
            pr1[0] = *(const float4*)(p1); pr1[1] = *(const float4*)(p1 + 4);
            bsrc += 256; p0 += 256; p1 += 256;
        }
        __syncthreads();
#pragma unroll
        for (int j=0;j<16;j++){
            float4 b0 = *(const float4*)&BS[j*264 + sb];
            float4 b1 = *(const float4*)&BS[j*264 + sb + 4];
            float a0 = acc0[j], a1 = acc1[j];
            a0 = fmaf(b0.x, cp0[0].x, a0); a0 = fmaf(b0.y, cp0[0].y, a0);
            a0 = fmaf(b0.z, cp0[0].z, a0); a0 = fmaf(b0.w, cp0[0].w, a0);
            a0 = fmaf(b1.x, cp0[1].x, a0); a0 = fmaf(b1.y, cp0[1].y, a0);
            a0 = fmaf(b1.z, cp0[1].z, a0); a0 = fmaf(b1.w, cp0[1].w, a0);
            a1 = fmaf(b0.x, cp1[0].x, a1); a1 = fmaf(b0.y, cp1[0].y, a1);
            a1 = fmaf(b0.z, cp1[0].z, a1); a1 = fmaf(b0.w, cp1[0].w, a1);
            a1 = fmaf(b1.x, cp1[1].x, a1); a1 = fmaf(b1.y, cp1[1].y, a1);
            a1 = fmaf(b1.z, cp1[1].z, a1); a1 = fmaf(b1.w, cp1[1].w, a1);
            acc0[j] = a0; acc1[j] = a1;
        }
        __syncthreads();
    }

#pragma unroll
    for (int m=8; m<64; m<<=1){
#pragma unroll
        for (int j=0;j<16;j++){
            acc0[j] += __shfl_xor(acc0[j], m);
            acc1[j] += __shfl_xor(acc1[j], m);
        }
    }
#pragma unroll
    for (int m=1;m<16;m<<=1) nr += __shfl_xor(nr, m);

    __syncthreads();
    float* RED = BS;
    const int wu2  = tid >> 6;
    const int lane = tid & 63;
    if (lane < 8){
#pragma unroll
        for (int j=0;j<16;j++){
            RED[(wu2*16 + j)*16 + lane]     = acc0[j];
            RED[(wu2*16 + j)*16 + lane + 8] = acc1[j];
        }
    }
    __syncthreads();
    const int j2 = tid >> 4, q2 = tid & 15;
    float s = RED[(0*16 + j2)*16 + q2] + RED[(1*16 + j2)*16 + q2]
            + RED[(2*16 + j2)*16 + q2] + RED[(3*16 + j2)*16 + q2];
    dotp[((size_t)kt*528 + jt*16 + j2)*16 + q2] = s;
    if (tau == 0) nrmp[kt*528 + jt*16 + srow] = nr;
}

// ---------------------------------------------------------------------------
// Fused sims tail (unchanged)
// ---------------------------------------------------------------------------
__global__ __launch_bounds__(256)
void simstail_k(const float* __restrict__ dotp, const float* __restrict__ nrmp,
                int* __restrict__ idx)
{
    const int q   = blockIdx.x;
    const int tid = threadIdx.x;
    __shared__ float invn[528];
    __shared__ float vals[528];

    for (int j=tid; j<528; j+=256){
        float s = 0.0f;
        for (int kt=0; kt<SKC; kt++) s += nrmp[kt*528 + j];
        invn[j] = 1.0f/(sqrtf(s) + 1e-8f);
    }
    __syncthreads();
    const float invq = invn[MM + q];
    for (int j=tid; j<528; j+=256){
        float s = 0.0f;
        for (int kt=0; kt<SKC; kt++) s += dotp[((size_t)kt*528 + j)*16 + q];
        vals[j] = s * invn[j] * invq;
    }
    __syncthreads();
    if (tid < 64){
        const int lane = tid;
        for (int kk=0; kk<KNN; kk++){
            float bv = -3.0e38f; int bi = 1<<30;
            for (int j=lane; j<528; j+=64){
                float v2 = vals[j];
                if (v2 > bv || (v2 == bv && j < bi)){ bv = v2; bi = j; }
            }
#pragma unroll
            for (int msk=1; msk<64; msk<<=1){
                float ov = __shfl_xor(bv, msk);
                int   oi = __shfl_xor(bi, msk);
                if (ov > bv || (ov == bv && oi < bi)){ bv = ov; bi = oi; }
            }
            if (lane == 0){
                idx[q*KNN + kk] = bi;
                vals[bi] = -3.0e38f;
            }
        }
    }
}

__global__ __launch_bounds__(256)
void fuse_k(const float* __restrict__ pred, const float* __restrict__ bank,
            const int* __restrict__ idx, float* __restrict__ out){
    int u = blockIdx.x*256 + threadIdx.x;
    int b = u / (PN/4);
    int e = (u - b*(PN/4)) * 4;
    int id[KNN];
#pragma unroll
    for (int k2=0;k2<KNN;k2++) id[k2] = idx[b*KNN + k2];
    float4 pv = *(const float4*)(pred + (size_t)b*PN + e);
    float ax = 0.5f*pv.x, ay = 0.5f*pv.y, az = 0.5f*pv.z, aw = 0.5f*pv.w;
#pragma unroll
    for (int k2=0;k2<KNN;k2++){
        const float* rp = (id[k2] < MM) ? (bank + (size_t)id[k2]*PN)
                                        : (pred + (size_t)(id[k2]-MM)*PN);
        float4 rv = *(const float4*)(rp + e);
        ax = fmaf(0.05f, rv.x, ax); ay = fmaf(0.05f, rv.y, ay);
        az = fmaf(0.05f, rv.z, az); aw = fmaf(0.05f, rv.w, aw);
    }
    float4 ov; ov.x=ax; ov.y=ay; ov.z=az; ov.w=aw;
    *(float4*)(out + (size_t)b*PN + e) = ov;
}

// ---------------------------------------------------------------------------
extern "C" void kernel_launch(void* const* d_in, const int* in_sizes, int n_in,
                              void* d_out, int out_size, void* d_ws, size_t ws_size,
                              hipStream_t stream)
{
    (void)in_sizes; (void)n_in; (void)out_size; (void)ws_size;
    const float* x_enc  = (const float*)d_in[0];
    const float* x_mark = (const float*)d_in[1];
    const float* W_emb  = (const float*)d_in[4];
    const float* b_emb  = (const float*)d_in[5];
    const float* Wq  = (const float*)d_in[6];
    const float* Wk  = (const float*)d_in[7];
    const float* Wv  = (const float*)d_in[8];
    const float* Wo  = (const float*)d_in[9];
    const float* bq  = (const float*)d_in[10];
    const float* bk  = (const float*)d_in[11];
    const float* bv_ = (const float*)d_in[12];
    const float* bo  = (const float*)d_in[13];
    const float* ln1w = (const float*)d_in[14];
    const float* ln1b = (const float*)d_in[15];
    const float* ln2w = (const float*)d_in[16];
    const float* ln2b = (const float*)d_in[17];
    const float* Wff1 = (const float*)d_in[18];
    const float* bff1 = (const float*)d_in[19];
    const float* Wff2 = (const float*)d_in[20];
    const float* bff2 = (const float*)d_in[21];
    const float* lnfw = (const float*)d_in[22];
    const float* lnfb = (const float*)d_in[23];
    const float* Wproj = (const float*)d_in[24];
    const float* bproj = (const float*)d_in[25];
    const float* bank  = (const float*)d_in[26];
    float* out = (float*)d_out;

    char* pp = (char*)d_ws;
    auto a16 = [&](size_t elems)->uint16_t*{ uint16_t* r=(uint16_t*)pp; pp += ((elems*2 + 255)/256)*256; return r; };
    auto af  = [&](size_t elems)->float*  { float* r=(float*)pp;  pp += ((elems*4 + 255)/256)*256; return r; };

    uint16_t* wembT = a16(262144);
    uint16_t* wqkvT = a16((size_t)2*1536*512);
    uint16_t* woT   = a16((size_t)2*262144);
    uint16_t* wff1T = a16((size_t)2*2048*512);
    uint16_t* wff2T = a16((size_t)2*512*2048);
    uint16_t* wprjT = a16(172032);
    float*    bqkv  = af(3072);
    uint16_t* hb    = a16((size_t)BT*512);
    uint16_t* tok   = a16((size_t)BT*512);
    float*    og    = af((size_t)BT*512);
    uint16_t* qsh   = a16((size_t)128*TT*64);
    uint16_t* ksh   = a16((size_t)128*TT*64);
    uint16_t* vsh   = a16((size_t)128*64*VSTR + 4096);
    uint16_t* t1b   = a16((size_t)BT*512);
    uint16_t* midb  = qsh;   // FF1 out aliases qsh..t1b (all dead at FF1 time)
    float*    h     = af((size_t)BT*512);
    float*    pred  = af((size_t)BB*PN);
    float*    dotp  = af((size_t)SKC*528*16);
    float*    nrmp  = af(SKC*528);
    int*      idxp  = (int*)af(256);

    dim3 blk(256);

    tok_k<<<dim3(17,16,BB), blk, 0, stream>>>(x_enc, x_mark, tok);

    WtrTab tab;
    tab.d[0] = { W_emb, wembT, 512, 512, 16, 16, 262144, 0 };
    tab.d[1] = { Wq, wqkvT,          512, 512, 16, 16, 786432, 256 };
    tab.d[2] = { Wk, wqkvT + 262144, 512, 512, 16, 16, 786432, 768 };
    tab.d[3] = { Wv, wqkvT + 524288, 512, 512, 16, 16, 786432, 1280 };
    tab.d[4] = { Wo, woT, 512, 512, 16, 16, 262144, 1792 };
    tab.d[5] = { Wff1, wff1T, 512, 2048, 64, 16, 1048576, 2304 };
    tab.d[6] = { Wff2, wff2T, 2048, 512, 16, 64, 1048576, 4352 };
    tab.d[7] = { Wproj, wprjT, 512, 336, 11, 16, 172032, 6400 };
    wtrall_k<<<dim3(6576), blk, 0, stream>>>(tab);
    catb_k<<<dim3(12), blk, 0, stream>>>(bq, bk, bv_, bqkv);

    ggemm<64, EPI_F32|EPI_H16><<<dim3(8,65), blk, 0, stream>>>(
        tok, wembT, b_emb, h, hb, nullptr, nullptr, BT, 512, 512);

    for (int i=0;i<2;i++){
        ggemm<128, EPI_QKV><<<dim3(12,65), blk, 0, stream>>>(
            hb, wqkvT + (size_t)i*786432, bqkv + i*1536,
            nullptr, qsh, ksh, vsh, BT, 1536, 512);
        attnm_k<<<dim3(9,HH,BB), blk, 0, stream>>>(qsh, ksh, vsh, t1b);
        ggemm<64, EPI_F32><<<dim3(8,65), blk, 0, stream>>>(
            t1b, woT + (size_t)i*262144, bo + i*512, og, nullptr,
            nullptr, nullptr, BT, 512, 512);
        ln_k<<<dim3(BT/4), blk, 0, stream>>>(h, og, ln1w + i*512, ln1b + i*512, h, hb);
        ggemm<128, EPI_GELU|EPI_H16><<<dim3(16,65), blk, 0, stream>>>(
            hb, wff1T + (size_t)i*1048576, bff1 + i*DFFN,
            nullptr, midb, nullptr, nullptr, BT, DFFN, 512);
        ggemm<64, EPI_F32><<<dim3(8,65), blk, 0, stream>>>(
            midb, wff2T + (size_t)i*1048576, bff2 + i*512, og, nullptr,
            nullptr, nullptr, BT, 512, DFFN);
        ln_k<<<dim3(BT/4), blk, 0, stream>>>(h, og, ln2w + i*512, ln2b + i*512, h, hb);
    }

    ln_k<<<dim3(BT/4), blk, 0, stream>>>(h, nullptr, lnfw, lnfb, h, hb);

    ggemm<64, EPI_PREDT><<<dim3(6,65), blk, 0, stream>>>(
        hb, wprjT, bproj, pred, nullptr, nullptr, nullptr, BT, PP, 512);

    sims_k<<<dim3(33,SKC), blk, 0, stream>>>(pred, bank, dotp, nrmp);
    simstail_k<<<dim3(BB), blk, 0, stream>>>(dotp, nrmp, idxp);
    fuse_k<<<dim3((BB*PN/4)/256), blk, 0, stream>>>(pred, bank, idxp, out);
}

// Round 14
// 637.129 us; speedup vs baseline: 1.9190x; 1.0488x over previous
//
#include <hip/hip_runtime.h>
#include <stdint.h>
#include <math.h>

#define TT 516
#define BB 16
#define DD 512
#define LL 512
#define NN 512
#define HH 8
#define DHD 64
#define DFFN 2048
#define PP 336
#define MM 512
#define KNN 10
#define BT (BB*TT)      /* 8256 */
#define PN (PP*NN)      /* 172032 */
#define SKC 32          /* sims k-chunks */
#define SCHUNK (PN/SKC) /* 5376 */
#define SSTG (SCHUNK/256) /* 21 stages */
#define VSTR 528        /* transposed-V row stride (uint16 elems) */

using f32x4 = __attribute__((ext_vector_type(4))) float;
using f16x8 = __attribute__((ext_vector_type(8))) _Float16;
using u16x8 = __attribute__((ext_vector_type(8))) unsigned short;

__device__ __forceinline__ float gelu_tanh(float x){
    float x3 = x*x*x;
    return 0.5f*x*(1.0f + tanhf(0.7978845608028654f*(x + 0.044715f*x3)));
}

__device__ __forceinline__ uint16_t f2h(float x){
    _Float16 h = (_Float16)x;
    return __builtin_bit_cast(uint16_t, h);
}

__device__ __forceinline__ float h2f(uint16_t u){
    return (float)__builtin_bit_cast(_Float16, u);
}

__device__ __forceinline__ void gl16(const uint16_t* g, uint16_t* l){
    __builtin_amdgcn_global_load_lds(
        (const __attribute__((address_space(1))) unsigned int*)(const void*)g,
        (__attribute__((address_space(3))) unsigned int*)(void*)l, 16, 0, 0);
}

__device__ __forceinline__ f16x8 ldh8(const uint16_t* p){
    return __builtin_bit_cast(f16x8, *(const u16x8*)p);
}

#define EPI_F32   1
#define EPI_H16   2
#define EPI_GELU  4
#define EPI_PREDT 8
#define EPI_QKV   16

// ---------------------------------------------------------------------------
// Unified fp16 single-pass MFMA GEMM: 128xBN tile, BK=64. BN in {64,128}.
// ---------------------------------------------------------------------------
template<int BN, int FLAGS>
__global__ __launch_bounds__(256, 4)
void ggemm(const uint16_t* __restrict__ Ah, const uint16_t* __restrict__ Bh,
           const float* __restrict__ bias, float* __restrict__ Cf,
           uint16_t* __restrict__ Cb, uint16_t* __restrict__ Xkh,
           uint16_t* __restrict__ Xvh, int Msz, int Nsz, int Ksz)
{
    constexpr int FN = BN/32;
    __shared__ uint16_t As0[8192];
    __shared__ uint16_t Bs0[BN*64];

    const int tid  = threadIdx.x;
    const int lane = tid & 63;
    const int wu   = __builtin_amdgcn_readfirstlane(tid >> 6);
    const int wm   = wu >> 1, wn = wu & 1;
    const int m0   = blockIdx.y * 128;
    const int n0   = blockIdx.x * BN;

    const int sr8 = lane >> 3;
    const int skw = (((lane & 7) ^ sr8) * 8);

    int rA[4], rB[FN];
#pragma unroll
    for (int i=0;i<4;i++){
        int r = m0 + (wu*4 + i)*8 + sr8;
        rA[i] = (r > Msz-1) ? Msz-1 : r;
    }
#pragma unroll
    for (int i=0;i<FN;i++){
        int r = n0 + (wu*FN + i)*8 + sr8;
        rB[i] = (r > Nsz-1) ? Nsz-1 : r;
    }

    f32x4 acc[4][FN];
#pragma unroll
    for (int i=0;i<4;i++)
#pragma unroll
        for (int j=0;j<FN;j++) acc[i][j] = (f32x4){0.f,0.f,0.f,0.f};

    const int lc16 = lane & 15;
    const int kgrp = lane >> 4;

    for (int kt = 0; kt < Ksz; kt += 64){
#pragma unroll
        for (int i=0;i<4;i++)
            gl16(Ah + (size_t)rA[i]*Ksz + kt + skw, &As0[(wu*4 + i)*512]);
#pragma unroll
        for (int i=0;i<FN;i++)
            gl16(Bh + (size_t)rB[i]*Ksz + kt + skw, &Bs0[(wu*FN + i)*512]);
        __syncthreads();

#pragma unroll
        for (int ks=0; ks<2; ks++){
            f16x8 ah[4];
#pragma unroll
            for (int fm=0; fm<4; fm++){
                const int r   = wm*64 + fm*16 + lc16;
                const int off = r*64 + (((ks*4 + kgrp) ^ (r & 7))*8);
                ah[fm] = ldh8(&As0[off]);
            }
#pragma unroll
            for (int fn=0; fn<FN; fn++){
                const int rb   = wn*(BN/2) + fn*16 + lc16;
                const int offb = rb*64 + (((ks*4 + kgrp) ^ (rb & 7))*8);
                f16x8 bh = ldh8(&Bs0[offb]);
#pragma unroll
                for (int fm=0; fm<4; fm++)
                    acc[fm][fn] = __builtin_amdgcn_mfma_f32_16x16x32_f16(ah[fm], bh, acc[fm][fn], 0,0,0);
            }
        }
        __syncthreads();
    }

    const int lr4 = (lane >> 4) * 4;
#pragma unroll
    for (int fm=0; fm<4; fm++){
        const int rbase = m0 + wm*64 + fm*16 + lr4;
#pragma unroll
        for (int fn=0; fn<FN; fn++){
            const int col = n0 + wn*(BN/2) + fn*16 + lc16;
            f32x4 v = acc[fm][fn];
            if (FLAGS & EPI_QKV){
                const int g   = col >> 9;
                const int cc2 = col & 511;
                const int hh2 = cc2 >> 6, dd2 = cc2 & 63;
                const float bcol = bias[col];
#pragma unroll
                for (int r=0;r<4;r++){
                    int row = rbase + r;
                    if (row < Msz){
                        float x = v[r] + bcol;
                        int b2 = row / TT, t2 = row - b2*TT;
                        int bh2 = b2*HH + hh2;
                        if (g == 0){
                            size_t o = ((size_t)bh2*TT + t2)*64 + dd2;
                            Cb[o] = f2h(x * 0.125f);
                        } else if (g == 1){
                            size_t o = ((size_t)bh2*TT + t2)*64 + dd2;
                            Xkh[o] = f2h(x);
                        } else {
                            size_t o = ((size_t)bh2*64 + dd2)*VSTR + t2;
                            Xvh[o] = f2h(x);
                        }
                    }
                }
            } else if (FLAGS & EPI_PREDT){
#pragma unroll
                for (int r=0;r<4;r++){
                    int row = rbase + r;
                    if (row < Msz && col < PP){
                        int b = row / TT, t = row - b*TT;
                        if (t < NN)
                            Cf[((size_t)b*PP + col)*NN + t] = v[r] + bias[col];
                    }
                }
            } else {
                const float bcol = bias[col];
#pragma unroll
                for (int r=0;r<4;r++){
                    int row = rbase + r;
                    if (row < Msz){
                        float x = v[r] + bcol;
                        if (FLAGS & EPI_GELU) x = gelu_tanh(x);
                        if (FLAGS & EPI_F32) Cf[(size_t)row*Nsz + col] = x;
                        if (FLAGS & EPI_H16) Cb[(size_t)row*Nsz + col] = f2h(x);
                    }
                }
            }
        }
    }
}

// ---------------------------------------------------------------------------
// tok transpose -> fp16 single plane (unchanged)
// ---------------------------------------------------------------------------
__global__ __launch_bounds__(256)
void tok_k(const float* __restrict__ xe, const float* __restrict__ xm,
           uint16_t* __restrict__ th)
{
    const int b = blockIdx.z;
    const int t0 = blockIdx.x*32, l0 = blockIdx.y*32;
    __shared__ float tile[32][33];
    const int i = threadIdx.x >> 3;
    const int j4 = (threadIdx.x & 7) * 4;
#pragma unroll
    for (int c=0;c<4;c++){
        int t = t0 + j4 + c;
        float v = 0.0f;
        if (t < 512)      v = xe[((size_t)b*LL + l0+i)*NN + t];
        else if (t < 516) v = xm[((size_t)b*LL + l0+i)*4 + (t-512)];
        tile[i][j4+c] = v;
    }
    __syncthreads();
    int t = t0 + i;
    if (t < TT){
#pragma unroll
        for (int c=0;c<4;c++){
            size_t idx = ((size_t)b*TT + t)*512 + l0 + j4 + c;
            th[idx] = f2h(tile[j4+c][i]);
        }
    }
}

// ---------------------------------------------------------------------------
// ALL weight transposes in one launch, fp16 single plane (unchanged)
// ---------------------------------------------------------------------------
struct WtrDesc {
    const float* src; uint16_t* dh;
    int Ksz, Nsz, ntx, nty; size_t zstride; int base;
};
struct WtrTab { WtrDesc d[8]; };

__global__ __launch_bounds__(256)
void wtrall_k(WtrTab tab)
{
    const int bid = blockIdx.x;
    int e = 0;
#pragma unroll
    for (int i=1;i<8;i++) if (bid >= tab.d[i].base) e = i;
    const float* src = tab.d[e].src;
    uint16_t* dh = tab.d[e].dh;
    const int Ksz = tab.d[e].Ksz, Nsz = tab.d[e].Nsz;
    const int ntx = tab.d[e].ntx, nty = tab.d[e].nty;
    const size_t zs = tab.d[e].zstride;
    int local = bid - tab.d[e].base;
    const int tilesper = ntx*nty;
    const int z = local / tilesper;
    local -= z*tilesper;
    const int tyi = local / ntx;
    const int txi = local - tyi*ntx;
    src += (size_t)z*Ksz*Nsz; dh += (size_t)z*zs;
    const int kt = tyi*32, nt = txi*32;

    __shared__ float tile[32][33];
    const int i = threadIdx.x >> 3;
    const int j4 = (threadIdx.x & 7) * 4;
#pragma unroll
    for (int c=0;c<4;c++){
        int n = nt + j4 + c;
        tile[i][j4+c] = (n < Nsz) ? src[(size_t)(kt+i)*Nsz + n] : 0.0f;
    }
    __syncthreads();
    int n = nt + i;
    if (n < Nsz){
#pragma unroll
        for (int c=0;c<4;c++)
            dh[(size_t)n*Ksz + kt + j4 + c] = f2h(tile[j4+c][i]);
    }
}

__global__ void catb_k(const float* __restrict__ bq, const float* __restrict__ bk,
                       const float* __restrict__ bv, float* __restrict__ dst){
    int j = blockIdx.x*256 + threadIdx.x;
    if (j >= 3072) return;
    int layer = j / 1536, r = j - layer*1536;
    float v;
    if (r < 512)       v = bq[layer*512 + r];
    else if (r < 1024) v = bk[layer*512 + r - 512];
    else               v = bv[layer*512 + r - 1024];
    dst[j] = v;
}

// ---------------------------------------------------------------------------
// MFMA flash attention, fp16 (unchanged)
// ---------------------------------------------------------------------------
__global__ __launch_bounds__(256, 4)
void attnm_k(const uint16_t* __restrict__ qs, const uint16_t* __restrict__ ks,
             const uint16_t* __restrict__ vts, uint16_t* __restrict__ oh)
{
    const int qt = blockIdx.x;
    const int h  = blockIdx.y;
    const int b  = blockIdx.z;
    const int bh = b*HH + h;
    const int q0 = qt*64;
    const int tid  = threadIdx.x;
    const int lane = tid & 63;
    const int wu   = __builtin_amdgcn_readfirstlane(tid >> 6);
    const int mrow = lane & 15;
    const int kgrp = lane >> 4;

    __shared__ uint16_t Khs[4096];
    __shared__ uint16_t Vhs[4096];
    __shared__ uint16_t Phs[4096];

    int tq = q0 + wu*16 + mrow; if (tq > TT-1) tq = TT-1;
    const uint16_t* qbase = qs + ((size_t)bh*TT + tq)*64 + kgrp*8;
    f16x8 qfh[2];
    qfh[0] = ldh8(qbase);      qfh[1] = ldh8(qbase + 32);

    const int srw = lane >> 3;
    const int sg  = lane & 7;

    f32x4 oacc[4];
#pragma unroll
    for (int f=0;f<4;f++) oacc[f] = (f32x4){0.f,0.f,0.f,0.f};
    float m_r[4] = {-1e30f,-1e30f,-1e30f,-1e30f};
    float l_r[4] = {0.f,0.f,0.f,0.f};

    for (int st=0; st<9; ++st){
        const int s0 = st*64;
        __syncthreads();
#pragma unroll
        for (int c=0;c<2;c++){
            const int r   = wu*16 + c*8 + srw;
            const int gsl = sg ^ (r & 7);
            int sk = s0 + r; if (sk > TT-1) sk = TT-1;
            const uint16_t* ksh_ = ks  + ((size_t)bh*TT + sk)*64 + gsl*8;
            int cb = s0 + gsl*8; if (cb > VSTR-8) cb = VSTR-8;
            const uint16_t* vsh_ = vts + ((size_t)bh*64 + r)*VSTR + cb;
            gl16(ksh_, &Khs[(wu*16 + c*8)*64]);
            gl16(vsh_, &Vhs[(wu*16 + c*8)*64]);
        }
        __syncthreads();

        f32x4 sacc[4];
#pragma unroll
        for (int f=0;f<4;f++) sacc[f] = (f32x4){0.f,0.f,0.f,0.f};
#pragma unroll
        for (int ks2=0; ks2<2; ks2++){
#pragma unroll
            for (int f=0; f<4; f++){
                const int sr = f*16 + mrow;
                const int sl = ((ks2*4 + kgrp) ^ (sr & 7))*8;
                f16x8 kbh = ldh8(&Khs[sr*64 + sl]);
                sacc[f] = __builtin_amdgcn_mfma_f32_16x16x32_f16(qfh[ks2], kbh, sacc[f], 0,0,0);
            }
        }

        float alpha[4];
#pragma unroll
        for (int r=0;r<4;r++){
            float mx = -1e30f;
#pragma unroll
            for (int f=0;f<4;f++){
                float sv = sacc[f][r];
                if (s0 + f*16 + mrow >= TT) sv = -1e30f;
                sacc[f][r] = sv;
                mx = fmaxf(mx, sv);
            }
#pragma unroll
            for (int msk=1; msk<16; msk<<=1) mx = fmaxf(mx, __shfl_xor(mx, msk));
            float mn = fmaxf(m_r[r], mx);
            alpha[r] = __expf(m_r[r] - mn);
            m_r[r] = mn;
            float rs = 0.0f;
#pragma unroll
            for (int f=0;f<4;f++){
                float e = __expf(sacc[f][r] - mn);
                sacc[f][r] = e;
                rs += e;
            }
#pragma unroll
            for (int msk=1; msk<16; msk<<=1) rs += __shfl_xor(rs, msk);
            l_r[r] = l_r[r]*alpha[r] + rs;
#pragma unroll
            for (int f=0;f<4;f++) oacc[f][r] *= alpha[r];
        }

#pragma unroll
        for (int r=0;r<4;r++){
            const int tr = wu*16 + kgrp*4 + r;
#pragma unroll
            for (int f=0;f<4;f++){
                const int c = f*16 + mrow;
                const int idx = tr*64 + ((c>>3) ^ (tr&7))*8 + (c&7);
                Phs[idx] = f2h(sacc[f][r]);
            }
        }

#pragma unroll
        for (int ks2=0; ks2<2; ks2++){
            const int trr = wu*16 + mrow;
            const int psl = ((ks2*4 + kgrp) ^ (trr & 7))*8;
            f16x8 pah = ldh8(&Phs[trr*64 + psl]);
#pragma unroll
            for (int f=0; f<4; f++){
                const int dr = f*16 + mrow;
                const int vsl = ((ks2*4 + kgrp) ^ (dr & 7))*8;
                f16x8 vbh = ldh8(&Vhs[dr*64 + vsl]);
                oacc[f] = __builtin_amdgcn_mfma_f32_16x16x32_f16(pah, vbh, oacc[f], 0,0,0);
            }
        }
    }

#pragma unroll
    for (int r=0;r<4;r++){
        const int t = q0 + wu*16 + kgrp*4 + r;
        if (t < TT){
            const float inv = 1.0f / l_r[r];
#pragma unroll
            for (int f=0;f<4;f++){
                const int d = f*16 + mrow;
                size_t o = ((size_t)(b*TT + t))*DD + h*DHD + d;
                oh[o] = f2h(oacc[f][r]*inv);
            }
        }
    }
}

// ---------------------------------------------------------------------------
// Residual + LayerNorm v3: all-fp16 I/O (fp32 math), wave-per-row, in-place.
// ---------------------------------------------------------------------------
__global__ __launch_bounds__(256)
void ln_k(const uint16_t* __restrict__ src, const uint16_t* __restrict__ res,
          const float* __restrict__ w, const float* __restrict__ bia,
          uint16_t* __restrict__ dst)
{
    const int r    = blockIdx.x*4 + (threadIdx.x >> 6);
    const int lane = threadIdx.x & 63;
    const int c0   = lane*8;
    const size_t off = (size_t)r*DD + c0;

    u16x8 xs = *(const u16x8*)(src + off);
    float x[8];
#pragma unroll
    for (int i=0;i<8;i++) x[i] = h2f(xs[i]);
    if (res){
        u16x8 rs = *(const u16x8*)(res + off);
#pragma unroll
        for (int i=0;i<8;i++) x[i] += h2f(rs[i]);
    }
    float s = 0.f, sq = 0.f;
#pragma unroll
    for (int i=0;i<8;i++){ s += x[i]; sq = fmaf(x[i], x[i], sq); }
#pragma unroll
    for (int msk=1; msk<64; msk<<=1){
        s  += __shfl_xor(s,  msk);
        sq += __shfl_xor(sq, msk);
    }
    float mu  = s * (1.0f/512.0f);
    float var = sq * (1.0f/512.0f) - mu*mu;
    float rsd = rsqrtf(var + 1e-5f);

    float4 w0 = *(const float4*)(w + c0);
    float4 w1 = *(const float4*)(w + c0 + 4);
    float4 b0 = *(const float4*)(bia + c0);
    float4 b1 = *(const float4*)(bia + c0 + 4);
    float wv[8] = {w0.x,w0.y,w0.z,w0.w,w1.x,w1.y,w1.z,w1.w};
    float bv[8] = {b0.x,b0.y,b0.z,b0.w,b1.x,b1.y,b1.z,b1.w};

    u16x8 vh;
#pragma unroll
    for (int i=0;i<8;i++) vh[i] = f2h((x[i]-mu)*rsd*wv[i] + bv[i]);
    *(u16x8*)(dst + off) = vh;
}

// ---------------------------------------------------------------------------
// sims v4 (unchanged, fp32)
// ---------------------------------------------------------------------------
__global__ __launch_bounds__(256, 4)
void sims_k(const float* __restrict__ pred, const float* __restrict__ bank,
            float* __restrict__ dotp, float* __restrict__ nrmp)
{
    const int jt = blockIdx.x, kt = blockIdx.y;
    const int tid  = threadIdx.x;
    const int qq    = tid & 7;
    const int slice = tid >> 3;
    const int sb    = slice*8;
    const int srow  = tid >> 4;
    const int tau   = tid & 15;

    __shared__ float BS[16*264];

    const int jr = jt*16 + srow;
    const float* bsrc = (jr < MM) ? (bank + (size_t)jr*PN)
                                  : (pred + (size_t)(jr - MM)*PN);
    bsrc += (size_t)kt*SCHUNK + tau*4;
    const float* p0 = pred + (size_t)qq*PN      + (size_t)kt*SCHUNK + sb;
    const float* p1 = pred + (size_t)(qq+8)*PN  + (size_t)kt*SCHUNK + sb;

    float acc0[16], acc1[16];
#pragma unroll
    for (int j=0;j<16;j++){ acc0[j] = 0.0f; acc1[j] = 0.0f; }
    float nr = 0.0f;

    float4 blv[4], pr0[2], pr1[2];
#pragma unroll
    for (int c=0;c<4;c++) blv[c] = *(const float4*)(bsrc + c*64);
    pr0[0] = *(const float4*)(p0); pr0[1] = *(const float4*)(p0 + 4);
    pr1[0] = *(const float4*)(p1); pr1[1] = *(const float4*)(p1 + 4);
    bsrc += 256; p0 += 256; p1 += 256;

    for (int st=0; st<SSTG; ++st){
#pragma unroll
        for (int c=0;c<4;c++){
            *(float4*)&BS[srow*264 + tau*4 + c*64] = blv[c];
            nr = fmaf(blv[c].x, blv[c].x, nr);
            nr = fmaf(blv[c].y, blv[c].y, nr);
            nr = fmaf(blv[c].z, blv[c].z, nr);
            nr = fmaf(blv[c].w, blv[c].w, nr);
        }
        float4 cp0[2] = {pr0[0], pr0[1]};
        float4 cp1[2] = {pr1[0], pr1[1]};
        if (st + 1 < SSTG){
#pragma unroll
            for (int c=0;c<4;c++) blv[c] = *(const float4*)(bsrc + c*64);
            pr0[0] = *(const float4*)(p0); pr0[1] = *(const float4*)(p0 + 4);
            pr1[0] = *(const float4*)(p1); pr1[1] = *(const float4*)(p1 + 4);
            bsrc += 256; p0 += 256; p1 += 256;
        }
        __syncthreads();
#pragma unroll
        for (int j=0;j<16;j++){
            float4 b0 = *(const float4*)&BS[j*264 + sb];
            float4 b1 = *(const float4*)&BS[j*264 + sb + 4];
            float a0 = acc0[j], a1 = acc1[j];
            a0 = fmaf(b0.x, cp0[0].x, a0); a0 = fmaf(b0.y, cp0[0].y, a0);
            a0 = fmaf(b0.z, cp0[0].z, a0); a0 = fmaf(b0.w, cp0[0].w, a0);
            a0 = fmaf(b1.x, cp0[1].x, a0); a0 = fmaf(b1.y, cp0[1].y, a0);
            a0 = fmaf(b1.z, cp0[1].z, a0); a0 = fmaf(b1.w, cp0[1].w, a0);
            a1 = fmaf(b0.x, cp1[0].x, a1); a1 = fmaf(b0.y, cp1[0].y, a1);
            a1 = fmaf(b0.z, cp1[0].z, a1); a1 = fmaf(b0.w, cp1[0].w, a1);
            a1 = fmaf(b1.x, cp1[1].x, a1); a1 = fmaf(b1.y, cp1[1].y, a1);
            a1 = fmaf(b1.z, cp1[1].z, a1); a1 = fmaf(b1.w, cp1[1].w, a1);
            acc0[j] = a0; acc1[j] = a1;
        }
        __syncthreads();
    }

#pragma unroll
    for (int m=8; m<64; m<<=1){
#pragma unroll
        for (int j=0;j<16;j++){
            acc0[j] += __shfl_xor(acc0[j], m);
            acc1[j] += __shfl_xor(acc1[j], m);
        }
    }
#pragma unroll
    for (int m=1;m<16;m<<=1) nr += __shfl_xor(nr, m);

    __syncthreads();
    float* RED = BS;
    const int wu2  = tid >> 6;
    const int lane = tid & 63;
    if (lane < 8){
#pragma unroll
        for (int j=0;j<16;j++){
            RED[(wu2*16 + j)*16 + lane]     = acc0[j];
            RED[(wu2*16 + j)*16 + lane + 8] = acc1[j];
        }
    }
    __syncthreads();
    const int j2 = tid >> 4, q2 = tid & 15;
    float s = RED[(0*16 + j2)*16 + q2] + RED[(1*16 + j2)*16 + q2]
            + RED[(2*16 + j2)*16 + q2] + RED[(3*16 + j2)*16 + q2];
    dotp[((size_t)kt*528 + jt*16 + j2)*16 + q2] = s;
    if (tau == 0) nrmp[kt*528 + jt*16 + srow] = nr;
}

// ---------------------------------------------------------------------------
// Fused sims tail (unchanged)
// ---------------------------------------------------------------------------
__global__ __launch_bounds__(256)
void simstail_k(const float* __restrict__ dotp, const float* __restrict__ nrmp,
                int* __restrict__ idx)
{
    const int q   = blockIdx.x;
    const int tid = threadIdx.x;
    __shared__ float invn[528];
    __shared__ float vals[528];

    for (int j=tid; j<528; j+=256){
        float s = 0.0f;
        for (int kt=0; kt<SKC; kt++) s += nrmp[kt*528 + j];
        invn[j] = 1.0f/(sqrtf(s) + 1e-8f);
    }
    __syncthreads();
    const float invq = invn[MM + q];
    for (int j=tid; j<528; j+=256){
        float s = 0.0f;
        for (int kt=0; kt<SKC; kt++) s += dotp[((size_t)kt*528 + j)*16 + q];
        vals[j] = s * invn[j] * invq;
    }
    __syncthreads();
    if (tid < 64){
        const int lane = tid;
        for (int kk=0; kk<KNN; kk++){
            float bv = -3.0e38f; int bi = 1<<30;
            for (int j=lane; j<528; j+=64){
                float v2 = vals[j];
                if (v2 > bv || (v2 == bv && j < bi)){ bv = v2; bi = j; }
            }
#pragma unroll
            for (int msk=1; msk<64; msk<<=1){
                float ov = __shfl_xor(bv, msk);
                int   oi = __shfl_xor(bi, msk);
                if (ov > bv || (ov == bv && oi < bi)){ bv = ov; bi = oi; }
            }
            if (lane == 0){
                idx[q*KNN + kk] = bi;
                vals[bi] = -3.0e38f;
            }
        }
    }
}

__global__ __launch_bounds__(256)
void fuse_k(const float* __restrict__ pred, const float* __restrict__ bank,
            const int* __restrict__ idx, float* __restrict__ out){
    int u = blockIdx.x*256 + threadIdx.x;
    int b = u / (PN/4);
    int e = (u - b*(PN/4)) * 4;
    int id[KNN];
#pragma unroll
    for (int k2=0;k2<KNN;k2++) id[k2] = idx[b*KNN + k2];
    float4 pv = *(const float4*)(pred + (size_t)b*PN + e);
    float ax = 0.5f*pv.x, ay = 0.5f*pv.y, az = 0.5f*pv.z, aw = 0.5f*pv.w;
#pragma unroll
    for (int k2=0;k2<KNN;k2++){
        const float* rp = (id[k2] < MM) ? (bank + (size_t)id[k2]*PN)
                                        : (pred + (size_t)(id[k2]-MM)*PN);
        float4 rv = *(const float4*)(rp + e);
        ax = fmaf(0.05f, rv.x, ax); ay = fmaf(0.05f, rv.y, ay);
        az = fmaf(0.05f, rv.z, az); aw = fmaf(0.05f, rv.w, aw);
    }
    float4 ov; ov.x=ax; ov.y=ay; ov.z=az; ov.w=aw;
    *(float4*)(out + (size_t)b*PN + e) = ov;
}

// ---------------------------------------------------------------------------
extern "C" void kernel_launch(void* const* d_in, const int* in_sizes, int n_in,
                              void* d_out, int out_size, void* d_ws, size_t ws_size,
                              hipStream_t stream)
{
    (void)in_sizes; (void)n_in; (void)out_size; (void)ws_size;
    const float* x_enc  = (const float*)d_in[0];
    const float* x_mark = (const float*)d_in[1];
    const float* W_emb  = (const float*)d_in[4];
    const float* b_emb  = (const float*)d_in[5];
    const float* Wq  = (const float*)d_in[6];
    const float* Wk  = (const float*)d_in[7];
    const float* Wv  = (const float*)d_in[8];
    const float* Wo  = (const float*)d_in[9];
    const float* bq  = (const float*)d_in[10];
    const float* bk  = (const float*)d_in[11];
    const float* bv_ = (const float*)d_in[12];
    const float* bo  = (const float*)d_in[13];
    const float* ln1w = (const float*)d_in[14];
    const float* ln1b = (const float*)d_in[15];
    const float* ln2w = (const float*)d_in[16];
    const float* ln2b = (const float*)d_in[17];
    const float* Wff1 = (const float*)d_in[18];
    const float* bff1 = (const float*)d_in[19];
    const float* Wff2 = (const float*)d_in[20];
    const float* bff2 = (const float*)d_in[21];
    const float* lnfw = (const float*)d_in[22];
    const float* lnfb = (const float*)d_in[23];
    const float* Wproj = (const float*)d_in[24];
    const float* bproj = (const float*)d_in[25];
    const float* bank  = (const float*)d_in[26];
    float* out = (float*)d_out;

    char* pp = (char*)d_ws;
    auto a16 = [&](size_t elems)->uint16_t*{ uint16_t* r=(uint16_t*)pp; pp += ((elems*2 + 255)/256)*256; return r; };
    auto af  = [&](size_t elems)->float*  { float* r=(float*)pp;  pp += ((elems*4 + 255)/256)*256; return r; };

    uint16_t* wembT = a16(262144);
    uint16_t* wqkvT = a16((size_t)2*1536*512);
    uint16_t* woT   = a16((size_t)2*262144);
    uint16_t* wff1T = a16((size_t)2*2048*512);
    uint16_t* wff2T = a16((size_t)2*512*2048);
    uint16_t* wprjT = a16(172032);
    float*    bqkv  = af(3072);
    uint16_t* hb    = a16((size_t)BT*512);    // fp16 residual stream
    uint16_t* tok   = a16((size_t)BT*512);
    uint16_t* og16  = a16((size_t)BT*512);    // fp16 sublayer outputs
    uint16_t* qsh   = a16((size_t)128*TT*64);
    uint16_t* ksh   = a16((size_t)128*TT*64);
    uint16_t* vsh   = a16((size_t)128*64*VSTR + 4096);
    uint16_t* t1b   = a16((size_t)BT*512);
    uint16_t* midb  = qsh;   // FF1 out aliases qsh..t1b (all dead at FF1 time)
    float*    pred  = af((size_t)BB*PN);
    float*    dotp  = af((size_t)SKC*528*16);
    float*    nrmp  = af(SKC*528);
    int*      idxp  = (int*)af(256);

    dim3 blk(256);

    tok_k<<<dim3(17,16,BB), blk, 0, stream>>>(x_enc, x_mark, tok);

    WtrTab tab;
    tab.d[0] = { W_emb, wembT, 512, 512, 16, 16, 262144, 0 };
    tab.d[1] = { Wq, wqkvT,          512, 512, 16, 16, 786432, 256 };
    tab.d[2] = { Wk, wqkvT + 262144, 512, 512, 16, 16, 786432, 768 };
    tab.d[3] = { Wv, wqkvT + 524288, 512, 512, 16, 16, 786432, 1280 };
    tab.d[4] = { Wo, woT, 512, 512, 16, 16, 262144, 1792 };
    tab.d[5] = { Wff1, wff1T, 512, 2048, 64, 16, 1048576, 2304 };
    tab.d[6] = { Wff2, wff2T, 2048, 512, 16, 64, 1048576, 4352 };
    tab.d[7] = { Wproj, wprjT, 512, 336, 11, 16, 172032, 6400 };
    wtrall_k<<<dim3(6576), blk, 0, stream>>>(tab);
    catb_k<<<dim3(12), blk, 0, stream>>>(bq, bk, bv_, bqkv);

    // embedding -> fp16 residual stream hb
    ggemm<64, EPI_H16><<<dim3(8,65), blk, 0, stream>>>(
        tok, wembT, b_emb, nullptr, hb, nullptr, nullptr, BT, 512, 512);

    for (int i=0;i<2;i++){
        ggemm<128, EPI_QKV><<<dim3(12,65), blk, 0, stream>>>(
            hb, wqkvT + (size_t)i*786432, bqkv + i*1536,
            nullptr, qsh, ksh, vsh, BT, 1536, 512);
        attnm_k<<<dim3(9,HH,BB), blk, 0, stream>>>(qsh, ksh, vsh, t1b);
        ggemm<64, EPI_H16><<<dim3(8,65), blk, 0, stream>>>(
            t1b, woT + (size_t)i*262144, bo + i*512, nullptr, og16,
            nullptr, nullptr, BT, 512, 512);
        ln_k<<<dim3(BT/4), blk, 0, stream>>>(hb, og16, ln1w + i*512, ln1b + i*512, hb);
        ggemm<128, EPI_GELU|EPI_H16><<<dim3(16,65), blk, 0, stream>>>(
            hb, wff1T + (size_t)i*1048576, bff1 + i*DFFN,
            nullptr, midb, nullptr, nullptr, BT, DFFN, 512);
        ggemm<64, EPI_H16><<<dim3(8,65), blk, 0, stream>>>(
            midb, wff2T + (size_t)i*1048576, bff2 + i*512, nullptr, og16,
            nullptr, nullptr, BT, 512, DFFN);
        ln_k<<<dim3(BT/4), blk, 0, stream>>>(hb, og16, ln2w + i*512, ln2b + i*512, hb);
    }

    ln_k<<<dim3(BT/4), blk, 0, stream>>>(hb, nullptr, lnfw, lnfb, hb);

    ggemm<64, EPI_PREDT><<<dim3(6,65), blk, 0, stream>>>(
        hb, wprjT, bproj, pred, nullptr, nullptr, nullptr, BT, PP, 512);

    sims_k<<<dim3(33,SKC), blk, 0, stream>>>(pred, bank, dotp, nrmp);
    simstail_k<<<dim3(BB), blk, 0, stream>>>(dotp, nrmp, idxp);
    fuse_k<<<dim3((BB*PN/4)/256), blk, 0, stream>>>(pred, bank, idxp, out);
}